// Round 14
// baseline (2673.017 us; speedup 1.0000x reference)
//
#include <hip/hip_runtime.h>

// ---------------------------------------------------------------------------
// HeteroGNN (2-layer hetero GAT) forward on MI355X — round 14.
// Round-13 post-mortem: lane-per-edge edge kernel spilled cacc[64] to scratch
// (VGPR blowout -> 2.98GB scratch traffic, 972us). Fix: ALGEBRAIC — the
// self-loop scalar is invE * sum_e hd[e] (dot distributes over the column
// sums), so the column accumulator is deleted; per-thread scalar s1/s2 +
// block reduce + 3-scalar atomicAdd. Structure otherwise identical to r13.
// ---------------------------------------------------------------------------

static constexpr int NPn = 150000;
static constexpr int NBn = 250000;
static constexpr int En  = 500000;

// concatenated CSR layout (256-aligned segments)
static constexpr int OFF_PP = 0;
static constexpr int OFF_BP = 150016;
static constexpr int OFF_BB = 300032;
static constexpr int NCAT   = 550144;
static constexpr int NB_TOT = NCAT / 256;
static constexpr int BS_BP  = OFF_BP / 256;
static constexpr int BS_BB  = OFF_BB / 256;

__device__ __forceinline__ float lrelu(float x, float s) { return x >= 0.0f ? x : s * x; }

__global__ void fill_kernel(float* out, float val, int n) {
  int i = blockIdx.x * blockDim.x + threadIdx.x;
  if (i < n) out[i] = val;
}

// ---------------- batched CSR build ----------------
struct Dsts { const int* d[3]; };

__global__ void zero_int_kernel(int* p, int n) {
  int i = blockIdx.x * blockDim.x + threadIdx.x;
  if (i < n) p[i] = 0;
}

__global__ void hist_all_kernel(Dsts ds, int* __restrict__ cnt) {
  int t = blockIdx.x * blockDim.x + threadIdx.x;
  if (t >= 3 * En) return;
  int rel = t / En, e = t - rel * En;
  int base = (rel == 0) ? OFF_PP : (rel == 1) ? OFF_BP : OFF_BB;
  atomicAdd(&cnt[base + ds.d[rel][e]], 1);
}

__global__ void scan1_kernel(const int* __restrict__ cnt, int* __restrict__ incl,
                             int* __restrict__ bsum, int n) {
  __shared__ int s[256];
  int i = blockIdx.x * 256 + threadIdx.x;
  s[threadIdx.x] = (i < n) ? cnt[i] : 0;
  __syncthreads();
  for (int o = 1; o < 256; o <<= 1) {
    int t = (threadIdx.x >= o) ? s[threadIdx.x - o] : 0;
    __syncthreads();
    s[threadIdx.x] += t;
    __syncthreads();
  }
  if (i < n) incl[i] = s[threadIdx.x];
  if (threadIdx.x == 255) bsum[blockIdx.x] = s[255];
}

__global__ void scan2_kernel(int* bsum) {
  int t = threadIdx.x;
  if (t >= 3) return;
  int lo = (t == 0) ? 0 : (t == 1) ? BS_BP : BS_BB;
  int hi = (t == 0) ? BS_BP : (t == 1) ? BS_BB : NB_TOT;
  int run = 0;
  for (int i = lo; i < hi; ++i) { int v = bsum[i]; bsum[i] = run; run += v; }
}

__global__ void scan3_kernel(const int* __restrict__ cnt, int* __restrict__ offs,
                             const int* __restrict__ bsum, int n) {
  int i = blockIdx.x * 256 + threadIdx.x;
  if (i < n) offs[i] = offs[i] - cnt[i] + bsum[i >> 8];
}

__global__ void copy_int_kernel(const int* __restrict__ src, int* __restrict__ dstp, int n) {
  int i = blockIdx.x * blockDim.x + threadIdx.x;
  if (i < n) dstp[i] = src[i];
}

__global__ void scatter_all_kernel(Dsts ds, int* __restrict__ cursor, int* __restrict__ eidx) {
  int t = blockIdx.x * blockDim.x + threadIdx.x;
  if (t >= 3 * En) return;
  int rel = t / En, e = t - rel * En;
  int base = (rel == 0) ? OFF_PP : (rel == 1) ? OFF_BP : OFF_BB;
  int p = atomicAdd(&cursor[base + ds.d[rel][e]], 1);
  eidx[rel * En + p] = e;
}

// ---------------- dense kernels (proven) ----------------
__global__ void proj_kernel(const float* __restrict__ X, const float* __restrict__ W,
                            const float* __restrict__ b, float* __restrict__ Y, int N) {
  __shared__ __align__(16) float Ws[32 * 64];
  __shared__ float bs[64];
  for (int i = threadIdx.x; i < 32 * 64; i += blockDim.x) Ws[i] = W[i];
  if (threadIdx.x < 64) bs[threadIdx.x] = b[threadIdx.x];
  __syncthreads();
  int row = blockIdx.x * blockDim.x + threadIdx.x;
  if (row >= N) return;
  float x[32];
  const float4* x4 = reinterpret_cast<const float4*>(X + (size_t)row * 32);
#pragma unroll
  for (int k = 0; k < 8; ++k) {
    float4 v = x4[k];
    x[4 * k + 0] = v.x; x[4 * k + 1] = v.y; x[4 * k + 2] = v.z; x[4 * k + 3] = v.w;
  }
  float4* y4 = reinterpret_cast<float4*>(Y + (size_t)row * 64);
#pragma unroll
  for (int cg = 0; cg < 4; ++cg) {
    float acc[16];
#pragma unroll
    for (int c = 0; c < 16; ++c) acc[c] = bs[cg * 16 + c];
#pragma unroll
    for (int k = 0; k < 32; ++k) {
      float xv = x[k];
      const float4* w4 = reinterpret_cast<const float4*>(&Ws[k * 64 + cg * 16]);
#pragma unroll
      for (int q = 0; q < 4; ++q) {
        float4 w = w4[q];
        acc[4 * q + 0] += xv * w.x; acc[4 * q + 1] += xv * w.y;
        acc[4 * q + 2] += xv * w.z; acc[4 * q + 3] += xv * w.w;
      }
    }
#pragma unroll
    for (int q = 0; q < 4; ++q)
      y4[cg * 4 + q] = make_float4(lrelu(acc[4 * q + 0], 0.01f), lrelu(acc[4 * q + 1], 0.01f),
                                   lrelu(acc[4 * q + 2], 0.01f), lrelu(acc[4 * q + 3], 0.01f));
  }
}

// H = X @ W; S1=H.a1; optional S2. X/H may alias (row-private).
__global__ void hgemm_kernel(const float* X, const float* __restrict__ W,
                             const float* __restrict__ a1, const float* __restrict__ a2,
                             float* H, float* __restrict__ S1,
                             float* __restrict__ S2, int N) {
  __shared__ __align__(16) float Ws[64 * 64];
  __shared__ float a1s[64], a2s[64];
  for (int i = threadIdx.x; i < 64 * 64; i += blockDim.x) Ws[i] = W[i];
  if (threadIdx.x < 64) {
    a1s[threadIdx.x] = a1[threadIdx.x];
    a2s[threadIdx.x] = a2 ? a2[threadIdx.x] : 0.0f;
  }
  __syncthreads();
  int row = blockIdx.x * blockDim.x + threadIdx.x;
  if (row >= N) return;
  float x[64];
  const float4* x4 = reinterpret_cast<const float4*>(X + (size_t)row * 64);
#pragma unroll
  for (int k = 0; k < 16; ++k) {
    float4 v = x4[k];
    x[4 * k + 0] = v.x; x[4 * k + 1] = v.y; x[4 * k + 2] = v.z; x[4 * k + 3] = v.w;
  }
  float4* h4 = reinterpret_cast<float4*>(H + (size_t)row * 64);
  float s1 = 0.0f, s2 = 0.0f;
#pragma unroll
  for (int cg = 0; cg < 4; ++cg) {
    float acc[16];
#pragma unroll
    for (int c = 0; c < 16; ++c) acc[c] = 0.0f;
#pragma unroll
    for (int k = 0; k < 64; ++k) {
      float xv = x[k];
      const float4* w4 = reinterpret_cast<const float4*>(&Ws[k * 64 + cg * 16]);
#pragma unroll
      for (int q = 0; q < 4; ++q) {
        float4 w = w4[q];
        acc[4 * q + 0] += xv * w.x; acc[4 * q + 1] += xv * w.y;
        acc[4 * q + 2] += xv * w.z; acc[4 * q + 3] += xv * w.w;
      }
    }
#pragma unroll
    for (int c = 0; c < 16; ++c) {
      s1 += acc[c] * a1s[cg * 16 + c];
      s2 += acc[c] * a2s[cg * 16 + c];
    }
#pragma unroll
    for (int q = 0; q < 4; ++q)
      h4[cg * 4 + q] = make_float4(acc[4 * q + 0], acc[4 * q + 1], acc[4 * q + 2], acc[4 * q + 3]);
  }
  S1[row] = s1;
  if (S2) S2[row] = s2;
}

__global__ void matvec_kernel(const float* __restrict__ X, const float* __restrict__ v,
                              float* __restrict__ out, int N) {
  __shared__ float vs[64];
  if (threadIdx.x < 64) vs[threadIdx.x] = v[threadIdx.x];
  __syncthreads();
  int i = blockIdx.x * blockDim.x + threadIdx.x;
  if (i >= N) return;
  const float4* x4 = reinterpret_cast<const float4*>(X + (size_t)i * 64);
  float s = 0.0f;
#pragma unroll
  for (int k = 0; k < 16; ++k) {
    float4 u = x4[k];
    s += u.x * vs[4 * k + 0] + u.y * vs[4 * k + 1] + u.z * vs[4 * k + 2] + u.w * vs[4 * k + 3];
  }
  out[i] = s;
}

__global__ void head_kernel(const float* __restrict__ X, const float* __restrict__ w,
                            const float* __restrict__ b, float* __restrict__ out, int N) {
  __shared__ float vs[64];
  if (threadIdx.x < 64) vs[threadIdx.x] = w[threadIdx.x];
  __syncthreads();
  int i = blockIdx.x * blockDim.x + threadIdx.x;
  if (i >= N) return;
  const float4* x4 = reinterpret_cast<const float4*>(X + (size_t)i * 64);
  float s = b[0];
#pragma unroll
  for (int k = 0; k < 16; ++k) {
    float4 u = x4[k];
    s += u.x * vs[4 * k + 0] + u.y * vs[4 * k + 1] + u.z * vs[4 * k + 2] + u.w * vs[4 * k + 3];
  }
  out[i] = s;
}

struct RowdotJobs { const float* M[7]; const float* v[7]; float* out[7]; };
__global__ void rowdot_batch_kernel(RowdotJobs J) {
  __shared__ float vs[64];
  int j = blockIdx.x;
  vs[threadIdx.x] = J.v[j][threadIdx.x];
  __syncthreads();
  float s = 0.0f;
  const float* M = J.M[j];
#pragma unroll
  for (int c = 0; c < 64; ++c) s += M[threadIdx.x * 64 + c] * vs[c];
  J.out[j][threadIdx.x] = s;
}

// ---------------- lane-per-edge fused edge kernel (spill-free) ----------------
// Per edge (one thread): hd1 = lrelu(ea@We+be)·wa1 (hd2 with wa2); x in VGPRs,
// Ws uniform-broadcast from LDS, coalesced hd writes. Self-loop scalars via
// the identity  dot(sum_cols, wa) == sum_e hd[e]  -> per-thread scalar sums
// s1,s2 block-reduced into sacc[3] = {Σhd_pp1, Σhd_pp2, Σhd_bb1}.
struct EdgeJobs {
  const float* EA[3]; const float* We[3]; const float* be[3];
  const float* wa1[3]; const float* wa2[3]; float* hd1[3]; float* hd2[3];
};
__global__ void edge_fused_kernel(EdgeJobs J, float* __restrict__ sacc) {
  int rel = blockIdx.x >> 9;          // 512 blocks per relation
  int blk = blockIdx.x & 511;
  __shared__ __align__(16) float Ws[16 * 64];
  __shared__ __align__(16) float bs[64], w1s[64], w2s[64];
  __shared__ float red1[4], red2[4];
  const float* We = J.We[rel];
  for (int i = threadIdx.x; i < 16 * 64; i += blockDim.x) Ws[i] = We[i];
  bool has2 = (J.wa2[rel] != nullptr);
  if (threadIdx.x < 64) {
    bs[threadIdx.x] = J.be[rel][threadIdx.x];
    w1s[threadIdx.x] = J.wa1[rel][threadIdx.x];
    w2s[threadIdx.x] = has2 ? J.wa2[rel][threadIdx.x] : 0.0f;
  }
  __syncthreads();
  const float4* Ws4 = reinterpret_cast<const float4*>(Ws);
  const float4* bs4 = reinterpret_cast<const float4*>(bs);
  const float4* w1s4 = reinterpret_cast<const float4*>(w1s);
  const float4* w2s4 = reinterpret_cast<const float4*>(w2s);
  const float* EA = J.EA[rel];
  float* hd1 = J.hd1[rel];
  float* hd2 = J.hd2[rel];
  float s1 = 0.0f, s2 = 0.0f;
  for (int e = blk * 256 + threadIdx.x; e < En; e += 512 * 256) {
    float x[16];
    const float4* xa = reinterpret_cast<const float4*>(EA + (size_t)e * 16);
#pragma unroll
    for (int k = 0; k < 4; ++k) {
      float4 v = xa[k];
      x[4 * k + 0] = v.x; x[4 * k + 1] = v.y; x[4 * k + 2] = v.z; x[4 * k + 3] = v.w;
    }
    float d1 = 0.0f, d2 = 0.0f;
#pragma unroll
    for (int jg = 0; jg < 16; ++jg) {
      float4 t = bs4[jg];
#pragma unroll
      for (int k = 0; k < 16; ++k) {
        float4 w = Ws4[k * 16 + jg];   // uniform across lanes -> broadcast
        t.x += x[k] * w.x; t.y += x[k] * w.y; t.z += x[k] * w.z; t.w += x[k] * w.w;
      }
      t.x = lrelu(t.x, 0.01f); t.y = lrelu(t.y, 0.01f);
      t.z = lrelu(t.z, 0.01f); t.w = lrelu(t.w, 0.01f);
      float4 w1 = w1s4[jg];
      d1 += t.x * w1.x + t.y * w1.y + t.z * w1.z + t.w * w1.w;
      float4 w2 = w2s4[jg];
      d2 += t.x * w2.x + t.y * w2.y + t.z * w2.z + t.w * w2.w;
    }
    hd1[e] = d1;
    if (has2) hd2[e] = d2;
    s1 += d1;
    s2 += d2;
  }
  if (rel < 2) {  // self-loop scalar sums needed only for pp (d1,d2) and bb (d1)
    int lane = threadIdx.x & 63, wid = threadIdx.x >> 6;
#pragma unroll
    for (int o = 32; o >= 1; o >>= 1) {
      s1 += __shfl_xor(s1, o, 64);
      s2 += __shfl_xor(s2, o, 64);
    }
    if (lane == 0) { red1[wid] = s1; red2[wid] = s2; }
    __syncthreads();
    if (threadIdx.x == 0) {
      float t1 = red1[0] + red1[1] + red1[2] + red1[3];
      float t2 = red2[0] + red2[1] + red2[2] + red2[3];
      if (rel == 0) {
        atomicAdd(&sacc[0], t1);
        atomicAdd(&sacc[1], t2);
      } else {
        atomicAdd(&sacc[2], t1);
      }
    }
  }
}

// self_* = sacc[*] * invE     <<<1,64>>>
__global__ void selfscale_kernel(const float* __restrict__ sacc, float invE,
                                 float* __restrict__ self_pp1, float* __restrict__ self_pp2,
                                 float* __restrict__ self_bb1) {
  if (threadIdx.x == 0) {
    self_pp1[0] = sacc[0] * invE;
    self_pp2[0] = sacc[1] * invE;
    self_bb1[0] = sacc[2] * invE;
  }
}

// ---------------- single-pass fused per-row GAT ----------------
__global__ void gat_row_kernel(const int* __restrict__ offs, const int* __restrict__ eidx,
                               const int* __restrict__ esrc,
                               const float* __restrict__ ssrc, const float* __restrict__ sdst,
                               const float* __restrict__ hd, const float* __restrict__ selfhd,
                               const float* __restrict__ H, const float* __restrict__ bias,
                               float* __restrict__ out, int N, int accum) {
  int wid = (int)(((size_t)blockIdx.x * blockDim.x + threadIdx.x) >> 6);
  int lane = threadIdx.x & 63;
  if (wid >= N) return;
  int lo = offs[wid], hi = offs[wid + 1];
  float sd = sdst[wid];
  float wsum = 1e-16f;
  float acc = 0.0f;
  if (selfhd) {
    float wself = __expf(lrelu(ssrc[wid] + sd + selfhd[0], 0.2f));
    wsum += wself;
    acc = wself * H[(size_t)wid * 64 + lane];
  }
  for (int p = lo; p < hi; ++p) {
    int e = eidx[p];
    int s = esrc[e];
    float w = __expf(lrelu(ssrc[s] + sd + hd[e], 0.2f));
    wsum += w;
    acc += w * H[(size_t)s * 64 + lane];
  }
  float r = acc / wsum + bias[lane];
  size_t o = (size_t)wid * 64 + lane;
  if (accum) out[o] += r;
  else       out[o] = r;
}

extern "C" void kernel_launch(void* const* d_in, const int* in_sizes, int n_in,
                              void* d_out, int out_size, void* d_ws, size_t ws_size,
                              hipStream_t stream) {
  dim3 B(256);
  auto cdiv = [](int a, int b) { return (a + b - 1) / b; };

  bool okmap = (n_in == 58) &&
               in_sizes[0] == NPn * 32 && in_sizes[1] == NBn * 32 &&
               in_sizes[2] == En * 16 && in_sizes[15] == 4096 &&
               in_sizes[17] == 64 && in_sizes[53] == 64 &&
               in_sizes[55] == 2 * En && in_sizes[57] == 2 * En;
  if (!okmap) {
    fill_kernel<<<cdiv(NPn, 256), B, 0, stream>>>((float*)d_out, 1000.0f, NPn);
    return;
  }

  const float* x_p  = (const float*)d_in[0];
  const float* x_b  = (const float*)d_in[1];
  const float* ea_pp = (const float*)d_in[2];
  const float* ea_bb = (const float*)d_in[3];
  const float* ea_bp = (const float*)d_in[4];
  const float* W_node_p = (const float*)d_in[5];
  const float* b_node_p = (const float*)d_in[6];
  const float* W_node_b = (const float*)d_in[7];
  const float* b_node_b = (const float*)d_in[8];
  const float* W_edge_pp = (const float*)d_in[9];
  const float* b_edge_pp = (const float*)d_in[10];
  const float* W_edge_bb = (const float*)d_in[11];
  const float* b_edge_bb = (const float*)d_in[12];
  const float* W_edge_bp = (const float*)d_in[13];
  const float* b_edge_bp = (const float*)d_in[14];
  const float* c1_pp_W = (const float*)d_in[15];
  const float* c1_pp_We = (const float*)d_in[16];
  const float* c1_pp_asrc = (const float*)d_in[17];
  const float* c1_pp_adst = (const float*)d_in[18];
  const float* c1_pp_aedge = (const float*)d_in[19];
  const float* c1_pp_bias = (const float*)d_in[20];
  const float* c1_bb_W = (const float*)d_in[21];
  const float* c1_bb_We = (const float*)d_in[22];
  const float* c1_bb_asrc = (const float*)d_in[23];
  const float* c1_bb_adst = (const float*)d_in[24];
  const float* c1_bb_aedge = (const float*)d_in[25];
  const float* c1_bb_bias = (const float*)d_in[26];
  const float* c1_bp_Wsrc = (const float*)d_in[27];
  const float* c1_bp_Wdst = (const float*)d_in[28];
  const float* c1_bp_We = (const float*)d_in[29];
  const float* c1_bp_asrc = (const float*)d_in[30];
  const float* c1_bp_adst = (const float*)d_in[31];
  const float* c1_bp_aedge = (const float*)d_in[32];
  const float* c1_bp_bias = (const float*)d_in[33];
  const float* c2_pp_W = (const float*)d_in[34];
  const float* c2_pp_We = (const float*)d_in[35];
  const float* c2_pp_asrc = (const float*)d_in[36];
  const float* c2_pp_adst = (const float*)d_in[37];
  const float* c2_pp_aedge = (const float*)d_in[38];
  const float* c2_pp_bias = (const float*)d_in[39];
  const float* c2_bp_Wsrc = (const float*)d_in[46];
  const float* c2_bp_Wdst = (const float*)d_in[47];
  const float* c2_bp_We = (const float*)d_in[48];
  const float* c2_bp_asrc = (const float*)d_in[49];
  const float* c2_bp_adst = (const float*)d_in[50];
  const float* c2_bp_aedge = (const float*)d_in[51];
  const float* c2_bp_bias = (const float*)d_in[52];
  const float* W_out = (const float*)d_in[53];
  const float* b_out = (const float*)d_in[54];
  const int* ei_pp = (const int*)d_in[55];
  const int* ei_bb = (const int*)d_in[56];
  const int* ei_bp = (const int*)d_in[57];

  // ---- workspace layout
  float* ws = (float*)d_ws;
  int* offs_cat = (int*)ws;                  // NCAT
  int* cnt_cat  = offs_cat + NCAT;           // NCAT
  int* bsum     = cnt_cat + NCAT;            // pad 2560
  int* eidx_cat = bsum + 2560;               // 3*En
  float* xp    = (float*)(eidx_cat + 3 * En);// NPn*64 (p2 aliases)
  float* p1    = xp + (size_t)NPn * 64;      // NPn*64
  float* b1v   = p1 + (size_t)NPn * 64;      // NBn*64
  float* hbuf  = b1v + (size_t)NBn * 64;     // NBn*64
  float* hd_pp1 = hbuf + (size_t)NBn * 64;   // En x5
  float* hd_pp2 = hd_pp1 + En;
  float* hd_bb1 = hd_pp2 + En;
  float* hd_bp1 = hd_bb1 + En;
  float* hd_bp2 = hd_bp1 + En;
  float* s_src = hd_bp2 + En;                // NBn
  float* s_dst = s_src + NBn;                // NBn
  float* small = s_dst + NBn;                // 1024
  float* p2    = xp;

  const size_t NEED = (size_t)(small + 1024 - ws) * sizeof(float);
  if (ws_size < NEED) {
    fill_kernel<<<cdiv(NPn, 256), B, 0, stream>>>((float*)d_out, 500.0f, NPn);
    return;
  }

  float* sacc    = small + 0;    // [3] scalar sums
  float* wa_pp1  = small + 128;  float* wa_pp2  = small + 192;
  float* wa_bb1  = small + 256;  float* wa_bp1  = small + 320; float* wa_bp2 = small + 384;
  float* wd1     = small + 448;  float* wd2     = small + 512;
  float* self_pp1= small + 576;  float* self_pp2= small + 577; float* self_bb1 = small + 578;
  const float invE = 1.0f / (float)En;

  hipMemsetAsync(sacc, 0, 16 * sizeof(float), stream);

  // ---- projections, collapsed vectors, edge scalars
  proj_kernel<<<cdiv(NPn, 256), B, 0, stream>>>(x_p, W_node_p, b_node_p, xp, NPn);

  RowdotJobs RJ;
  RJ.M[0] = c1_pp_We;  RJ.v[0] = c1_pp_aedge; RJ.out[0] = wa_pp1;
  RJ.M[1] = c2_pp_We;  RJ.v[1] = c2_pp_aedge; RJ.out[1] = wa_pp2;
  RJ.M[2] = c1_bb_We;  RJ.v[2] = c1_bb_aedge; RJ.out[2] = wa_bb1;
  RJ.M[3] = c1_bp_We;  RJ.v[3] = c1_bp_aedge; RJ.out[3] = wa_bp1;
  RJ.M[4] = c2_bp_We;  RJ.v[4] = c2_bp_aedge; RJ.out[4] = wa_bp2;
  RJ.M[5] = c1_bp_Wdst; RJ.v[5] = c1_bp_adst; RJ.out[5] = wd1;
  RJ.M[6] = c2_bp_Wdst; RJ.v[6] = c2_bp_adst; RJ.out[6] = wd2;
  rowdot_batch_kernel<<<7, 64, 0, stream>>>(RJ);

  EdgeJobs EJ;
  EJ.EA[0] = ea_pp; EJ.We[0] = W_edge_pp; EJ.be[0] = b_edge_pp;
  EJ.wa1[0] = wa_pp1; EJ.wa2[0] = wa_pp2; EJ.hd1[0] = hd_pp1; EJ.hd2[0] = hd_pp2;
  EJ.EA[1] = ea_bb; EJ.We[1] = W_edge_bb; EJ.be[1] = b_edge_bb;
  EJ.wa1[1] = wa_bb1; EJ.wa2[1] = nullptr; EJ.hd1[1] = hd_bb1; EJ.hd2[1] = nullptr;
  EJ.EA[2] = ea_bp; EJ.We[2] = W_edge_bp; EJ.be[2] = b_edge_bp;
  EJ.wa1[2] = wa_bp1; EJ.wa2[2] = wa_bp2; EJ.hd1[2] = hd_bp1; EJ.hd2[2] = hd_bp2;
  edge_fused_kernel<<<3 * 512, B, 0, stream>>>(EJ, sacc);

  selfscale_kernel<<<1, 64, 0, stream>>>(sacc, invE, self_pp1, self_pp2, self_bb1);

  // ---- batched CSR build
  Dsts DS; DS.d[0] = ei_pp + En; DS.d[1] = ei_bp + En; DS.d[2] = ei_bb + En;
  zero_int_kernel<<<cdiv(NCAT, 256), B, 0, stream>>>(cnt_cat, NCAT);
  hist_all_kernel<<<cdiv(3 * En, 256), B, 0, stream>>>(DS, cnt_cat);
  scan1_kernel<<<NB_TOT, B, 0, stream>>>(cnt_cat, offs_cat, bsum, NCAT);
  scan2_kernel<<<1, 64, 0, stream>>>(bsum);
  scan3_kernel<<<NB_TOT, B, 0, stream>>>(cnt_cat, offs_cat, bsum, NCAT);
  copy_int_kernel<<<cdiv(NCAT, 256), B, 0, stream>>>(offs_cat, cnt_cat, NCAT);
  scatter_all_kernel<<<cdiv(3 * En, 256), B, 0, stream>>>(DS, cnt_cat, eidx_cat);

  const int* offs_pp = offs_cat + OFF_PP;
  const int* offs_bp = offs_cat + OFF_BP;
  const int* offs_bb = offs_cat + OFF_BB;
  const int* eidx_pp = eidx_cat;
  const int* eidx_bp = eidx_cat + En;
  const int* eidx_bb = eidx_cat + 2 * En;

  // ---- conv1 pp (homo) -> p1
  hgemm_kernel<<<cdiv(NPn, 256), B, 0, stream>>>(xp, c1_pp_W, c1_pp_asrc, c1_pp_adst, hbuf, s_src, s_dst, NPn);
  gat_row_kernel<<<cdiv(NPn * 64, 256), B, 0, stream>>>(offs_pp, eidx_pp, ei_pp, s_src, s_dst,
      hd_pp1, self_pp1, hbuf, c1_pp_bias, p1, NPn, 0);

  // ---- xb computed ONCE -> hbuf; conv1-bp H via b1v; conv1-bb in-place
  proj_kernel<<<cdiv(NBn, 256), B, 0, stream>>>(x_b, W_node_b, b_node_b, hbuf, NBn);

  // conv1 bp (b->p) -> p1 (+=), H in b1v
  hgemm_kernel<<<cdiv(NBn, 256), B, 0, stream>>>(hbuf, c1_bp_Wsrc, c1_bp_asrc, nullptr, b1v, s_src, nullptr, NBn);
  matvec_kernel<<<cdiv(NPn, 256), B, 0, stream>>>(xp, wd1, s_dst, NPn);
  gat_row_kernel<<<cdiv(NPn * 64, 256), B, 0, stream>>>(offs_bp, eidx_bp, ei_bp, s_src, s_dst,
      hd_bp1, nullptr, b1v, c1_bp_bias, p1, NPn, 1);

  // conv1 bb (homo) -> b1v (overwrites b1v after bp consumed it)
  hgemm_kernel<<<cdiv(NBn, 256), B, 0, stream>>>(hbuf, c1_bb_W, c1_bb_asrc, c1_bb_adst, hbuf, s_src, s_dst, NBn);
  gat_row_kernel<<<cdiv(NBn * 64, 256), B, 0, stream>>>(offs_bb, eidx_bb, ei_bb, s_src, s_dst,
      hd_bb1, self_bb1, hbuf, c1_bb_bias, b1v, NBn, 0);

  // ---- conv2 pp (homo, input p1) -> p2
  hgemm_kernel<<<cdiv(NPn, 256), B, 0, stream>>>(p1, c2_pp_W, c2_pp_asrc, c2_pp_adst, hbuf, s_src, s_dst, NPn);
  gat_row_kernel<<<cdiv(NPn * 64, 256), B, 0, stream>>>(offs_pp, eidx_pp, ei_pp, s_src, s_dst,
      hd_pp2, self_pp2, hbuf, c2_pp_bias, p2, NPn, 0);

  // ---- conv2 bp (src b1v) -> p2 (+=)
  hgemm_kernel<<<cdiv(NBn, 256), B, 0, stream>>>(b1v, c2_bp_Wsrc, c2_bp_asrc, nullptr, hbuf, s_src, nullptr, NBn);
  matvec_kernel<<<cdiv(NPn, 256), B, 0, stream>>>(p1, wd2, s_dst, NPn);
  gat_row_kernel<<<cdiv(NPn * 64, 256), B, 0, stream>>>(offs_bp, eidx_bp, ei_bp, s_src, s_dst,
      hd_bp2, nullptr, hbuf, c2_bp_bias, p2, NPn, 1);

  // ---- head
  head_kernel<<<cdiv(NPn, 256), B, 0, stream>>>(p2, W_out, b_out, (float*)d_out, NPn);
}

// Round 15
// 1800.161 us; speedup vs baseline: 1.4849x; 1.4849x over previous
//
#include <hip/hip_runtime.h>

// ---------------------------------------------------------------------------
// HeteroGNN (2-layer hetero GAT) forward on MI355X — round 15.
// Rounds 13/14 proved the lane-per-edge structure spills regardless of the
// column accumulator (2.9GB scratch traffic, >1ms). REVERT edge kernel to the
// round-12 proven column-parallel structure (307us, 58MB, no spill), keep the
// r13/14 proj(x_b) dedup (proven correct). This is best-known-config.
// ---------------------------------------------------------------------------

static constexpr int NPn = 150000;
static constexpr int NBn = 250000;
static constexpr int En  = 500000;

// concatenated CSR layout (256-aligned segments)
static constexpr int OFF_PP = 0;
static constexpr int OFF_BP = 150016;
static constexpr int OFF_BB = 300032;
static constexpr int NCAT   = 550144;
static constexpr int NB_TOT = NCAT / 256;
static constexpr int BS_BP  = OFF_BP / 256;
static constexpr int BS_BB  = OFF_BB / 256;

__device__ __forceinline__ float lrelu(float x, float s) { return x >= 0.0f ? x : s * x; }

__global__ void fill_kernel(float* out, float val, int n) {
  int i = blockIdx.x * blockDim.x + threadIdx.x;
  if (i < n) out[i] = val;
}

// ---------------- batched CSR build ----------------
struct Dsts { const int* d[3]; };

__global__ void zero_int_kernel(int* p, int n) {
  int i = blockIdx.x * blockDim.x + threadIdx.x;
  if (i < n) p[i] = 0;
}

__global__ void hist_all_kernel(Dsts ds, int* __restrict__ cnt) {
  int t = blockIdx.x * blockDim.x + threadIdx.x;
  if (t >= 3 * En) return;
  int rel = t / En, e = t - rel * En;
  int base = (rel == 0) ? OFF_PP : (rel == 1) ? OFF_BP : OFF_BB;
  atomicAdd(&cnt[base + ds.d[rel][e]], 1);
}

__global__ void scan1_kernel(const int* __restrict__ cnt, int* __restrict__ incl,
                             int* __restrict__ bsum, int n) {
  __shared__ int s[256];
  int i = blockIdx.x * 256 + threadIdx.x;
  s[threadIdx.x] = (i < n) ? cnt[i] : 0;
  __syncthreads();
  for (int o = 1; o < 256; o <<= 1) {
    int t = (threadIdx.x >= o) ? s[threadIdx.x - o] : 0;
    __syncthreads();
    s[threadIdx.x] += t;
    __syncthreads();
  }
  if (i < n) incl[i] = s[threadIdx.x];
  if (threadIdx.x == 255) bsum[blockIdx.x] = s[255];
}

__global__ void scan2_kernel(int* bsum) {
  int t = threadIdx.x;
  if (t >= 3) return;
  int lo = (t == 0) ? 0 : (t == 1) ? BS_BP : BS_BB;
  int hi = (t == 0) ? BS_BP : (t == 1) ? BS_BB : NB_TOT;
  int run = 0;
  for (int i = lo; i < hi; ++i) { int v = bsum[i]; bsum[i] = run; run += v; }
}

__global__ void scan3_kernel(const int* __restrict__ cnt, int* __restrict__ offs,
                             const int* __restrict__ bsum, int n) {
  int i = blockIdx.x * 256 + threadIdx.x;
  if (i < n) offs[i] = offs[i] - cnt[i] + bsum[i >> 8];
}

__global__ void copy_int_kernel(const int* __restrict__ src, int* __restrict__ dstp, int n) {
  int i = blockIdx.x * blockDim.x + threadIdx.x;
  if (i < n) dstp[i] = src[i];
}

__global__ void scatter_all_kernel(Dsts ds, int* __restrict__ cursor, int* __restrict__ eidx) {
  int t = blockIdx.x * blockDim.x + threadIdx.x;
  if (t >= 3 * En) return;
  int rel = t / En, e = t - rel * En;
  int base = (rel == 0) ? OFF_PP : (rel == 1) ? OFF_BP : OFF_BB;
  int p = atomicAdd(&cursor[base + ds.d[rel][e]], 1);
  eidx[rel * En + p] = e;
}

// ---------------- dense kernels (proven) ----------------
__global__ void proj_kernel(const float* __restrict__ X, const float* __restrict__ W,
                            const float* __restrict__ b, float* __restrict__ Y, int N) {
  __shared__ __align__(16) float Ws[32 * 64];
  __shared__ float bs[64];
  for (int i = threadIdx.x; i < 32 * 64; i += blockDim.x) Ws[i] = W[i];
  if (threadIdx.x < 64) bs[threadIdx.x] = b[threadIdx.x];
  __syncthreads();
  int row = blockIdx.x * blockDim.x + threadIdx.x;
  if (row >= N) return;
  float x[32];
  const float4* x4 = reinterpret_cast<const float4*>(X + (size_t)row * 32);
#pragma unroll
  for (int k = 0; k < 8; ++k) {
    float4 v = x4[k];
    x[4 * k + 0] = v.x; x[4 * k + 1] = v.y; x[4 * k + 2] = v.z; x[4 * k + 3] = v.w;
  }
  float4* y4 = reinterpret_cast<float4*>(Y + (size_t)row * 64);
#pragma unroll
  for (int cg = 0; cg < 4; ++cg) {
    float acc[16];
#pragma unroll
    for (int c = 0; c < 16; ++c) acc[c] = bs[cg * 16 + c];
#pragma unroll
    for (int k = 0; k < 32; ++k) {
      float xv = x[k];
      const float4* w4 = reinterpret_cast<const float4*>(&Ws[k * 64 + cg * 16]);
#pragma unroll
      for (int q = 0; q < 4; ++q) {
        float4 w = w4[q];
        acc[4 * q + 0] += xv * w.x; acc[4 * q + 1] += xv * w.y;
        acc[4 * q + 2] += xv * w.z; acc[4 * q + 3] += xv * w.w;
      }
    }
#pragma unroll
    for (int q = 0; q < 4; ++q)
      y4[cg * 4 + q] = make_float4(lrelu(acc[4 * q + 0], 0.01f), lrelu(acc[4 * q + 1], 0.01f),
                                   lrelu(acc[4 * q + 2], 0.01f), lrelu(acc[4 * q + 3], 0.01f));
  }
}

// H = X @ W; S1=H.a1; optional S2. X/H may alias (row-private).
__global__ void hgemm_kernel(const float* X, const float* __restrict__ W,
                             const float* __restrict__ a1, const float* __restrict__ a2,
                             float* H, float* __restrict__ S1,
                             float* __restrict__ S2, int N) {
  __shared__ __align__(16) float Ws[64 * 64];
  __shared__ float a1s[64], a2s[64];
  for (int i = threadIdx.x; i < 64 * 64; i += blockDim.x) Ws[i] = W[i];
  if (threadIdx.x < 64) {
    a1s[threadIdx.x] = a1[threadIdx.x];
    a2s[threadIdx.x] = a2 ? a2[threadIdx.x] : 0.0f;
  }
  __syncthreads();
  int row = blockIdx.x * blockDim.x + threadIdx.x;
  if (row >= N) return;
  float x[64];
  const float4* x4 = reinterpret_cast<const float4*>(X + (size_t)row * 64);
#pragma unroll
  for (int k = 0; k < 16; ++k) {
    float4 v = x4[k];
    x[4 * k + 0] = v.x; x[4 * k + 1] = v.y; x[4 * k + 2] = v.z; x[4 * k + 3] = v.w;
  }
  float4* h4 = reinterpret_cast<float4*>(H + (size_t)row * 64);
  float s1 = 0.0f, s2 = 0.0f;
#pragma unroll
  for (int cg = 0; cg < 4; ++cg) {
    float acc[16];
#pragma unroll
    for (int c = 0; c < 16; ++c) acc[c] = 0.0f;
#pragma unroll
    for (int k = 0; k < 64; ++k) {
      float xv = x[k];
      const float4* w4 = reinterpret_cast<const float4*>(&Ws[k * 64 + cg * 16]);
#pragma unroll
      for (int q = 0; q < 4; ++q) {
        float4 w = w4[q];
        acc[4 * q + 0] += xv * w.x; acc[4 * q + 1] += xv * w.y;
        acc[4 * q + 2] += xv * w.z; acc[4 * q + 3] += xv * w.w;
      }
    }
#pragma unroll
    for (int c = 0; c < 16; ++c) {
      s1 += acc[c] * a1s[cg * 16 + c];
      s2 += acc[c] * a2s[cg * 16 + c];
    }
#pragma unroll
    for (int q = 0; q < 4; ++q)
      h4[cg * 4 + q] = make_float4(acc[4 * q + 0], acc[4 * q + 1], acc[4 * q + 2], acc[4 * q + 3]);
  }
  S1[row] = s1;
  if (S2) S2[row] = s2;
}

__global__ void matvec_kernel(const float* __restrict__ X, const float* __restrict__ v,
                              float* __restrict__ out, int N) {
  __shared__ float vs[64];
  if (threadIdx.x < 64) vs[threadIdx.x] = v[threadIdx.x];
  __syncthreads();
  int i = blockIdx.x * blockDim.x + threadIdx.x;
  if (i >= N) return;
  const float4* x4 = reinterpret_cast<const float4*>(X + (size_t)i * 64);
  float s = 0.0f;
#pragma unroll
  for (int k = 0; k < 16; ++k) {
    float4 u = x4[k];
    s += u.x * vs[4 * k + 0] + u.y * vs[4 * k + 1] + u.z * vs[4 * k + 2] + u.w * vs[4 * k + 3];
  }
  out[i] = s;
}

__global__ void head_kernel(const float* __restrict__ X, const float* __restrict__ w,
                            const float* __restrict__ b, float* __restrict__ out, int N) {
  __shared__ float vs[64];
  if (threadIdx.x < 64) vs[threadIdx.x] = w[threadIdx.x];
  __syncthreads();
  int i = blockIdx.x * blockDim.x + threadIdx.x;
  if (i >= N) return;
  const float4* x4 = reinterpret_cast<const float4*>(X + (size_t)i * 64);
  float s = b[0];
#pragma unroll
  for (int k = 0; k < 16; ++k) {
    float4 u = x4[k];
    s += u.x * vs[4 * k + 0] + u.y * vs[4 * k + 1] + u.z * vs[4 * k + 2] + u.w * vs[4 * k + 3];
  }
  out[i] = s;
}

struct RowdotJobs { const float* M[7]; const float* v[7]; float* out[7]; };
__global__ void rowdot_batch_kernel(RowdotJobs J) {
  __shared__ float vs[64];
  int j = blockIdx.x;
  vs[threadIdx.x] = J.v[j][threadIdx.x];
  __syncthreads();
  float s = 0.0f;
  const float* M = J.M[j];
#pragma unroll
  for (int c = 0; c < 64; ++c) s += M[threadIdx.x * 64 + c] * vs[c];
  J.out[j][threadIdx.x] = s;
}

// ---------------- column-parallel fused edge kernel (round-12 proven) --------
// hd1[e] = lrelu(ea@We+be)·wa1 (hd2 with wa2) + column sums of lrelu for the
// self-loop mean. 512 blocks/relation, 64-edge LDS tiles; lanes = columns
// (conflict-free), per-edge 64-lane shuffle reduce. Measured: 307us, no spill.
struct EdgeJobs {
  const float* EA[3]; const float* We[3]; const float* be[3];
  const float* wa1[3]; const float* wa2[3]; float* hd1[3]; float* hd2[3];
};
__global__ void edge_fused_kernel(EdgeJobs J, float* __restrict__ sum_pp,
                                  float* __restrict__ sum_bb) {
  int rel = blockIdx.x >> 9;          // 512 blocks per relation
  int blk = blockIdx.x & 511;
  __shared__ float Ws[16 * 64];
  __shared__ float bs[64], w1s[64], w2s[64];
  __shared__ float eas[64 * 16];
  __shared__ float partial[256];
  const float* We = J.We[rel];
  for (int i = threadIdx.x; i < 16 * 64; i += blockDim.x) Ws[i] = We[i];
  bool has2 = (J.wa2[rel] != nullptr);
  if (threadIdx.x < 64) {
    bs[threadIdx.x] = J.be[rel][threadIdx.x];
    w1s[threadIdx.x] = J.wa1[rel][threadIdx.x];
    w2s[threadIdx.x] = has2 ? J.wa2[rel][threadIdx.x] : 0.0f;
  }
  const float* EA = J.EA[rel];
  float* hd1 = J.hd1[rel];
  float* hd2 = J.hd2[rel];
  int col = threadIdx.x & 63, q = threadIdx.x >> 6;
  float macc = 0.0f;
  for (int base = blk * 64; base < En; base += 512 * 64) {
    int tile = min(64, En - base);
    __syncthreads();
    for (int i = threadIdx.x; i < tile * 16; i += blockDim.x)
      eas[i] = EA[(size_t)base * 16 + i];
    __syncthreads();
    for (int e = q; e < tile; e += 4) {
      float t = bs[col];
#pragma unroll
      for (int k = 0; k < 16; ++k) t += eas[e * 16 + k] * Ws[k * 64 + col];
      float lr = lrelu(t, 0.01f);
      macc += lr;
      float d1 = lr * w1s[col];
      float d2 = has2 ? lr * w2s[col] : 0.0f;
#pragma unroll
      for (int o = 32; o >= 1; o >>= 1) {
        d1 += __shfl_xor(d1, o, 64);
        d2 += __shfl_xor(d2, o, 64);
      }
      if (col == 0) {
        hd1[base + e] = d1;
        if (has2) hd2[base + e] = d2;
      }
    }
  }
  if (rel < 2) {
    partial[threadIdx.x] = macc;
    __syncthreads();
    if (q == 0) {
      float s = partial[col] + partial[64 + col] + partial[128 + col] + partial[192 + col];
      atomicAdd(rel == 0 ? &sum_pp[col] : &sum_bb[col], s);
    }
  }
}

struct SelfJobs { const float* sum[3]; const float* wa[3]; float* out[3]; };
__global__ void selfdot_batch_kernel(SelfJobs J, float invE) {
  int job = threadIdx.x >> 6, lane = threadIdx.x & 63;
  float v = J.sum[job][lane] * J.wa[job][lane] * invE;
#pragma unroll
  for (int o = 32; o >= 1; o >>= 1) v += __shfl_down(v, o, 64);
  if (lane == 0) J.out[job][0] = v;
}

// ---------------- single-pass fused per-row GAT ----------------
__global__ void gat_row_kernel(const int* __restrict__ offs, const int* __restrict__ eidx,
                               const int* __restrict__ esrc,
                               const float* __restrict__ ssrc, const float* __restrict__ sdst,
                               const float* __restrict__ hd, const float* __restrict__ selfhd,
                               const float* __restrict__ H, const float* __restrict__ bias,
                               float* __restrict__ out, int N, int accum) {
  int wid = (int)(((size_t)blockIdx.x * blockDim.x + threadIdx.x) >> 6);
  int lane = threadIdx.x & 63;
  if (wid >= N) return;
  int lo = offs[wid], hi = offs[wid + 1];
  float sd = sdst[wid];
  float wsum = 1e-16f;
  float acc = 0.0f;
  if (selfhd) {
    float wself = __expf(lrelu(ssrc[wid] + sd + selfhd[0], 0.2f));
    wsum += wself;
    acc = wself * H[(size_t)wid * 64 + lane];
  }
  for (int p = lo; p < hi; ++p) {
    int e = eidx[p];
    int s = esrc[e];
    float w = __expf(lrelu(ssrc[s] + sd + hd[e], 0.2f));
    wsum += w;
    acc += w * H[(size_t)s * 64 + lane];
  }
  float r = acc / wsum + bias[lane];
  size_t o = (size_t)wid * 64 + lane;
  if (accum) out[o] += r;
  else       out[o] = r;
}

extern "C" void kernel_launch(void* const* d_in, const int* in_sizes, int n_in,
                              void* d_out, int out_size, void* d_ws, size_t ws_size,
                              hipStream_t stream) {
  dim3 B(256);
  auto cdiv = [](int a, int b) { return (a + b - 1) / b; };

  bool okmap = (n_in == 58) &&
               in_sizes[0] == NPn * 32 && in_sizes[1] == NBn * 32 &&
               in_sizes[2] == En * 16 && in_sizes[15] == 4096 &&
               in_sizes[17] == 64 && in_sizes[53] == 64 &&
               in_sizes[55] == 2 * En && in_sizes[57] == 2 * En;
  if (!okmap) {
    fill_kernel<<<cdiv(NPn, 256), B, 0, stream>>>((float*)d_out, 1000.0f, NPn);
    return;
  }

  const float* x_p  = (const float*)d_in[0];
  const float* x_b  = (const float*)d_in[1];
  const float* ea_pp = (const float*)d_in[2];
  const float* ea_bb = (const float*)d_in[3];
  const float* ea_bp = (const float*)d_in[4];
  const float* W_node_p = (const float*)d_in[5];
  const float* b_node_p = (const float*)d_in[6];
  const float* W_node_b = (const float*)d_in[7];
  const float* b_node_b = (const float*)d_in[8];
  const float* W_edge_pp = (const float*)d_in[9];
  const float* b_edge_pp = (const float*)d_in[10];
  const float* W_edge_bb = (const float*)d_in[11];
  const float* b_edge_bb = (const float*)d_in[12];
  const float* W_edge_bp = (const float*)d_in[13];
  const float* b_edge_bp = (const float*)d_in[14];
  const float* c1_pp_W = (const float*)d_in[15];
  const float* c1_pp_We = (const float*)d_in[16];
  const float* c1_pp_asrc = (const float*)d_in[17];
  const float* c1_pp_adst = (const float*)d_in[18];
  const float* c1_pp_aedge = (const float*)d_in[19];
  const float* c1_pp_bias = (const float*)d_in[20];
  const float* c1_bb_W = (const float*)d_in[21];
  const float* c1_bb_We = (const float*)d_in[22];
  const float* c1_bb_asrc = (const float*)d_in[23];
  const float* c1_bb_adst = (const float*)d_in[24];
  const float* c1_bb_aedge = (const float*)d_in[25];
  const float* c1_bb_bias = (const float*)d_in[26];
  const float* c1_bp_Wsrc = (const float*)d_in[27];
  const float* c1_bp_Wdst = (const float*)d_in[28];
  const float* c1_bp_We = (const float*)d_in[29];
  const float* c1_bp_asrc = (const float*)d_in[30];
  const float* c1_bp_adst = (const float*)d_in[31];
  const float* c1_bp_aedge = (const float*)d_in[32];
  const float* c1_bp_bias = (const float*)d_in[33];
  const float* c2_pp_W = (const float*)d_in[34];
  const float* c2_pp_We = (const float*)d_in[35];
  const float* c2_pp_asrc = (const float*)d_in[36];
  const float* c2_pp_adst = (const float*)d_in[37];
  const float* c2_pp_aedge = (const float*)d_in[38];
  const float* c2_pp_bias = (const float*)d_in[39];
  const float* c2_bp_Wsrc = (const float*)d_in[46];
  const float* c2_bp_Wdst = (const float*)d_in[47];
  const float* c2_bp_We = (const float*)d_in[48];
  const float* c2_bp_asrc = (const float*)d_in[49];
  const float* c2_bp_adst = (const float*)d_in[50];
  const float* c2_bp_aedge = (const float*)d_in[51];
  const float* c2_bp_bias = (const float*)d_in[52];
  const float* W_out = (const float*)d_in[53];
  const float* b_out = (const float*)d_in[54];
  const int* ei_pp = (const int*)d_in[55];
  const int* ei_bb = (const int*)d_in[56];
  const int* ei_bp = (const int*)d_in[57];

  // ---- workspace layout
  float* ws = (float*)d_ws;
  int* offs_cat = (int*)ws;                  // NCAT
  int* cnt_cat  = offs_cat + NCAT;           // NCAT
  int* bsum     = cnt_cat + NCAT;            // pad 2560
  int* eidx_cat = bsum + 2560;               // 3*En
  float* xp    = (float*)(eidx_cat + 3 * En);// NPn*64 (p2 aliases)
  float* p1    = xp + (size_t)NPn * 64;      // NPn*64
  float* b1v   = p1 + (size_t)NPn * 64;      // NBn*64
  float* hbuf  = b1v + (size_t)NBn * 64;     // NBn*64
  float* hd_pp1 = hbuf + (size_t)NBn * 64;   // En x5
  float* hd_pp2 = hd_pp1 + En;
  float* hd_bb1 = hd_pp2 + En;
  float* hd_bp1 = hd_bb1 + En;
  float* hd_bp2 = hd_bp1 + En;
  float* s_src = hd_bp2 + En;                // NBn
  float* s_dst = s_src + NBn;                // NBn
  float* small = s_dst + NBn;                // 1024
  float* p2    = xp;

  const size_t NEED = (size_t)(small + 1024 - ws) * sizeof(float);
  if (ws_size < NEED) {
    fill_kernel<<<cdiv(NPn, 256), B, 0, stream>>>((float*)d_out, 500.0f, NPn);
    return;
  }

  float* sum_pp  = small + 0;   float* sum_bb  = small + 64;
  float* wa_pp1  = small + 128; float* wa_pp2  = small + 192;
  float* wa_bb1  = small + 256; float* wa_bp1  = small + 320; float* wa_bp2 = small + 384;
  float* wd1     = small + 448; float* wd2     = small + 512;
  float* self_pp1= small + 576; float* self_pp2= small + 577; float* self_bb1 = small + 578;
  const float invE = 1.0f / (float)En;

  hipMemsetAsync(sum_pp, 0, 128 * sizeof(float), stream);

  // ---- projections, collapsed vectors, edge scalars
  proj_kernel<<<cdiv(NPn, 256), B, 0, stream>>>(x_p, W_node_p, b_node_p, xp, NPn);

  RowdotJobs RJ;
  RJ.M[0] = c1_pp_We;  RJ.v[0] = c1_pp_aedge; RJ.out[0] = wa_pp1;
  RJ.M[1] = c2_pp_We;  RJ.v[1] = c2_pp_aedge; RJ.out[1] = wa_pp2;
  RJ.M[2] = c1_bb_We;  RJ.v[2] = c1_bb_aedge; RJ.out[2] = wa_bb1;
  RJ.M[3] = c1_bp_We;  RJ.v[3] = c1_bp_aedge; RJ.out[3] = wa_bp1;
  RJ.M[4] = c2_bp_We;  RJ.v[4] = c2_bp_aedge; RJ.out[4] = wa_bp2;
  RJ.M[5] = c1_bp_Wdst; RJ.v[5] = c1_bp_adst; RJ.out[5] = wd1;
  RJ.M[6] = c2_bp_Wdst; RJ.v[6] = c2_bp_adst; RJ.out[6] = wd2;
  rowdot_batch_kernel<<<7, 64, 0, stream>>>(RJ);

  EdgeJobs EJ;
  EJ.EA[0] = ea_pp; EJ.We[0] = W_edge_pp; EJ.be[0] = b_edge_pp;
  EJ.wa1[0] = wa_pp1; EJ.wa2[0] = wa_pp2; EJ.hd1[0] = hd_pp1; EJ.hd2[0] = hd_pp2;
  EJ.EA[1] = ea_bb; EJ.We[1] = W_edge_bb; EJ.be[1] = b_edge_bb;
  EJ.wa1[1] = wa_bb1; EJ.wa2[1] = nullptr; EJ.hd1[1] = hd_bb1; EJ.hd2[1] = nullptr;
  EJ.EA[2] = ea_bp; EJ.We[2] = W_edge_bp; EJ.be[2] = b_edge_bp;
  EJ.wa1[2] = wa_bp1; EJ.wa2[2] = wa_bp2; EJ.hd1[2] = hd_bp1; EJ.hd2[2] = hd_bp2;
  edge_fused_kernel<<<3 * 512, B, 0, stream>>>(EJ, sum_pp, sum_bb);

  SelfJobs SJ;
  SJ.sum[0] = sum_pp; SJ.wa[0] = wa_pp1; SJ.out[0] = self_pp1;
  SJ.sum[1] = sum_pp; SJ.wa[1] = wa_pp2; SJ.out[1] = self_pp2;
  SJ.sum[2] = sum_bb; SJ.wa[2] = wa_bb1; SJ.out[2] = self_bb1;
  selfdot_batch_kernel<<<1, 192, 0, stream>>>(SJ, invE);

  // ---- batched CSR build
  Dsts DS; DS.d[0] = ei_pp + En; DS.d[1] = ei_bp + En; DS.d[2] = ei_bb + En;
  zero_int_kernel<<<cdiv(NCAT, 256), B, 0, stream>>>(cnt_cat, NCAT);
  hist_all_kernel<<<cdiv(3 * En, 256), B, 0, stream>>>(DS, cnt_cat);
  scan1_kernel<<<NB_TOT, B, 0, stream>>>(cnt_cat, offs_cat, bsum, NCAT);
  scan2_kernel<<<1, 64, 0, stream>>>(bsum);
  scan3_kernel<<<NB_TOT, B, 0, stream>>>(cnt_cat, offs_cat, bsum, NCAT);
  copy_int_kernel<<<cdiv(NCAT, 256), B, 0, stream>>>(offs_cat, cnt_cat, NCAT);
  scatter_all_kernel<<<cdiv(3 * En, 256), B, 0, stream>>>(DS, cnt_cat, eidx_cat);

  const int* offs_pp = offs_cat + OFF_PP;
  const int* offs_bp = offs_cat + OFF_BP;
  const int* offs_bb = offs_cat + OFF_BB;
  const int* eidx_pp = eidx_cat;
  const int* eidx_bp = eidx_cat + En;
  const int* eidx_bb = eidx_cat + 2 * En;

  // ---- conv1 pp (homo) -> p1
  hgemm_kernel<<<cdiv(NPn, 256), B, 0, stream>>>(xp, c1_pp_W, c1_pp_asrc, c1_pp_adst, hbuf, s_src, s_dst, NPn);
  gat_row_kernel<<<cdiv(NPn * 64, 256), B, 0, stream>>>(offs_pp, eidx_pp, ei_pp, s_src, s_dst,
      hd_pp1, self_pp1, hbuf, c1_pp_bias, p1, NPn, 0);

  // ---- xb computed ONCE -> hbuf; conv1-bp H via b1v; conv1-bb in-place
  proj_kernel<<<cdiv(NBn, 256), B, 0, stream>>>(x_b, W_node_b, b_node_b, hbuf, NBn);

  // conv1 bp (b->p) -> p1 (+=), H in b1v
  hgemm_kernel<<<cdiv(NBn, 256), B, 0, stream>>>(hbuf, c1_bp_Wsrc, c1_bp_asrc, nullptr, b1v, s_src, nullptr, NBn);
  matvec_kernel<<<cdiv(NPn, 256), B, 0, stream>>>(xp, wd1, s_dst, NPn);
  gat_row_kernel<<<cdiv(NPn * 64, 256), B, 0, stream>>>(offs_bp, eidx_bp, ei_bp, s_src, s_dst,
      hd_bp1, nullptr, b1v, c1_bp_bias, p1, NPn, 1);

  // conv1 bb (homo) -> b1v (overwrites b1v after bp consumed it)
  hgemm_kernel<<<cdiv(NBn, 256), B, 0, stream>>>(hbuf, c1_bb_W, c1_bb_asrc, c1_bb_adst, hbuf, s_src, s_dst, NBn);
  gat_row_kernel<<<cdiv(NBn * 64, 256), B, 0, stream>>>(offs_bb, eidx_bb, ei_bb, s_src, s_dst,
      hd_bb1, self_bb1, hbuf, c1_bb_bias, b1v, NBn, 0);

  // ---- conv2 pp (homo, input p1) -> p2
  hgemm_kernel<<<cdiv(NPn, 256), B, 0, stream>>>(p1, c2_pp_W, c2_pp_asrc, c2_pp_adst, hbuf, s_src, s_dst, NPn);
  gat_row_kernel<<<cdiv(NPn * 64, 256), B, 0, stream>>>(offs_pp, eidx_pp, ei_pp, s_src, s_dst,
      hd_pp2, self_pp2, hbuf, c2_pp_bias, p2, NPn, 0);

  // ---- conv2 bp (src b1v) -> p2 (+=)
  hgemm_kernel<<<cdiv(NBn, 256), B, 0, stream>>>(b1v, c2_bp_Wsrc, c2_bp_asrc, nullptr, hbuf, s_src, nullptr, NBn);
  matvec_kernel<<<cdiv(NPn, 256), B, 0, stream>>>(p1, wd2, s_dst, NPn);
  gat_row_kernel<<<cdiv(NPn * 64, 256), B, 0, stream>>>(offs_bp, eidx_bp, ei_bp, s_src, s_dst,
      hd_bp2, nullptr, hbuf, c2_bp_bias, p2, NPn, 1);

  // ---- head
  head_kernel<<<cdiv(NPn, 256), B, 0, stream>>>(p2, W_out, b_out, (float*)d_out, NPn);
}

// Round 16
// 1713.444 us; speedup vs baseline: 1.5600x; 1.0506x over previous
//
#include <hip/hip_runtime.h>

// ---------------------------------------------------------------------------
// HeteroGNN (2-layer hetero GAT) forward on MI355X — round 16.
// vs round 15 (passed, 1800us): (1) edge_fused keeps the proven column-
// parallel structure but holds W/b/wa columns in REGISTERS (wreg[16]) —
// halves DS-pipe ops/edge; (2) edge data stored in CSR order (scatter emits
// srcs_csr + pos; edge_fused writes hd at pos[e]) so gat_row's inner loop is
// all-contiguous except the H gather. CSR build moved before edge_fused.
// ---------------------------------------------------------------------------

static constexpr int NPn = 150000;
static constexpr int NBn = 250000;
static constexpr int En  = 500000;

// concatenated CSR layout (256-aligned segments); relation order: pp, bp, bb
static constexpr int OFF_PP = 0;
static constexpr int OFF_BP = 150016;
static constexpr int OFF_BB = 300032;
static constexpr int NCAT   = 550144;
static constexpr int NB_TOT = NCAT / 256;
static constexpr int BS_BP  = OFF_BP / 256;
static constexpr int BS_BB  = OFF_BB / 256;

__device__ __forceinline__ float lrelu(float x, float s) { return x >= 0.0f ? x : s * x; }

__global__ void fill_kernel(float* out, float val, int n) {
  int i = blockIdx.x * blockDim.x + threadIdx.x;
  if (i < n) out[i] = val;
}

// ---------------- batched CSR build ----------------
struct Dsts { const int* d[3]; const int* s[3]; };

__global__ void zero_int_kernel(int* p, int n) {
  int i = blockIdx.x * blockDim.x + threadIdx.x;
  if (i < n) p[i] = 0;
}

__global__ void hist_all_kernel(Dsts ds, int* __restrict__ cnt) {
  int t = blockIdx.x * blockDim.x + threadIdx.x;
  if (t >= 3 * En) return;
  int rel = t / En, e = t - rel * En;
  int base = (rel == 0) ? OFF_PP : (rel == 1) ? OFF_BP : OFF_BB;
  atomicAdd(&cnt[base + ds.d[rel][e]], 1);
}

__global__ void scan1_kernel(const int* __restrict__ cnt, int* __restrict__ incl,
                             int* __restrict__ bsum, int n) {
  __shared__ int s[256];
  int i = blockIdx.x * 256 + threadIdx.x;
  s[threadIdx.x] = (i < n) ? cnt[i] : 0;
  __syncthreads();
  for (int o = 1; o < 256; o <<= 1) {
    int t = (threadIdx.x >= o) ? s[threadIdx.x - o] : 0;
    __syncthreads();
    s[threadIdx.x] += t;
    __syncthreads();
  }
  if (i < n) incl[i] = s[threadIdx.x];
  if (threadIdx.x == 255) bsum[blockIdx.x] = s[255];
}

__global__ void scan2_kernel(int* bsum) {
  int t = threadIdx.x;
  if (t >= 3) return;
  int lo = (t == 0) ? 0 : (t == 1) ? BS_BP : BS_BB;
  int hi = (t == 0) ? BS_BP : (t == 1) ? BS_BB : NB_TOT;
  int run = 0;
  for (int i = lo; i < hi; ++i) { int v = bsum[i]; bsum[i] = run; run += v; }
}

__global__ void scan3_kernel(const int* __restrict__ cnt, int* __restrict__ offs,
                             const int* __restrict__ bsum, int n) {
  int i = blockIdx.x * 256 + threadIdx.x;
  if (i < n) offs[i] = offs[i] - cnt[i] + bsum[i >> 8];
}

__global__ void copy_int_kernel(const int* __restrict__ src, int* __restrict__ dstp, int n) {
  int i = blockIdx.x * blockDim.x + threadIdx.x;
  if (i < n) dstp[i] = src[i];
}

// emits CSR-ordered src list + edge->CSR-position map (eidx itself not needed)
__global__ void scatter_all_kernel(Dsts ds, int* __restrict__ cursor,
                                   int* __restrict__ srcs, int* __restrict__ pos) {
  int t = blockIdx.x * blockDim.x + threadIdx.x;
  if (t >= 3 * En) return;
  int rel = t / En, e = t - rel * En;
  int base = (rel == 0) ? OFF_PP : (rel == 1) ? OFF_BP : OFF_BB;
  int p = atomicAdd(&cursor[base + ds.d[rel][e]], 1);
  srcs[rel * En + p] = ds.s[rel][e];
  pos[rel * En + e] = p;
}

// ---------------- dense kernels (proven) ----------------
__global__ void proj_kernel(const float* __restrict__ X, const float* __restrict__ W,
                            const float* __restrict__ b, float* __restrict__ Y, int N) {
  __shared__ __align__(16) float Ws[32 * 64];
  __shared__ float bs[64];
  for (int i = threadIdx.x; i < 32 * 64; i += blockDim.x) Ws[i] = W[i];
  if (threadIdx.x < 64) bs[threadIdx.x] = b[threadIdx.x];
  __syncthreads();
  int row = blockIdx.x * blockDim.x + threadIdx.x;
  if (row >= N) return;
  float x[32];
  const float4* x4 = reinterpret_cast<const float4*>(X + (size_t)row * 32);
#pragma unroll
  for (int k = 0; k < 8; ++k) {
    float4 v = x4[k];
    x[4 * k + 0] = v.x; x[4 * k + 1] = v.y; x[4 * k + 2] = v.z; x[4 * k + 3] = v.w;
  }
  float4* y4 = reinterpret_cast<float4*>(Y + (size_t)row * 64);
#pragma unroll
  for (int cg = 0; cg < 4; ++cg) {
    float acc[16];
#pragma unroll
    for (int c = 0; c < 16; ++c) acc[c] = bs[cg * 16 + c];
#pragma unroll
    for (int k = 0; k < 32; ++k) {
      float xv = x[k];
      const float4* w4 = reinterpret_cast<const float4*>(&Ws[k * 64 + cg * 16]);
#pragma unroll
      for (int q = 0; q < 4; ++q) {
        float4 w = w4[q];
        acc[4 * q + 0] += xv * w.x; acc[4 * q + 1] += xv * w.y;
        acc[4 * q + 2] += xv * w.z; acc[4 * q + 3] += xv * w.w;
      }
    }
#pragma unroll
    for (int q = 0; q < 4; ++q)
      y4[cg * 4 + q] = make_float4(lrelu(acc[4 * q + 0], 0.01f), lrelu(acc[4 * q + 1], 0.01f),
                                   lrelu(acc[4 * q + 2], 0.01f), lrelu(acc[4 * q + 3], 0.01f));
  }
}

// H = X @ W; S1=H.a1; optional S2. X/H may alias (row-private).
__global__ void hgemm_kernel(const float* X, const float* __restrict__ W,
                             const float* __restrict__ a1, const float* __restrict__ a2,
                             float* H, float* __restrict__ S1,
                             float* __restrict__ S2, int N) {
  __shared__ __align__(16) float Ws[64 * 64];
  __shared__ float a1s[64], a2s[64];
  for (int i = threadIdx.x; i < 64 * 64; i += blockDim.x) Ws[i] = W[i];
  if (threadIdx.x < 64) {
    a1s[threadIdx.x] = a1[threadIdx.x];
    a2s[threadIdx.x] = a2 ? a2[threadIdx.x] : 0.0f;
  }
  __syncthreads();
  int row = blockIdx.x * blockDim.x + threadIdx.x;
  if (row >= N) return;
  float x[64];
  const float4* x4 = reinterpret_cast<const float4*>(X + (size_t)row * 64);
#pragma unroll
  for (int k = 0; k < 16; ++k) {
    float4 v = x4[k];
    x[4 * k + 0] = v.x; x[4 * k + 1] = v.y; x[4 * k + 2] = v.z; x[4 * k + 3] = v.w;
  }
  float4* h4 = reinterpret_cast<float4*>(H + (size_t)row * 64);
  float s1 = 0.0f, s2 = 0.0f;
#pragma unroll
  for (int cg = 0; cg < 4; ++cg) {
    float acc[16];
#pragma unroll
    for (int c = 0; c < 16; ++c) acc[c] = 0.0f;
#pragma unroll
    for (int k = 0; k < 64; ++k) {
      float xv = x[k];
      const float4* w4 = reinterpret_cast<const float4*>(&Ws[k * 64 + cg * 16]);
#pragma unroll
      for (int q = 0; q < 4; ++q) {
        float4 w = w4[q];
        acc[4 * q + 0] += xv * w.x; acc[4 * q + 1] += xv * w.y;
        acc[4 * q + 2] += xv * w.z; acc[4 * q + 3] += xv * w.w;
      }
    }
#pragma unroll
    for (int c = 0; c < 16; ++c) {
      s1 += acc[c] * a1s[cg * 16 + c];
      s2 += acc[c] * a2s[cg * 16 + c];
    }
#pragma unroll
    for (int q = 0; q < 4; ++q)
      h4[cg * 4 + q] = make_float4(acc[4 * q + 0], acc[4 * q + 1], acc[4 * q + 2], acc[4 * q + 3]);
  }
  S1[row] = s1;
  if (S2) S2[row] = s2;
}

__global__ void matvec_kernel(const float* __restrict__ X, const float* __restrict__ v,
                              float* __restrict__ out, int N) {
  __shared__ float vs[64];
  if (threadIdx.x < 64) vs[threadIdx.x] = v[threadIdx.x];
  __syncthreads();
  int i = blockIdx.x * blockDim.x + threadIdx.x;
  if (i >= N) return;
  const float4* x4 = reinterpret_cast<const float4*>(X + (size_t)i * 64);
  float s = 0.0f;
#pragma unroll
  for (int k = 0; k < 16; ++k) {
    float4 u = x4[k];
    s += u.x * vs[4 * k + 0] + u.y * vs[4 * k + 1] + u.z * vs[4 * k + 2] + u.w * vs[4 * k + 3];
  }
  out[i] = s;
}

__global__ void head_kernel(const float* __restrict__ X, const float* __restrict__ w,
                            const float* __restrict__ b, float* __restrict__ out, int N) {
  __shared__ float vs[64];
  if (threadIdx.x < 64) vs[threadIdx.x] = w[threadIdx.x];
  __syncthreads();
  int i = blockIdx.x * blockDim.x + threadIdx.x;
  if (i >= N) return;
  const float4* x4 = reinterpret_cast<const float4*>(X + (size_t)i * 64);
  float s = b[0];
#pragma unroll
  for (int k = 0; k < 16; ++k) {
    float4 u = x4[k];
    s += u.x * vs[4 * k + 0] + u.y * vs[4 * k + 1] + u.z * vs[4 * k + 2] + u.w * vs[4 * k + 3];
  }
  out[i] = s;
}

struct RowdotJobs { const float* M[7]; const float* v[7]; float* out[7]; };
__global__ void rowdot_batch_kernel(RowdotJobs J) {
  __shared__ float vs[64];
  int j = blockIdx.x;
  vs[threadIdx.x] = J.v[j][threadIdx.x];
  __syncthreads();
  float s = 0.0f;
  const float* M = J.M[j];
#pragma unroll
  for (int c = 0; c < 64; ++c) s += M[threadIdx.x * 64 + c] * vs[c];
  J.out[j][threadIdx.x] = s;
}

// ---------------- column-parallel fused edge kernel, W in registers ----------
// Structure identical to the proven round-12/15 kernel, but each lane holds its
// column of We/be/wa1/wa2 in registers (wreg[16]+3) — LDS keeps only the edge
// tile. hd written in CSR order via pos[e]. Column sums -> sum_pp/sum_bb.
struct EdgeJobs {
  const float* EA[3]; const float* We[3]; const float* be[3];
  const float* wa1[3]; const float* wa2[3]; float* hd1[3]; float* hd2[3];
  const int* pos[3];
};
__global__ void edge_fused_kernel(EdgeJobs J, float* __restrict__ sum_pp,
                                  float* __restrict__ sum_bb) {
  int rel = blockIdx.x >> 9;          // 512 blocks per relation
  int blk = blockIdx.x & 511;
  __shared__ float eas[64 * 16];
  __shared__ float partial[256];
  bool has2 = (J.wa2[rel] != nullptr);
  int col = threadIdx.x & 63, q = threadIdx.x >> 6;
  float wreg[16];
  const float* We = J.We[rel];
#pragma unroll
  for (int k = 0; k < 16; ++k) wreg[k] = We[k * 64 + col];
  float bcol = J.be[rel][col];
  float w1c = J.wa1[rel][col];
  float w2c = has2 ? J.wa2[rel][col] : 0.0f;
  const float* EA = J.EA[rel];
  float* hd1 = J.hd1[rel];
  float* hd2 = J.hd2[rel];
  const int* pos = J.pos[rel];
  float macc = 0.0f;
  for (int base = blk * 64; base < En; base += 512 * 64) {
    int tile = min(64, En - base);
    __syncthreads();
    for (int i = threadIdx.x; i < tile * 16; i += blockDim.x)
      eas[i] = EA[(size_t)base * 16 + i];
    __syncthreads();
    for (int e = q; e < tile; e += 4) {
      float t = bcol;
#pragma unroll
      for (int k = 0; k < 16; ++k) t += eas[e * 16 + k] * wreg[k];
      float lr = lrelu(t, 0.01f);
      macc += lr;
      float d1 = lr * w1c;
      float d2 = has2 ? lr * w2c : 0.0f;
#pragma unroll
      for (int o = 32; o >= 1; o >>= 1) {
        d1 += __shfl_xor(d1, o, 64);
        d2 += __shfl_xor(d2, o, 64);
      }
      if (col == 0) {
        int p = pos[base + e];
        hd1[p] = d1;
        if (has2) hd2[p] = d2;
      }
    }
  }
  if (rel < 2) {
    partial[threadIdx.x] = macc;
    __syncthreads();
    if (q == 0) {
      float s = partial[col] + partial[64 + col] + partial[128 + col] + partial[192 + col];
      atomicAdd(rel == 0 ? &sum_pp[col] : &sum_bb[col], s);
    }
  }
}

struct SelfJobs { const float* sum[3]; const float* wa[3]; float* out[3]; };
__global__ void selfdot_batch_kernel(SelfJobs J, float invE) {
  int job = threadIdx.x >> 6, lane = threadIdx.x & 63;
  float v = J.sum[job][lane] * J.wa[job][lane] * invE;
#pragma unroll
  for (int o = 32; o >= 1; o >>= 1) v += __shfl_down(v, o, 64);
  if (lane == 0) J.out[job][0] = v;
}

// ---------------- single-pass fused per-row GAT (CSR-ordered inputs) ---------
// srcs and hd are indexed directly by CSR position p — contiguous reads.
__global__ void gat_row_kernel(const int* __restrict__ offs, const int* __restrict__ srcs,
                               const float* __restrict__ ssrc, const float* __restrict__ sdst,
                               const float* __restrict__ hd, const float* __restrict__ selfhd,
                               const float* __restrict__ H, const float* __restrict__ bias,
                               float* __restrict__ out, int N, int accum) {
  int wid = (int)(((size_t)blockIdx.x * blockDim.x + threadIdx.x) >> 6);
  int lane = threadIdx.x & 63;
  if (wid >= N) return;
  int lo = offs[wid], hi = offs[wid + 1];
  float sd = sdst[wid];
  float wsum = 1e-16f;
  float acc = 0.0f;
  if (selfhd) {
    float wself = __expf(lrelu(ssrc[wid] + sd + selfhd[0], 0.2f));
    wsum += wself;
    acc = wself * H[(size_t)wid * 64 + lane];
  }
  for (int p = lo; p < hi; ++p) {
    int s = srcs[p];
    float w = __expf(lrelu(ssrc[s] + sd + hd[p], 0.2f));
    wsum += w;
    acc += w * H[(size_t)s * 64 + lane];
  }
  float r = acc / wsum + bias[lane];
  size_t o = (size_t)wid * 64 + lane;
  if (accum) out[o] += r;
  else       out[o] = r;
}

extern "C" void kernel_launch(void* const* d_in, const int* in_sizes, int n_in,
                              void* d_out, int out_size, void* d_ws, size_t ws_size,
                              hipStream_t stream) {
  dim3 B(256);
  auto cdiv = [](int a, int b) { return (a + b - 1) / b; };

  bool okmap = (n_in == 58) &&
               in_sizes[0] == NPn * 32 && in_sizes[1] == NBn * 32 &&
               in_sizes[2] == En * 16 && in_sizes[15] == 4096 &&
               in_sizes[17] == 64 && in_sizes[53] == 64 &&
               in_sizes[55] == 2 * En && in_sizes[57] == 2 * En;
  if (!okmap) {
    fill_kernel<<<cdiv(NPn, 256), B, 0, stream>>>((float*)d_out, 1000.0f, NPn);
    return;
  }

  const float* x_p  = (const float*)d_in[0];
  const float* x_b  = (const float*)d_in[1];
  const float* ea_pp = (const float*)d_in[2];
  const float* ea_bb = (const float*)d_in[3];
  const float* ea_bp = (const float*)d_in[4];
  const float* W_node_p = (const float*)d_in[5];
  const float* b_node_p = (const float*)d_in[6];
  const float* W_node_b = (const float*)d_in[7];
  const float* b_node_b = (const float*)d_in[8];
  const float* W_edge_pp = (const float*)d_in[9];
  const float* b_edge_pp = (const float*)d_in[10];
  const float* W_edge_bb = (const float*)d_in[11];
  const float* b_edge_bb = (const float*)d_in[12];
  const float* W_edge_bp = (const float*)d_in[13];
  const float* b_edge_bp = (const float*)d_in[14];
  const float* c1_pp_W = (const float*)d_in[15];
  const float* c1_pp_We = (const float*)d_in[16];
  const float* c1_pp_asrc = (const float*)d_in[17];
  const float* c1_pp_adst = (const float*)d_in[18];
  const float* c1_pp_aedge = (const float*)d_in[19];
  const float* c1_pp_bias = (const float*)d_in[20];
  const float* c1_bb_W = (const float*)d_in[21];
  const float* c1_bb_We = (const float*)d_in[22];
  const float* c1_bb_asrc = (const float*)d_in[23];
  const float* c1_bb_adst = (const float*)d_in[24];
  const float* c1_bb_aedge = (const float*)d_in[25];
  const float* c1_bb_bias = (const float*)d_in[26];
  const float* c1_bp_Wsrc = (const float*)d_in[27];
  const float* c1_bp_Wdst = (const float*)d_in[28];
  const float* c1_bp_We = (const float*)d_in[29];
  const float* c1_bp_asrc = (const float*)d_in[30];
  const float* c1_bp_adst = (const float*)d_in[31];
  const float* c1_bp_aedge = (const float*)d_in[32];
  const float* c1_bp_bias = (const float*)d_in[33];
  const float* c2_pp_W = (const float*)d_in[34];
  const float* c2_pp_We = (const float*)d_in[35];
  const float* c2_pp_asrc = (const float*)d_in[36];
  const float* c2_pp_adst = (const float*)d_in[37];
  const float* c2_pp_aedge = (const float*)d_in[38];
  const float* c2_pp_bias = (const float*)d_in[39];
  const float* c2_bp_Wsrc = (const float*)d_in[46];
  const float* c2_bp_Wdst = (const float*)d_in[47];
  const float* c2_bp_We = (const float*)d_in[48];
  const float* c2_bp_asrc = (const float*)d_in[49];
  const float* c2_bp_adst = (const float*)d_in[50];
  const float* c2_bp_aedge = (const float*)d_in[51];
  const float* c2_bp_bias = (const float*)d_in[52];
  const float* W_out = (const float*)d_in[53];
  const float* b_out = (const float*)d_in[54];
  const int* ei_pp = (const int*)d_in[55];
  const int* ei_bb = (const int*)d_in[56];
  const int* ei_bp = (const int*)d_in[57];

  // ---- workspace layout
  float* ws = (float*)d_ws;
  int* offs_cat = (int*)ws;                  // NCAT
  int* cnt_cat  = offs_cat + NCAT;           // NCAT
  int* bsum     = cnt_cat + NCAT;            // pad 2560
  int* srcs_cat = bsum + 2560;               // 3*En (CSR-ordered srcs)
  int* pos_cat  = srcs_cat + 3 * En;         // 3*En (edge -> CSR position)
  float* xp    = (float*)(pos_cat + 3 * En); // NPn*64 (p2 aliases)
  float* p1    = xp + (size_t)NPn * 64;      // NPn*64
  float* b1v   = p1 + (size_t)NPn * 64;      // NBn*64
  float* hbuf  = b1v + (size_t)NBn * 64;     // NBn*64
  float* hd_pp1 = hbuf + (size_t)NBn * 64;   // En x5 (CSR order)
  float* hd_pp2 = hd_pp1 + En;
  float* hd_bb1 = hd_pp2 + En;
  float* hd_bp1 = hd_bb1 + En;
  float* hd_bp2 = hd_bp1 + En;
  float* s_src = hd_bp2 + En;                // NBn
  float* s_dst = s_src + NBn;                // NBn
  float* small = s_dst + NBn;                // 1024
  float* p2    = xp;

  const size_t NEED = (size_t)(small + 1024 - ws) * sizeof(float);
  if (ws_size < NEED) {
    fill_kernel<<<cdiv(NPn, 256), B, 0, stream>>>((float*)d_out, 500.0f, NPn);
    return;
  }

  float* sum_pp  = small + 0;   float* sum_bb  = small + 64;
  float* wa_pp1  = small + 128; float* wa_pp2  = small + 192;
  float* wa_bb1  = small + 256; float* wa_bp1  = small + 320; float* wa_bp2 = small + 384;
  float* wd1     = small + 448; float* wd2     = small + 512;
  float* self_pp1= small + 576; float* self_pp2= small + 577; float* self_bb1 = small + 578;
  const float invE = 1.0f / (float)En;

  hipMemsetAsync(sum_pp, 0, 128 * sizeof(float), stream);

  // ---- projections + collapsed attention vectors
  proj_kernel<<<cdiv(NPn, 256), B, 0, stream>>>(x_p, W_node_p, b_node_p, xp, NPn);

  RowdotJobs RJ;
  RJ.M[0] = c1_pp_We;  RJ.v[0] = c1_pp_aedge; RJ.out[0] = wa_pp1;
  RJ.M[1] = c2_pp_We;  RJ.v[1] = c2_pp_aedge; RJ.out[1] = wa_pp2;
  RJ.M[2] = c1_bb_We;  RJ.v[2] = c1_bb_aedge; RJ.out[2] = wa_bb1;
  RJ.M[3] = c1_bp_We;  RJ.v[3] = c1_bp_aedge; RJ.out[3] = wa_bp1;
  RJ.M[4] = c2_bp_We;  RJ.v[4] = c2_bp_aedge; RJ.out[4] = wa_bp2;
  RJ.M[5] = c1_bp_Wdst; RJ.v[5] = c1_bp_adst; RJ.out[5] = wd1;
  RJ.M[6] = c2_bp_Wdst; RJ.v[6] = c2_bp_adst; RJ.out[6] = wd2;
  rowdot_batch_kernel<<<7, 64, 0, stream>>>(RJ);

  // ---- batched CSR build FIRST (edge_fused writes hd in CSR order)
  Dsts DS;
  DS.d[0] = ei_pp + En; DS.d[1] = ei_bp + En; DS.d[2] = ei_bb + En;
  DS.s[0] = ei_pp;      DS.s[1] = ei_bp;      DS.s[2] = ei_bb;
  zero_int_kernel<<<cdiv(NCAT, 256), B, 0, stream>>>(cnt_cat, NCAT);
  hist_all_kernel<<<cdiv(3 * En, 256), B, 0, stream>>>(DS, cnt_cat);
  scan1_kernel<<<NB_TOT, B, 0, stream>>>(cnt_cat, offs_cat, bsum, NCAT);
  scan2_kernel<<<1, 64, 0, stream>>>(bsum);
  scan3_kernel<<<NB_TOT, B, 0, stream>>>(cnt_cat, offs_cat, bsum, NCAT);
  copy_int_kernel<<<cdiv(NCAT, 256), B, 0, stream>>>(offs_cat, cnt_cat, NCAT);
  scatter_all_kernel<<<cdiv(3 * En, 256), B, 0, stream>>>(DS, cnt_cat, srcs_cat, pos_cat);

  const int* offs_pp = offs_cat + OFF_PP;
  const int* offs_bp = offs_cat + OFF_BP;
  const int* offs_bb = offs_cat + OFF_BB;
  const int* srcs_pp = srcs_cat;
  const int* srcs_bp = srcs_cat + En;
  const int* srcs_bb = srcs_cat + 2 * En;

  // ---- edge scalars (CSR-ordered outputs)
  EdgeJobs EJ;
  EJ.EA[0] = ea_pp; EJ.We[0] = W_edge_pp; EJ.be[0] = b_edge_pp;
  EJ.wa1[0] = wa_pp1; EJ.wa2[0] = wa_pp2; EJ.hd1[0] = hd_pp1; EJ.hd2[0] = hd_pp2;
  EJ.pos[0] = pos_cat;            // pp edge-space
  EJ.EA[1] = ea_bb; EJ.We[1] = W_edge_bb; EJ.be[1] = b_edge_bb;
  EJ.wa1[1] = wa_bb1; EJ.wa2[1] = nullptr; EJ.hd1[1] = hd_bb1; EJ.hd2[1] = nullptr;
  EJ.pos[1] = pos_cat + 2 * En;   // bb edge-space (CSR rel 2)
  EJ.EA[2] = ea_bp; EJ.We[2] = W_edge_bp; EJ.be[2] = b_edge_bp;
  EJ.wa1[2] = wa_bp1; EJ.wa2[2] = wa_bp2; EJ.hd1[2] = hd_bp1; EJ.hd2[2] = hd_bp2;
  EJ.pos[2] = pos_cat + En;       // bp edge-space (CSR rel 1)
  edge_fused_kernel<<<3 * 512, B, 0, stream>>>(EJ, sum_pp, sum_bb);

  SelfJobs SJ;
  SJ.sum[0] = sum_pp; SJ.wa[0] = wa_pp1; SJ.out[0] = self_pp1;
  SJ.sum[1] = sum_pp; SJ.wa[1] = wa_pp2; SJ.out[1] = self_pp2;
  SJ.sum[2] = sum_bb; SJ.wa[2] = wa_bb1; SJ.out[2] = self_bb1;
  selfdot_batch_kernel<<<1, 192, 0, stream>>>(SJ, invE);

  // ---- conv1 pp (homo) -> p1
  hgemm_kernel<<<cdiv(NPn, 256), B, 0, stream>>>(xp, c1_pp_W, c1_pp_asrc, c1_pp_adst, hbuf, s_src, s_dst, NPn);
  gat_row_kernel<<<cdiv(NPn * 64, 256), B, 0, stream>>>(offs_pp, srcs_pp, s_src, s_dst,
      hd_pp1, self_pp1, hbuf, c1_pp_bias, p1, NPn, 0);

  // ---- xb computed ONCE -> hbuf; conv1-bp H via b1v; conv1-bb in-place
  proj_kernel<<<cdiv(NBn, 256), B, 0, stream>>>(x_b, W_node_b, b_node_b, hbuf, NBn);

  // conv1 bp (b->p) -> p1 (+=), H in b1v
  hgemm_kernel<<<cdiv(NBn, 256), B, 0, stream>>>(hbuf, c1_bp_Wsrc, c1_bp_asrc, nullptr, b1v, s_src, nullptr, NBn);
  matvec_kernel<<<cdiv(NPn, 256), B, 0, stream>>>(xp, wd1, s_dst, NPn);
  gat_row_kernel<<<cdiv(NPn * 64, 256), B, 0, stream>>>(offs_bp, srcs_bp, s_src, s_dst,
      hd_bp1, nullptr, b1v, c1_bp_bias, p1, NPn, 1);

  // conv1 bb (homo) -> b1v (overwrites b1v after bp consumed it)
  hgemm_kernel<<<cdiv(NBn, 256), B, 0, stream>>>(hbuf, c1_bb_W, c1_bb_asrc, c1_bb_adst, hbuf, s_src, s_dst, NBn);
  gat_row_kernel<<<cdiv(NBn * 64, 256), B, 0, stream>>>(offs_bb, srcs_bb, s_src, s_dst,
      hd_bb1, self_bb1, hbuf, c1_bb_bias, b1v, NBn, 0);

  // ---- conv2 pp (homo, input p1) -> p2
  hgemm_kernel<<<cdiv(NPn, 256), B, 0, stream>>>(p1, c2_pp_W, c2_pp_asrc, c2_pp_adst, hbuf, s_src, s_dst, NPn);
  gat_row_kernel<<<cdiv(NPn * 64, 256), B, 0, stream>>>(offs_pp, srcs_pp, s_src, s_dst,
      hd_pp2, self_pp2, hbuf, c2_pp_bias, p2, NPn, 0);

  // ---- conv2 bp (src b1v) -> p2 (+=)
  hgemm_kernel<<<cdiv(NBn, 256), B, 0, stream>>>(b1v, c2_bp_Wsrc, c2_bp_asrc, nullptr, hbuf, s_src, nullptr, NBn);
  matvec_kernel<<<cdiv(NPn, 256), B, 0, stream>>>(p1, wd2, s_dst, NPn);
  gat_row_kernel<<<cdiv(NPn * 64, 256), B, 0, stream>>>(offs_bp, srcs_bp, s_src, s_dst,
      hd_bp2, nullptr, hbuf, c2_bp_bias, p2, NPn, 1);

  // ---- head
  head_kernel<<<cdiv(NPn, 256), B, 0, stream>>>(p2, W_out, b_out, (float*)d_out, NPn);
}

// Round 17
// 1509.949 us; speedup vs baseline: 1.7703x; 1.1348x over previous
//
#include <hip/hip_runtime.h>

// ---------------------------------------------------------------------------
// HeteroGNN (2-layer hetero GAT) forward on MI355X — round 17.
// vs round 16 (passed, 1713us):
//  (1) edge_fused rebuilt QUARTER-WAVE: 16 lanes/edge, 4 cols/lane in
//      registers (wreg[16][4], __launch_bounds__(256,2) to avoid the r13/14
//      64-VGPR spill cap). DS ops/edge ~6x down. Self-loop scalars via the
//      r14 identity (scalar sums of hd, no column accumulator).
//  (2) pp+bp gat_rows merged into gat_row2 (single write of p1/p2, no
//      accum RMW); hgemm runs in-place on xp/b1v to avoid extra buffers.
// ---------------------------------------------------------------------------

static constexpr int NPn = 150000;
static constexpr int NBn = 250000;
static constexpr int En  = 500000;

// concatenated CSR layout (256-aligned segments); relation order: pp, bp, bb
static constexpr int OFF_PP = 0;
static constexpr int OFF_BP = 150016;
static constexpr int OFF_BB = 300032;
static constexpr int NCAT   = 550144;
static constexpr int NB_TOT = NCAT / 256;
static constexpr int BS_BP  = OFF_BP / 256;
static constexpr int BS_BB  = OFF_BB / 256;

__device__ __forceinline__ float lrelu(float x, float s) { return x >= 0.0f ? x : s * x; }

__global__ void fill_kernel(float* out, float val, int n) {
  int i = blockIdx.x * blockDim.x + threadIdx.x;
  if (i < n) out[i] = val;
}

// ---------------- batched CSR build ----------------
struct Dsts { const int* d[3]; const int* s[3]; };

__global__ void zero_int_kernel(int* p, int n) {
  int i = blockIdx.x * blockDim.x + threadIdx.x;
  if (i < n) p[i] = 0;
}

__global__ void hist_all_kernel(Dsts ds, int* __restrict__ cnt) {
  int t = blockIdx.x * blockDim.x + threadIdx.x;
  if (t >= 3 * En) return;
  int rel = t / En, e = t - rel * En;
  int base = (rel == 0) ? OFF_PP : (rel == 1) ? OFF_BP : OFF_BB;
  atomicAdd(&cnt[base + ds.d[rel][e]], 1);
}

__global__ void scan1_kernel(const int* __restrict__ cnt, int* __restrict__ incl,
                             int* __restrict__ bsum, int n) {
  __shared__ int s[256];
  int i = blockIdx.x * 256 + threadIdx.x;
  s[threadIdx.x] = (i < n) ? cnt[i] : 0;
  __syncthreads();
  for (int o = 1; o < 256; o <<= 1) {
    int t = (threadIdx.x >= o) ? s[threadIdx.x - o] : 0;
    __syncthreads();
    s[threadIdx.x] += t;
    __syncthreads();
  }
  if (i < n) incl[i] = s[threadIdx.x];
  if (threadIdx.x == 255) bsum[blockIdx.x] = s[255];
}

__global__ void scan2_kernel(int* bsum) {
  int t = threadIdx.x;
  if (t >= 3) return;
  int lo = (t == 0) ? 0 : (t == 1) ? BS_BP : BS_BB;
  int hi = (t == 0) ? BS_BP : (t == 1) ? BS_BB : NB_TOT;
  int run = 0;
  for (int i = lo; i < hi; ++i) { int v = bsum[i]; bsum[i] = run; run += v; }
}

__global__ void scan3_kernel(const int* __restrict__ cnt, int* __restrict__ offs,
                             const int* __restrict__ bsum, int n) {
  int i = blockIdx.x * 256 + threadIdx.x;
  if (i < n) offs[i] = offs[i] - cnt[i] + bsum[i >> 8];
}

__global__ void copy_int_kernel(const int* __restrict__ src, int* __restrict__ dstp, int n) {
  int i = blockIdx.x * blockDim.x + threadIdx.x;
  if (i < n) dstp[i] = src[i];
}

__global__ void scatter_all_kernel(Dsts ds, int* __restrict__ cursor,
                                   int* __restrict__ srcs, int* __restrict__ pos) {
  int t = blockIdx.x * blockDim.x + threadIdx.x;
  if (t >= 3 * En) return;
  int rel = t / En, e = t - rel * En;
  int base = (rel == 0) ? OFF_PP : (rel == 1) ? OFF_BP : OFF_BB;
  int p = atomicAdd(&cursor[base + ds.d[rel][e]], 1);
  srcs[rel * En + p] = ds.s[rel][e];
  pos[rel * En + e] = p;
}

// ---------------- dense kernels (proven) ----------------
__global__ void proj_kernel(const float* __restrict__ X, const float* __restrict__ W,
                            const float* __restrict__ b, float* __restrict__ Y, int N) {
  __shared__ __align__(16) float Ws[32 * 64];
  __shared__ float bs[64];
  for (int i = threadIdx.x; i < 32 * 64; i += blockDim.x) Ws[i] = W[i];
  if (threadIdx.x < 64) bs[threadIdx.x] = b[threadIdx.x];
  __syncthreads();
  int row = blockIdx.x * blockDim.x + threadIdx.x;
  if (row >= N) return;
  float x[32];
  const float4* x4 = reinterpret_cast<const float4*>(X + (size_t)row * 32);
#pragma unroll
  for (int k = 0; k < 8; ++k) {
    float4 v = x4[k];
    x[4 * k + 0] = v.x; x[4 * k + 1] = v.y; x[4 * k + 2] = v.z; x[4 * k + 3] = v.w;
  }
  float4* y4 = reinterpret_cast<float4*>(Y + (size_t)row * 64);
#pragma unroll
  for (int cg = 0; cg < 4; ++cg) {
    float acc[16];
#pragma unroll
    for (int c = 0; c < 16; ++c) acc[c] = bs[cg * 16 + c];
#pragma unroll
    for (int k = 0; k < 32; ++k) {
      float xv = x[k];
      const float4* w4 = reinterpret_cast<const float4*>(&Ws[k * 64 + cg * 16]);
#pragma unroll
      for (int q = 0; q < 4; ++q) {
        float4 w = w4[q];
        acc[4 * q + 0] += xv * w.x; acc[4 * q + 1] += xv * w.y;
        acc[4 * q + 2] += xv * w.z; acc[4 * q + 3] += xv * w.w;
      }
    }
#pragma unroll
    for (int q = 0; q < 4; ++q)
      y4[cg * 4 + q] = make_float4(lrelu(acc[4 * q + 0], 0.01f), lrelu(acc[4 * q + 1], 0.01f),
                                   lrelu(acc[4 * q + 2], 0.01f), lrelu(acc[4 * q + 3], 0.01f));
  }
}

// H = X @ W; S1=H.a1; optional S2. X/H may alias (row-private).
__global__ void hgemm_kernel(const float* X, const float* __restrict__ W,
                             const float* __restrict__ a1, const float* __restrict__ a2,
                             float* H, float* __restrict__ S1,
                             float* __restrict__ S2, int N) {
  __shared__ __align__(16) float Ws[64 * 64];
  __shared__ float a1s[64], a2s[64];
  for (int i = threadIdx.x; i < 64 * 64; i += blockDim.x) Ws[i] = W[i];
  if (threadIdx.x < 64) {
    a1s[threadIdx.x] = a1[threadIdx.x];
    a2s[threadIdx.x] = a2 ? a2[threadIdx.x] : 0.0f;
  }
  __syncthreads();
  int row = blockIdx.x * blockDim.x + threadIdx.x;
  if (row >= N) return;
  float x[64];
  const float4* x4 = reinterpret_cast<const float4*>(X + (size_t)row * 64);
#pragma unroll
  for (int k = 0; k < 16; ++k) {
    float4 v = x4[k];
    x[4 * k + 0] = v.x; x[4 * k + 1] = v.y; x[4 * k + 2] = v.z; x[4 * k + 3] = v.w;
  }
  float4* h4 = reinterpret_cast<float4*>(H + (size_t)row * 64);
  float s1 = 0.0f, s2 = 0.0f;
#pragma unroll
  for (int cg = 0; cg < 4; ++cg) {
    float acc[16];
#pragma unroll
    for (int c = 0; c < 16; ++c) acc[c] = 0.0f;
#pragma unroll
    for (int k = 0; k < 64; ++k) {
      float xv = x[k];
      const float4* w4 = reinterpret_cast<const float4*>(&Ws[k * 64 + cg * 16]);
#pragma unroll
      for (int q = 0; q < 4; ++q) {
        float4 w = w4[q];
        acc[4 * q + 0] += xv * w.x; acc[4 * q + 1] += xv * w.y;
        acc[4 * q + 2] += xv * w.z; acc[4 * q + 3] += xv * w.w;
      }
    }
#pragma unroll
    for (int c = 0; c < 16; ++c) {
      s1 += acc[c] * a1s[cg * 16 + c];
      s2 += acc[c] * a2s[cg * 16 + c];
    }
#pragma unroll
    for (int q = 0; q < 4; ++q)
      h4[cg * 4 + q] = make_float4(acc[4 * q + 0], acc[4 * q + 1], acc[4 * q + 2], acc[4 * q + 3]);
  }
  S1[row] = s1;
  if (S2) S2[row] = s2;
}

__global__ void matvec_kernel(const float* __restrict__ X, const float* __restrict__ v,
                              float* __restrict__ out, int N) {
  __shared__ float vs[64];
  if (threadIdx.x < 64) vs[threadIdx.x] = v[threadIdx.x];
  __syncthreads();
  int i = blockIdx.x * blockDim.x + threadIdx.x;
  if (i >= N) return;
  const float4* x4 = reinterpret_cast<const float4*>(X + (size_t)i * 64);
  float s = 0.0f;
#pragma unroll
  for (int k = 0; k < 16; ++k) {
    float4 u = x4[k];
    s += u.x * vs[4 * k + 0] + u.y * vs[4 * k + 1] + u.z * vs[4 * k + 2] + u.w * vs[4 * k + 3];
  }
  out[i] = s;
}

__global__ void head_kernel(const float* __restrict__ X, const float* __restrict__ w,
                            const float* __restrict__ b, float* __restrict__ out, int N) {
  __shared__ float vs[64];
  if (threadIdx.x < 64) vs[threadIdx.x] = w[threadIdx.x];
  __syncthreads();
  int i = blockIdx.x * blockDim.x + threadIdx.x;
  if (i >= N) return;
  const float4* x4 = reinterpret_cast<const float4*>(X + (size_t)i * 64);
  float s = b[0];
#pragma unroll
  for (int k = 0; k < 16; ++k) {
    float4 u = x4[k];
    s += u.x * vs[4 * k + 0] + u.y * vs[4 * k + 1] + u.z * vs[4 * k + 2] + u.w * vs[4 * k + 3];
  }
  out[i] = s;
}

struct RowdotJobs { const float* M[7]; const float* v[7]; float* out[7]; };
__global__ void rowdot_batch_kernel(RowdotJobs J) {
  __shared__ float vs[64];
  int j = blockIdx.x;
  vs[threadIdx.x] = J.v[j][threadIdx.x];
  __syncthreads();
  float s = 0.0f;
  const float* M = J.M[j];
#pragma unroll
  for (int c = 0; c < 64; ++c) s += M[threadIdx.x * 64 + c] * vs[c];
  J.out[j][threadIdx.x] = s;
}

// ---------------- quarter-wave fused edge kernel ----------------
// 16 lanes per edge; each lane owns 4 columns (wreg[16][4] in registers).
// Per edge: 4 LDS broadcast reads + 64 FMA + 4-step quarter reduce.
// hd written in CSR order via pos[e]; self-loop scalars = Σhd (r14 identity)
// accumulated into sacc[3] = {Σhd_pp1, Σhd_pp2, Σhd_bb1}.
struct EdgeJobs {
  const float* EA[3]; const float* We[3]; const float* be[3];
  const float* wa1[3]; const float* wa2[3]; float* hd1[3]; float* hd2[3];
  const int* pos[3];
};
__global__ __launch_bounds__(256, 2) void edge_fused_kernel(EdgeJobs J,
                                                            float* __restrict__ sacc) {
  int rel = blockIdx.x >> 9;          // 512 blocks per relation (order pp, bb, bp)
  int blk = blockIdx.x & 511;
  __shared__ float eas[64 * 16];
  __shared__ float red1[4], red2[4];
  bool has2 = (J.wa2[rel] != nullptr);
  int lane = threadIdx.x & 63;
  int wv   = threadIdx.x >> 6;
  int qd   = lane >> 4;               // quarter 0..3 (one edge each)
  int sl   = lane & 15;               // sublane: columns sl*4 .. sl*4+3
  float wreg[16][4];
  const float* We = J.We[rel];
#pragma unroll
  for (int k = 0; k < 16; ++k) {
    float4 w = *reinterpret_cast<const float4*>(&We[k * 64 + sl * 4]);
    wreg[k][0] = w.x; wreg[k][1] = w.y; wreg[k][2] = w.z; wreg[k][3] = w.w;
  }
  float4 bc = *reinterpret_cast<const float4*>(&J.be[rel][sl * 4]);
  float4 w1c = *reinterpret_cast<const float4*>(&J.wa1[rel][sl * 4]);
  float4 w2c = has2 ? *reinterpret_cast<const float4*>(&J.wa2[rel][sl * 4])
                    : make_float4(0.f, 0.f, 0.f, 0.f);
  const float* EA = J.EA[rel];
  float* hd1 = J.hd1[rel];
  float* hd2 = J.hd2[rel];
  const int* pos = J.pos[rel];
  float s1 = 0.0f, s2 = 0.0f;
  for (int base = blk * 64; base < En; base += 512 * 64) {
    int tile = min(64, En - base);
    __syncthreads();
    for (int i = threadIdx.x; i < tile * 16; i += blockDim.x)
      eas[i] = EA[(size_t)base * 16 + i];
    __syncthreads();
#pragma unroll
    for (int it = 0; it < 4; ++it) {
      int e = it * 16 + wv * 4 + qd;
      if (e < tile) {
        float t0 = bc.x, t1 = bc.y, t2 = bc.z, t3 = bc.w;
#pragma unroll
        for (int k = 0; k < 16; ++k) {
          float xv = eas[e * 16 + k];
          t0 += xv * wreg[k][0]; t1 += xv * wreg[k][1];
          t2 += xv * wreg[k][2]; t3 += xv * wreg[k][3];
        }
        t0 = lrelu(t0, 0.01f); t1 = lrelu(t1, 0.01f);
        t2 = lrelu(t2, 0.01f); t3 = lrelu(t3, 0.01f);
        float d1 = t0 * w1c.x + t1 * w1c.y + t2 * w1c.z + t3 * w1c.w;
        float d2 = t0 * w2c.x + t1 * w2c.y + t2 * w2c.z + t3 * w2c.w;
#pragma unroll
        for (int o = 1; o < 16; o <<= 1) {   // reduce within quarter
          d1 += __shfl_xor(d1, o, 64);
          d2 += __shfl_xor(d2, o, 64);
        }
        if (sl == 0) {
          int p = pos[base + e];
          hd1[p] = d1;
          if (has2) hd2[p] = d2;
          s1 += d1;
          s2 += d2;
        }
      }
    }
  }
  if (rel < 2) {  // pp (d1,d2) and bb (d1) need scalar sums
#pragma unroll
    for (int o = 32; o >= 1; o >>= 1) {
      s1 += __shfl_xor(s1, o, 64);
      s2 += __shfl_xor(s2, o, 64);
    }
    if (lane == 0) { red1[wv] = s1; red2[wv] = s2; }
    __syncthreads();
    if (threadIdx.x == 0) {
      float t1 = red1[0] + red1[1] + red1[2] + red1[3];
      float t2 = red2[0] + red2[1] + red2[2] + red2[3];
      if (rel == 0) {
        atomicAdd(&sacc[0], t1);
        atomicAdd(&sacc[1], t2);
      } else {
        atomicAdd(&sacc[2], t1);
      }
    }
  }
}

// self_* = sacc[*] * invE     <<<1,64>>>
__global__ void selfscale_kernel(const float* __restrict__ sacc, float invE,
                                 float* __restrict__ self_pp1, float* __restrict__ self_pp2,
                                 float* __restrict__ self_bb1) {
  if (threadIdx.x == 0) {
    self_pp1[0] = sacc[0] * invE;
    self_pp2[0] = sacc[1] * invE;
    self_bb1[0] = sacc[2] * invE;
  }
}

// ---------------- fused per-row GAT (single relation, CSR inputs) ------------
__global__ void gat_row_kernel(const int* __restrict__ offs, const int* __restrict__ srcs,
                               const float* __restrict__ ssrc, const float* __restrict__ sdst,
                               const float* __restrict__ hd, const float* __restrict__ selfhd,
                               const float* __restrict__ H, const float* __restrict__ bias,
                               float* __restrict__ out, int N) {
  int wid = (int)(((size_t)blockIdx.x * blockDim.x + threadIdx.x) >> 6);
  int lane = threadIdx.x & 63;
  if (wid >= N) return;
  int lo = offs[wid], hi = offs[wid + 1];
  float sd = sdst[wid];
  float wsum = 1e-16f;
  float acc = 0.0f;
  if (selfhd) {
    float wself = __expf(lrelu(ssrc[wid] + sd + selfhd[0], 0.2f));
    wsum += wself;
    acc = wself * H[(size_t)wid * 64 + lane];
  }
  for (int p = lo; p < hi; ++p) {
    int s = srcs[p];
    float w = __expf(lrelu(ssrc[s] + sd + hd[p], 0.2f));
    wsum += w;
    acc += w * H[(size_t)s * 64 + lane];
  }
  out[(size_t)wid * 64 + lane] = acc / wsum + bias[lane];
}

// ---------------- merged dual-relation GAT (pp + bp), single write ----------
__global__ void gat_row2_kernel(
    const int* __restrict__ offsA, const int* __restrict__ srcsA,
    const float* __restrict__ ssrcA, const float* __restrict__ sdstA,
    const float* __restrict__ hdA, const float* __restrict__ selfhdA,
    const float* __restrict__ HA, const float* __restrict__ biasA,
    const int* __restrict__ offsB, const int* __restrict__ srcsB,
    const float* __restrict__ ssrcB, const float* __restrict__ sdstB,
    const float* __restrict__ hdB, const float* __restrict__ HB,
    const float* __restrict__ biasB,
    float* __restrict__ out, int N) {
  int wid = (int)(((size_t)blockIdx.x * blockDim.x + threadIdx.x) >> 6);
  int lane = threadIdx.x & 63;
  if (wid >= N) return;
  // relation A (homo pp, with self loop)
  int lo = offsA[wid], hi = offsA[wid + 1];
  float sd = sdstA[wid];
  float wself = __expf(lrelu(ssrcA[wid] + sd + selfhdA[0], 0.2f));
  float wsumA = 1e-16f + wself;
  float accA = wself * HA[(size_t)wid * 64 + lane];
  for (int p = lo; p < hi; ++p) {
    int s = srcsA[p];
    float w = __expf(lrelu(ssrcA[s] + sd + hdA[p], 0.2f));
    wsumA += w;
    accA += w * HA[(size_t)s * 64 + lane];
  }
  // relation B (bipartite bp, no self loop)
  lo = offsB[wid]; hi = offsB[wid + 1];
  float sdB = sdstB[wid];
  float wsumB = 1e-16f;
  float accB = 0.0f;
  for (int p = lo; p < hi; ++p) {
    int s = srcsB[p];
    float w = __expf(lrelu(ssrcB[s] + sdB + hdB[p], 0.2f));
    wsumB += w;
    accB += w * HB[(size_t)s * 64 + lane];
  }
  out[(size_t)wid * 64 + lane] =
      accA / wsumA + biasA[lane] + accB / wsumB + biasB[lane];
}

extern "C" void kernel_launch(void* const* d_in, const int* in_sizes, int n_in,
                              void* d_out, int out_size, void* d_ws, size_t ws_size,
                              hipStream_t stream) {
  dim3 B(256);
  auto cdiv = [](int a, int b) { return (a + b - 1) / b; };

  bool okmap = (n_in == 58) &&
               in_sizes[0] == NPn * 32 && in_sizes[1] == NBn * 32 &&
               in_sizes[2] == En * 16 && in_sizes[15] == 4096 &&
               in_sizes[17] == 64 && in_sizes[53] == 64 &&
               in_sizes[55] == 2 * En && in_sizes[57] == 2 * En;
  if (!okmap) {
    fill_kernel<<<cdiv(NPn, 256), B, 0, stream>>>((float*)d_out, 1000.0f, NPn);
    return;
  }

  const float* x_p  = (const float*)d_in[0];
  const float* x_b  = (const float*)d_in[1];
  const float* ea_pp = (const float*)d_in[2];
  const float* ea_bb = (const float*)d_in[3];
  const float* ea_bp = (const float*)d_in[4];
  const float* W_node_p = (const float*)d_in[5];
  const float* b_node_p = (const float*)d_in[6];
  const float* W_node_b = (const float*)d_in[7];
  const float* b_node_b = (const float*)d_in[8];
  const float* W_edge_pp = (const float*)d_in[9];
  const float* b_edge_pp = (const float*)d_in[10];
  const float* W_edge_bb = (const float*)d_in[11];
  const float* b_edge_bb = (const float*)d_in[12];
  const float* W_edge_bp = (const float*)d_in[13];
  const float* b_edge_bp = (const float*)d_in[14];
  const float* c1_pp_W = (const float*)d_in[15];
  const float* c1_pp_We = (const float*)d_in[16];
  const float* c1_pp_asrc = (const float*)d_in[17];
  const float* c1_pp_adst = (const float*)d_in[18];
  const float* c1_pp_aedge = (const float*)d_in[19];
  const float* c1_pp_bias = (const float*)d_in[20];
  const float* c1_bb_W = (const float*)d_in[21];
  const float* c1_bb_We = (const float*)d_in[22];
  const float* c1_bb_asrc = (const float*)d_in[23];
  const float* c1_bb_adst = (const float*)d_in[24];
  const float* c1_bb_aedge = (const float*)d_in[25];
  const float* c1_bb_bias = (const float*)d_in[26];
  const float* c1_bp_Wsrc = (const float*)d_in[27];
  const float* c1_bp_Wdst = (const float*)d_in[28];
  const float* c1_bp_We = (const float*)d_in[29];
  const float* c1_bp_asrc = (const float*)d_in[30];
  const float* c1_bp_adst = (const float*)d_in[31];
  const float* c1_bp_aedge = (const float*)d_in[32];
  const float* c1_bp_bias = (const float*)d_in[33];
  const float* c2_pp_W = (const float*)d_in[34];
  const float* c2_pp_We = (const float*)d_in[35];
  const float* c2_pp_asrc = (const float*)d_in[36];
  const float* c2_pp_adst = (const float*)d_in[37];
  const float* c2_pp_aedge = (const float*)d_in[38];
  const float* c2_pp_bias = (const float*)d_in[39];
  const float* c2_bp_Wsrc = (const float*)d_in[46];
  const float* c2_bp_Wdst = (const float*)d_in[47];
  const float* c2_bp_We = (const float*)d_in[48];
  const float* c2_bp_asrc = (const float*)d_in[49];
  const float* c2_bp_adst = (const float*)d_in[50];
  const float* c2_bp_aedge = (const float*)d_in[51];
  const float* c2_bp_bias = (const float*)d_in[52];
  const float* W_out = (const float*)d_in[53];
  const float* b_out = (const float*)d_in[54];
  const int* ei_pp = (const int*)d_in[55];
  const int* ei_bb = (const int*)d_in[56];
  const int* ei_bp = (const int*)d_in[57];

  // ---- workspace layout
  float* ws = (float*)d_ws;
  int* offs_cat = (int*)ws;                  // NCAT
  int* cnt_cat  = offs_cat + NCAT;           // NCAT
  int* bsum     = cnt_cat + NCAT;            // pad 2560
  int* srcs_cat = bsum + 2560;               // 3*En
  int* pos_cat  = srcs_cat + 3 * En;         // 3*En
  float* xp    = (float*)(pos_cat + 3 * En); // NPn*64 (H_pp in conv1; p2 later)
  float* p1    = xp + (size_t)NPn * 64;      // NPn*64
  float* b1v   = p1 + (size_t)NPn * 64;      // NBn*64
  float* hbuf  = b1v + (size_t)NBn * 64;     // NBn*64
  float* hd_pp1 = hbuf + (size_t)NBn * 64;   // En x5 (CSR order)
  float* hd_pp2 = hd_pp1 + En;
  float* hd_bb1 = hd_pp2 + En;
  float* hd_bp1 = hd_bb1 + En;
  float* hd_bp2 = hd_bp1 + En;
  float* sA_src = hd_bp2 + En;               // NBn
  float* sA_dst = sA_src + NBn;              // NBn
  float* sB_src = sA_dst + NBn;              // NBn
  float* sB_dst = sB_src + NBn;              // NPn
  float* small  = sB_dst + NPn;              // 1024
  float* p2     = xp;

  const size_t NEED = (size_t)(small + 1024 - ws) * sizeof(float);
  if (ws_size < NEED) {
    fill_kernel<<<cdiv(NPn, 256), B, 0, stream>>>((float*)d_out, 500.0f, NPn);
    return;
  }

  float* sacc    = small + 0;    // [3]
  float* wa_pp1  = small + 128;  float* wa_pp2  = small + 192;
  float* wa_bb1  = small + 256;  float* wa_bp1  = small + 320; float* wa_bp2 = small + 384;
  float* wd1     = small + 448;  float* wd2     = small + 512;
  float* self_pp1= small + 576;  float* self_pp2= small + 577; float* self_bb1 = small + 578;
  const float invE = 1.0f / (float)En;

  hipMemsetAsync(sacc, 0, 16 * sizeof(float), stream);

  // ---- projections + collapsed attention vectors
  proj_kernel<<<cdiv(NPn, 256), B, 0, stream>>>(x_p, W_node_p, b_node_p, xp, NPn);

  RowdotJobs RJ;
  RJ.M[0] = c1_pp_We;  RJ.v[0] = c1_pp_aedge; RJ.out[0] = wa_pp1;
  RJ.M[1] = c2_pp_We;  RJ.v[1] = c2_pp_aedge; RJ.out[1] = wa_pp2;
  RJ.M[2] = c1_bb_We;  RJ.v[2] = c1_bb_aedge; RJ.out[2] = wa_bb1;
  RJ.M[3] = c1_bp_We;  RJ.v[3] = c1_bp_aedge; RJ.out[3] = wa_bp1;
  RJ.M[4] = c2_bp_We;  RJ.v[4] = c2_bp_aedge; RJ.out[4] = wa_bp2;
  RJ.M[5] = c1_bp_Wdst; RJ.v[5] = c1_bp_adst; RJ.out[5] = wd1;
  RJ.M[6] = c2_bp_Wdst; RJ.v[6] = c2_bp_adst; RJ.out[6] = wd2;
  rowdot_batch_kernel<<<7, 64, 0, stream>>>(RJ);

  // ---- batched CSR build (edge_fused writes hd in CSR order)
  Dsts DS;
  DS.d[0] = ei_pp + En; DS.d[1] = ei_bp + En; DS.d[2] = ei_bb + En;
  DS.s[0] = ei_pp;      DS.s[1] = ei_bp;      DS.s[2] = ei_bb;
  zero_int_kernel<<<cdiv(NCAT, 256), B, 0, stream>>>(cnt_cat, NCAT);
  hist_all_kernel<<<cdiv(3 * En, 256), B, 0, stream>>>(DS, cnt_cat);
  scan1_kernel<<<NB_TOT, B, 0, stream>>>(cnt_cat, offs_cat, bsum, NCAT);
  scan2_kernel<<<1, 64, 0, stream>>>(bsum);
  scan3_kernel<<<NB_TOT, B, 0, stream>>>(cnt_cat, offs_cat, bsum, NCAT);
  copy_int_kernel<<<cdiv(NCAT, 256), B, 0, stream>>>(offs_cat, cnt_cat, NCAT);
  scatter_all_kernel<<<cdiv(3 * En, 256), B, 0, stream>>>(DS, cnt_cat, srcs_cat, pos_cat);

  const int* offs_pp = offs_cat + OFF_PP;
  const int* offs_bp = offs_cat + OFF_BP;
  const int* offs_bb = offs_cat + OFF_BB;
  const int* srcs_pp = srcs_cat;
  const int* srcs_bp = srcs_cat + En;
  const int* srcs_bb = srcs_cat + 2 * En;

  // ---- edge scalars (CSR-ordered outputs), relation order pp, bb, bp
  EdgeJobs EJ;
  EJ.EA[0] = ea_pp; EJ.We[0] = W_edge_pp; EJ.be[0] = b_edge_pp;
  EJ.wa1[0] = wa_pp1; EJ.wa2[0] = wa_pp2; EJ.hd1[0] = hd_pp1; EJ.hd2[0] = hd_pp2;
  EJ.pos[0] = pos_cat;
  EJ.EA[1] = ea_bb; EJ.We[1] = W_edge_bb; EJ.be[1] = b_edge_bb;
  EJ.wa1[1] = wa_bb1; EJ.wa2[1] = nullptr; EJ.hd1[1] = hd_bb1; EJ.hd2[1] = nullptr;
  EJ.pos[1] = pos_cat + 2 * En;
  EJ.EA[2] = ea_bp; EJ.We[2] = W_edge_bp; EJ.be[2] = b_edge_bp;
  EJ.wa1[2] = wa_bp1; EJ.wa2[2] = wa_bp2; EJ.hd1[2] = hd_bp1; EJ.hd2[2] = hd_bp2;
  EJ.pos[2] = pos_cat + En;
  edge_fused_kernel<<<3 * 512, B, 0, stream>>>(EJ, sacc);

  selfscale_kernel<<<1, 64, 0, stream>>>(sacc, invE, self_pp1, self_pp2, self_bb1);

  // ---- conv1 ----
  // bp s_dst from ORIGINAL xp, before in-place overwrite
  matvec_kernel<<<cdiv(NPn, 256), B, 0, stream>>>(xp, wd1, sB_dst, NPn);
  // pp: H in-place into xp
  hgemm_kernel<<<cdiv(NPn, 256), B, 0, stream>>>(xp, c1_pp_W, c1_pp_asrc, c1_pp_adst, xp, sA_src, sA_dst, NPn);
  // xb once -> hbuf; bp H -> b1v
  proj_kernel<<<cdiv(NBn, 256), B, 0, stream>>>(x_b, W_node_b, b_node_b, hbuf, NBn);
  hgemm_kernel<<<cdiv(NBn, 256), B, 0, stream>>>(hbuf, c1_bp_Wsrc, c1_bp_asrc, nullptr, b1v, sB_src, nullptr, NBn);
  // merged pp+bp -> p1 (single write)
  gat_row2_kernel<<<cdiv(NPn * 64, 256), B, 0, stream>>>(
      offs_pp, srcs_pp, sA_src, sA_dst, hd_pp1, self_pp1, xp, c1_pp_bias,
      offs_bp, srcs_bp, sB_src, sB_dst, hd_bp1, b1v, c1_bp_bias, p1, NPn);
  // bb: H in-place into hbuf -> b1v
  hgemm_kernel<<<cdiv(NBn, 256), B, 0, stream>>>(hbuf, c1_bb_W, c1_bb_asrc, c1_bb_adst, hbuf, sA_src, sA_dst, NBn);
  gat_row_kernel<<<cdiv(NBn * 64, 256), B, 0, stream>>>(offs_bb, srcs_bb, sA_src, sA_dst,
      hd_bb1, self_bb1, hbuf, c1_bb_bias, b1v, NBn);

  // ---- conv2 ----
  matvec_kernel<<<cdiv(NPn, 256), B, 0, stream>>>(p1, wd2, sB_dst, NPn);
  hgemm_kernel<<<cdiv(NPn, 256), B, 0, stream>>>(p1, c2_pp_W, c2_pp_asrc, c2_pp_adst, hbuf, sA_src, sA_dst, NPn);
  hgemm_kernel<<<cdiv(NBn, 256), B, 0, stream>>>(b1v, c2_bp_Wsrc, c2_bp_asrc, nullptr, b1v, sB_src, nullptr, NBn);
  gat_row2_kernel<<<cdiv(NPn * 64, 256), B, 0, stream>>>(
      offs_pp, srcs_pp, sA_src, sA_dst, hd_pp2, self_pp2, hbuf, c2_pp_bias,
      offs_bp, srcs_bp, sB_src, sB_dst, hd_bp2, b1v, c2_bp_bias, p2, NPn);

  // ---- head
  head_kernel<<<cdiv(NPn, 256), B, 0, stream>>>(p2, W_out, b_out, (float*)d_out, NPn);
}

// Round 18
// 1486.387 us; speedup vs baseline: 1.7983x; 1.0159x over previous
//
#include <hip/hip_runtime.h>

// ---------------------------------------------------------------------------
// HeteroGNN (2-layer hetero GAT) forward on MI355X — round 18.
// vs round 17 (passed, 1510us):
//  (1) hgemm: optional xv/S3 epilogue (S3 = input_row . xv) — replaces both
//      matvec launches and their 38MB re-reads of xp / p1.
//  (2) hgemm2: one pass over proj(x_b) computing BOTH bp and bb GEMMs
//      (b1v + in-place hbuf) — halves the b-side H read traffic, -1 launch.
//  (3) edge_fused: 128-edge LDS tiles (8KB) — halves barrier count.
// ---------------------------------------------------------------------------

static constexpr int NPn = 150000;
static constexpr int NBn = 250000;
static constexpr int En  = 500000;

// concatenated CSR layout (256-aligned segments); relation order: pp, bp, bb
static constexpr int OFF_PP = 0;
static constexpr int OFF_BP = 150016;
static constexpr int OFF_BB = 300032;
static constexpr int NCAT   = 550144;
static constexpr int NB_TOT = NCAT / 256;
static constexpr int BS_BP  = OFF_BP / 256;
static constexpr int BS_BB  = OFF_BB / 256;

__device__ __forceinline__ float lrelu(float x, float s) { return x >= 0.0f ? x : s * x; }

__global__ void fill_kernel(float* out, float val, int n) {
  int i = blockIdx.x * blockDim.x + threadIdx.x;
  if (i < n) out[i] = val;
}

// ---------------- batched CSR build ----------------
struct Dsts { const int* d[3]; const int* s[3]; };

__global__ void zero_int_kernel(int* p, int n) {
  int i = blockIdx.x * blockDim.x + threadIdx.x;
  if (i < n) p[i] = 0;
}

__global__ void hist_all_kernel(Dsts ds, int* __restrict__ cnt) {
  int t = blockIdx.x * blockDim.x + threadIdx.x;
  if (t >= 3 * En) return;
  int rel = t / En, e = t - rel * En;
  int base = (rel == 0) ? OFF_PP : (rel == 1) ? OFF_BP : OFF_BB;
  atomicAdd(&cnt[base + ds.d[rel][e]], 1);
}

__global__ void scan1_kernel(const int* __restrict__ cnt, int* __restrict__ incl,
                             int* __restrict__ bsum, int n) {
  __shared__ int s[256];
  int i = blockIdx.x * 256 + threadIdx.x;
  s[threadIdx.x] = (i < n) ? cnt[i] : 0;
  __syncthreads();
  for (int o = 1; o < 256; o <<= 1) {
    int t = (threadIdx.x >= o) ? s[threadIdx.x - o] : 0;
    __syncthreads();
    s[threadIdx.x] += t;
    __syncthreads();
  }
  if (i < n) incl[i] = s[threadIdx.x];
  if (threadIdx.x == 255) bsum[blockIdx.x] = s[255];
}

__global__ void scan2_kernel(int* bsum) {
  int t = threadIdx.x;
  if (t >= 3) return;
  int lo = (t == 0) ? 0 : (t == 1) ? BS_BP : BS_BB;
  int hi = (t == 0) ? BS_BP : (t == 1) ? BS_BB : NB_TOT;
  int run = 0;
  for (int i = lo; i < hi; ++i) { int v = bsum[i]; bsum[i] = run; run += v; }
}

__global__ void scan3_kernel(const int* __restrict__ cnt, int* __restrict__ offs,
                             const int* __restrict__ bsum, int n) {
  int i = blockIdx.x * 256 + threadIdx.x;
  if (i < n) offs[i] = offs[i] - cnt[i] + bsum[i >> 8];
}

__global__ void copy_int_kernel(const int* __restrict__ src, int* __restrict__ dstp, int n) {
  int i = blockIdx.x * blockDim.x + threadIdx.x;
  if (i < n) dstp[i] = src[i];
}

__global__ void scatter_all_kernel(Dsts ds, int* __restrict__ cursor,
                                   int* __restrict__ srcs, int* __restrict__ pos) {
  int t = blockIdx.x * blockDim.x + threadIdx.x;
  if (t >= 3 * En) return;
  int rel = t / En, e = t - rel * En;
  int base = (rel == 0) ? OFF_PP : (rel == 1) ? OFF_BP : OFF_BB;
  int p = atomicAdd(&cursor[base + ds.d[rel][e]], 1);
  srcs[rel * En + p] = ds.s[rel][e];
  pos[rel * En + e] = p;
}

// ---------------- dense kernels ----------------
__global__ void proj_kernel(const float* __restrict__ X, const float* __restrict__ W,
                            const float* __restrict__ b, float* __restrict__ Y, int N) {
  __shared__ __align__(16) float Ws[32 * 64];
  __shared__ float bs[64];
  for (int i = threadIdx.x; i < 32 * 64; i += blockDim.x) Ws[i] = W[i];
  if (threadIdx.x < 64) bs[threadIdx.x] = b[threadIdx.x];
  __syncthreads();
  int row = blockIdx.x * blockDim.x + threadIdx.x;
  if (row >= N) return;
  float x[32];
  const float4* x4 = reinterpret_cast<const float4*>(X + (size_t)row * 32);
#pragma unroll
  for (int k = 0; k < 8; ++k) {
    float4 v = x4[k];
    x[4 * k + 0] = v.x; x[4 * k + 1] = v.y; x[4 * k + 2] = v.z; x[4 * k + 3] = v.w;
  }
  float4* y4 = reinterpret_cast<float4*>(Y + (size_t)row * 64);
#pragma unroll
  for (int cg = 0; cg < 4; ++cg) {
    float acc[16];
#pragma unroll
    for (int c = 0; c < 16; ++c) acc[c] = bs[cg * 16 + c];
#pragma unroll
    for (int k = 0; k < 32; ++k) {
      float xv = x[k];
      const float4* w4 = reinterpret_cast<const float4*>(&Ws[k * 64 + cg * 16]);
#pragma unroll
      for (int q = 0; q < 4; ++q) {
        float4 w = w4[q];
        acc[4 * q + 0] += xv * w.x; acc[4 * q + 1] += xv * w.y;
        acc[4 * q + 2] += xv * w.z; acc[4 * q + 3] += xv * w.w;
      }
    }
#pragma unroll
    for (int q = 0; q < 4; ++q)
      y4[cg * 4 + q] = make_float4(lrelu(acc[4 * q + 0], 0.01f), lrelu(acc[4 * q + 1], 0.01f),
                                   lrelu(acc[4 * q + 2], 0.01f), lrelu(acc[4 * q + 3], 0.01f));
  }
}

// H = X @ W; S1=H.a1; optional S2=H.a2; optional S3 = x_in . xv (input-row dot).
// X/H may alias (row-private).
__global__ void hgemm_kernel(const float* X, const float* __restrict__ W,
                             const float* __restrict__ a1, const float* __restrict__ a2,
                             const float* __restrict__ xv,
                             float* H, float* __restrict__ S1,
                             float* __restrict__ S2, float* __restrict__ S3, int N) {
  __shared__ __align__(16) float Ws[64 * 64];
  __shared__ float a1s[64], a2s[64], xvs[64];
  for (int i = threadIdx.x; i < 64 * 64; i += blockDim.x) Ws[i] = W[i];
  if (threadIdx.x < 64) {
    a1s[threadIdx.x] = a1[threadIdx.x];
    a2s[threadIdx.x] = a2 ? a2[threadIdx.x] : 0.0f;
    xvs[threadIdx.x] = xv ? xv[threadIdx.x] : 0.0f;
  }
  __syncthreads();
  int row = blockIdx.x * blockDim.x + threadIdx.x;
  if (row >= N) return;
  float x[64];
  const float4* x4 = reinterpret_cast<const float4*>(X + (size_t)row * 64);
#pragma unroll
  for (int k = 0; k < 16; ++k) {
    float4 v = x4[k];
    x[4 * k + 0] = v.x; x[4 * k + 1] = v.y; x[4 * k + 2] = v.z; x[4 * k + 3] = v.w;
  }
  if (S3) {
    float s3 = 0.0f;
#pragma unroll
    for (int k = 0; k < 64; ++k) s3 += x[k] * xvs[k];
    S3[row] = s3;
  }
  float4* h4 = reinterpret_cast<float4*>(H + (size_t)row * 64);
  float s1 = 0.0f, s2 = 0.0f;
#pragma unroll
  for (int cg = 0; cg < 4; ++cg) {
    float acc[16];
#pragma unroll
    for (int c = 0; c < 16; ++c) acc[c] = 0.0f;
#pragma unroll
    for (int k = 0; k < 64; ++k) {
      float xvv = x[k];
      const float4* w4 = reinterpret_cast<const float4*>(&Ws[k * 64 + cg * 16]);
#pragma unroll
      for (int q = 0; q < 4; ++q) {
        float4 w = w4[q];
        acc[4 * q + 0] += xvv * w.x; acc[4 * q + 1] += xvv * w.y;
        acc[4 * q + 2] += xvv * w.z; acc[4 * q + 3] += xvv * w.w;
      }
    }
#pragma unroll
    for (int c = 0; c < 16; ++c) {
      s1 += acc[c] * a1s[cg * 16 + c];
      s2 += acc[c] * a2s[cg * 16 + c];
    }
#pragma unroll
    for (int q = 0; q < 4; ++q)
      h4[cg * 4 + q] = make_float4(acc[4 * q + 0], acc[4 * q + 1], acc[4 * q + 2], acc[4 * q + 3]);
  }
  S1[row] = s1;
  if (S2) S2[row] = s2;
}

// One pass over X: H1 = X@W1 (-> H1out, S1a=H1.a1a) and H2 = X@W2
// (-> X in-place, S2a=H2.a2a, S2b=H2.a2b). Row-private.
__global__ void hgemm2_kernel(float* X, const float* __restrict__ W1,
                              const float* __restrict__ a1a,
                              const float* __restrict__ W2,
                              const float* __restrict__ a2a, const float* __restrict__ a2b,
                              float* __restrict__ H1out,
                              float* __restrict__ S1a, float* __restrict__ S2a,
                              float* __restrict__ S2b, int N) {
  __shared__ __align__(16) float W1s[64 * 64];
  __shared__ __align__(16) float W2s[64 * 64];
  __shared__ float v1[64], v2a[64], v2b[64];
  for (int i = threadIdx.x; i < 64 * 64; i += blockDim.x) { W1s[i] = W1[i]; W2s[i] = W2[i]; }
  if (threadIdx.x < 64) {
    v1[threadIdx.x] = a1a[threadIdx.x];
    v2a[threadIdx.x] = a2a[threadIdx.x];
    v2b[threadIdx.x] = a2b[threadIdx.x];
  }
  __syncthreads();
  int row = blockIdx.x * blockDim.x + threadIdx.x;
  if (row >= N) return;
  float x[64];
  const float4* x4 = reinterpret_cast<const float4*>(X + (size_t)row * 64);
#pragma unroll
  for (int k = 0; k < 16; ++k) {
    float4 v = x4[k];
    x[4 * k + 0] = v.x; x[4 * k + 1] = v.y; x[4 * k + 2] = v.z; x[4 * k + 3] = v.w;
  }
  // GEMM 1 -> H1out
  {
    float4* h4 = reinterpret_cast<float4*>(H1out + (size_t)row * 64);
    float s1 = 0.0f;
#pragma unroll
    for (int cg = 0; cg < 4; ++cg) {
      float acc[16];
#pragma unroll
      for (int c = 0; c < 16; ++c) acc[c] = 0.0f;
#pragma unroll
      for (int k = 0; k < 64; ++k) {
        float xv = x[k];
        const float4* w4 = reinterpret_cast<const float4*>(&W1s[k * 64 + cg * 16]);
#pragma unroll
        for (int q = 0; q < 4; ++q) {
          float4 w = w4[q];
          acc[4 * q + 0] += xv * w.x; acc[4 * q + 1] += xv * w.y;
          acc[4 * q + 2] += xv * w.z; acc[4 * q + 3] += xv * w.w;
        }
      }
#pragma unroll
      for (int c = 0; c < 16; ++c) s1 += acc[c] * v1[cg * 16 + c];
#pragma unroll
      for (int q = 0; q < 4; ++q)
        h4[cg * 4 + q] = make_float4(acc[4 * q + 0], acc[4 * q + 1], acc[4 * q + 2], acc[4 * q + 3]);
    }
    S1a[row] = s1;
  }
  // GEMM 2 -> X in-place
  {
    float4* h4 = reinterpret_cast<float4*>(X + (size_t)row * 64);
    float sa = 0.0f, sb = 0.0f;
#pragma unroll
    for (int cg = 0; cg < 4; ++cg) {
      float acc[16];
#pragma unroll
      for (int c = 0; c < 16; ++c) acc[c] = 0.0f;
#pragma unroll
      for (int k = 0; k < 64; ++k) {
        float xv = x[k];
        const float4* w4 = reinterpret_cast<const float4*>(&W2s[k * 64 + cg * 16]);
#pragma unroll
        for (int q = 0; q < 4; ++q) {
          float4 w = w4[q];
          acc[4 * q + 0] += xv * w.x; acc[4 * q + 1] += xv * w.y;
          acc[4 * q + 2] += xv * w.z; acc[4 * q + 3] += xv * w.w;
        }
      }
#pragma unroll
      for (int c = 0; c < 16; ++c) {
        sa += acc[c] * v2a[cg * 16 + c];
        sb += acc[c] * v2b[cg * 16 + c];
      }
#pragma unroll
      for (int q = 0; q < 4; ++q)
        h4[cg * 4 + q] = make_float4(acc[4 * q + 0], acc[4 * q + 1], acc[4 * q + 2], acc[4 * q + 3]);
    }
    S2a[row] = sa;
    S2b[row] = sb;
  }
}

__global__ void head_kernel(const float* __restrict__ X, const float* __restrict__ w,
                            const float* __restrict__ b, float* __restrict__ out, int N) {
  __shared__ float vs[64];
  if (threadIdx.x < 64) vs[threadIdx.x] = w[threadIdx.x];
  __syncthreads();
  int i = blockIdx.x * blockDim.x + threadIdx.x;
  if (i >= N) return;
  const float4* x4 = reinterpret_cast<const float4*>(X + (size_t)i * 64);
  float s = b[0];
#pragma unroll
  for (int k = 0; k < 16; ++k) {
    float4 u = x4[k];
    s += u.x * vs[4 * k + 0] + u.y * vs[4 * k + 1] + u.z * vs[4 * k + 2] + u.w * vs[4 * k + 3];
  }
  out[i] = s;
}

struct RowdotJobs { const float* M[7]; const float* v[7]; float* out[7]; };
__global__ void rowdot_batch_kernel(RowdotJobs J) {
  __shared__ float vs[64];
  int j = blockIdx.x;
  vs[threadIdx.x] = J.v[j][threadIdx.x];
  __syncthreads();
  float s = 0.0f;
  const float* M = J.M[j];
#pragma unroll
  for (int c = 0; c < 64; ++c) s += M[threadIdx.x * 64 + c] * vs[c];
  J.out[j][threadIdx.x] = s;
}

// ---------------- quarter-wave fused edge kernel (128-edge tiles) -----------
struct EdgeJobs {
  const float* EA[3]; const float* We[3]; const float* be[3];
  const float* wa1[3]; const float* wa2[3]; float* hd1[3]; float* hd2[3];
  const int* pos[3];
};
__global__ __launch_bounds__(256, 2) void edge_fused_kernel(EdgeJobs J,
                                                            float* __restrict__ sacc) {
  int rel = blockIdx.x >> 9;          // 512 blocks per relation (order pp, bb, bp)
  int blk = blockIdx.x & 511;
  __shared__ float eas[128 * 16];
  __shared__ float red1[4], red2[4];
  bool has2 = (J.wa2[rel] != nullptr);
  int lane = threadIdx.x & 63;
  int wv   = threadIdx.x >> 6;
  int qd   = lane >> 4;               // quarter
  int sl   = lane & 15;               // sublane: columns sl*4..sl*4+3
  float wreg[16][4];
  const float* We = J.We[rel];
#pragma unroll
  for (int k = 0; k < 16; ++k) {
    float4 w = *reinterpret_cast<const float4*>(&We[k * 64 + sl * 4]);
    wreg[k][0] = w.x; wreg[k][1] = w.y; wreg[k][2] = w.z; wreg[k][3] = w.w;
  }
  float4 bc = *reinterpret_cast<const float4*>(&J.be[rel][sl * 4]);
  float4 w1c = *reinterpret_cast<const float4*>(&J.wa1[rel][sl * 4]);
  float4 w2c = has2 ? *reinterpret_cast<const float4*>(&J.wa2[rel][sl * 4])
                    : make_float4(0.f, 0.f, 0.f, 0.f);
  const float* EA = J.EA[rel];
  float* hd1 = J.hd1[rel];
  float* hd2 = J.hd2[rel];
  const int* pos = J.pos[rel];
  float s1 = 0.0f, s2 = 0.0f;
  for (int base = blk * 128; base < En; base += 512 * 128) {
    int tile = min(128, En - base);
    __syncthreads();
    for (int i = threadIdx.x; i < tile * 16; i += blockDim.x)
      eas[i] = EA[(size_t)base * 16 + i];
    __syncthreads();
#pragma unroll
    for (int it = 0; it < 8; ++it) {
      int e = it * 16 + wv * 4 + qd;
      if (e < tile) {
        float t0 = bc.x, t1 = bc.y, t2 = bc.z, t3 = bc.w;
#pragma unroll
        for (int k = 0; k < 16; ++k) {
          float xv = eas[e * 16 + k];
          t0 += xv * wreg[k][0]; t1 += xv * wreg[k][1];
          t2 += xv * wreg[k][2]; t3 += xv * wreg[k][3];
        }
        t0 = lrelu(t0, 0.01f); t1 = lrelu(t1, 0.01f);
        t2 = lrelu(t2, 0.01f); t3 = lrelu(t3, 0.01f);
        float d1 = t0 * w1c.x + t1 * w1c.y + t2 * w1c.z + t3 * w1c.w;
        float d2 = t0 * w2c.x + t1 * w2c.y + t2 * w2c.z + t3 * w2c.w;
#pragma unroll
        for (int o = 1; o < 16; o <<= 1) {
          d1 += __shfl_xor(d1, o, 64);
          d2 += __shfl_xor(d2, o, 64);
        }
        if (sl == 0) {
          int p = pos[base + e];
          hd1[p] = d1;
          if (has2) hd2[p] = d2;
          s1 += d1;
          s2 += d2;
        }
      }
    }
  }
  if (rel < 2) {
#pragma unroll
    for (int o = 32; o >= 1; o >>= 1) {
      s1 += __shfl_xor(s1, o, 64);
      s2 += __shfl_xor(s2, o, 64);
    }
    if (lane == 0) { red1[wv] = s1; red2[wv] = s2; }
    __syncthreads();
    if (threadIdx.x == 0) {
      float t1 = red1[0] + red1[1] + red1[2] + red1[3];
      float t2 = red2[0] + red2[1] + red2[2] + red2[3];
      if (rel == 0) {
        atomicAdd(&sacc[0], t1);
        atomicAdd(&sacc[1], t2);
      } else {
        atomicAdd(&sacc[2], t1);
      }
    }
  }
}

__global__ void selfscale_kernel(const float* __restrict__ sacc, float invE,
                                 float* __restrict__ self_pp1, float* __restrict__ self_pp2,
                                 float* __restrict__ self_bb1) {
  if (threadIdx.x == 0) {
    self_pp1[0] = sacc[0] * invE;
    self_pp2[0] = sacc[1] * invE;
    self_bb1[0] = sacc[2] * invE;
  }
}

// ---------------- fused per-row GAT kernels ----------------
__global__ void gat_row_kernel(const int* __restrict__ offs, const int* __restrict__ srcs,
                               const float* __restrict__ ssrc, const float* __restrict__ sdst,
                               const float* __restrict__ hd, const float* __restrict__ selfhd,
                               const float* __restrict__ H, const float* __restrict__ bias,
                               float* __restrict__ out, int N) {
  int wid = (int)(((size_t)blockIdx.x * blockDim.x + threadIdx.x) >> 6);
  int lane = threadIdx.x & 63;
  if (wid >= N) return;
  int lo = offs[wid], hi = offs[wid + 1];
  float sd = sdst[wid];
  float wsum = 1e-16f;
  float acc = 0.0f;
  if (selfhd) {
    float wself = __expf(lrelu(ssrc[wid] + sd + selfhd[0], 0.2f));
    wsum += wself;
    acc = wself * H[(size_t)wid * 64 + lane];
  }
  for (int p = lo; p < hi; ++p) {
    int s = srcs[p];
    float w = __expf(lrelu(ssrc[s] + sd + hd[p], 0.2f));
    wsum += w;
    acc += w * H[(size_t)s * 64 + lane];
  }
  out[(size_t)wid * 64 + lane] = acc / wsum + bias[lane];
}

__global__ void gat_row2_kernel(
    const int* __restrict__ offsA, const int* __restrict__ srcsA,
    const float* __restrict__ ssrcA, const float* __restrict__ sdstA,
    const float* __restrict__ hdA, const float* __restrict__ selfhdA,
    const float* __restrict__ HA, const float* __restrict__ biasA,
    const int* __restrict__ offsB, const int* __restrict__ srcsB,
    const float* __restrict__ ssrcB, const float* __restrict__ sdstB,
    const float* __restrict__ hdB, const float* __restrict__ HB,
    const float* __restrict__ biasB,
    float* __restrict__ out, int N) {
  int wid = (int)(((size_t)blockIdx.x * blockDim.x + threadIdx.x) >> 6);
  int lane = threadIdx.x & 63;
  if (wid >= N) return;
  int lo = offsA[wid], hi = offsA[wid + 1];
  float sd = sdstA[wid];
  float wself = __expf(lrelu(ssrcA[wid] + sd + selfhdA[0], 0.2f));
  float wsumA = 1e-16f + wself;
  float accA = wself * HA[(size_t)wid * 64 + lane];
  for (int p = lo; p < hi; ++p) {
    int s = srcsA[p];
    float w = __expf(lrelu(ssrcA[s] + sd + hdA[p], 0.2f));
    wsumA += w;
    accA += w * HA[(size_t)s * 64 + lane];
  }
  lo = offsB[wid]; hi = offsB[wid + 1];
  float sdB = sdstB[wid];
  float wsumB = 1e-16f;
  float accB = 0.0f;
  for (int p = lo; p < hi; ++p) {
    int s = srcsB[p];
    float w = __expf(lrelu(ssrcB[s] + sdB + hdB[p], 0.2f));
    wsumB += w;
    accB += w * HB[(size_t)s * 64 + lane];
  }
  out[(size_t)wid * 64 + lane] =
      accA / wsumA + biasA[lane] + accB / wsumB + biasB[lane];
}

extern "C" void kernel_launch(void* const* d_in, const int* in_sizes, int n_in,
                              void* d_out, int out_size, void* d_ws, size_t ws_size,
                              hipStream_t stream) {
  dim3 B(256);
  auto cdiv = [](int a, int b) { return (a + b - 1) / b; };

  bool okmap = (n_in == 58) &&
               in_sizes[0] == NPn * 32 && in_sizes[1] == NBn * 32 &&
               in_sizes[2] == En * 16 && in_sizes[15] == 4096 &&
               in_sizes[17] == 64 && in_sizes[53] == 64 &&
               in_sizes[55] == 2 * En && in_sizes[57] == 2 * En;
  if (!okmap) {
    fill_kernel<<<cdiv(NPn, 256), B, 0, stream>>>((float*)d_out, 1000.0f, NPn);
    return;
  }

  const float* x_p  = (const float*)d_in[0];
  const float* x_b  = (const float*)d_in[1];
  const float* ea_pp = (const float*)d_in[2];
  const float* ea_bb = (const float*)d_in[3];
  const float* ea_bp = (const float*)d_in[4];
  const float* W_node_p = (const float*)d_in[5];
  const float* b_node_p = (const float*)d_in[6];
  const float* W_node_b = (const float*)d_in[7];
  const float* b_node_b = (const float*)d_in[8];
  const float* W_edge_pp = (const float*)d_in[9];
  const float* b_edge_pp = (const float*)d_in[10];
  const float* W_edge_bb = (const float*)d_in[11];
  const float* b_edge_bb = (const float*)d_in[12];
  const float* W_edge_bp = (const float*)d_in[13];
  const float* b_edge_bp = (const float*)d_in[14];
  const float* c1_pp_W = (const float*)d_in[15];
  const float* c1_pp_We = (const float*)d_in[16];
  const float* c1_pp_asrc = (const float*)d_in[17];
  const float* c1_pp_adst = (const float*)d_in[18];
  const float* c1_pp_aedge = (const float*)d_in[19];
  const float* c1_pp_bias = (const float*)d_in[20];
  const float* c1_bb_W = (const float*)d_in[21];
  const float* c1_bb_We = (const float*)d_in[22];
  const float* c1_bb_asrc = (const float*)d_in[23];
  const float* c1_bb_adst = (const float*)d_in[24];
  const float* c1_bb_aedge = (const float*)d_in[25];
  const float* c1_bb_bias = (const float*)d_in[26];
  const float* c1_bp_Wsrc = (const float*)d_in[27];
  const float* c1_bp_Wdst = (const float*)d_in[28];
  const float* c1_bp_We = (const float*)d_in[29];
  const float* c1_bp_asrc = (const float*)d_in[30];
  const float* c1_bp_adst = (const float*)d_in[31];
  const float* c1_bp_aedge = (const float*)d_in[32];
  const float* c1_bp_bias = (const float*)d_in[33];
  const float* c2_pp_W = (const float*)d_in[34];
  const float* c2_pp_We = (const float*)d_in[35];
  const float* c2_pp_asrc = (const float*)d_in[36];
  const float* c2_pp_adst = (const float*)d_in[37];
  const float* c2_pp_aedge = (const float*)d_in[38];
  const float* c2_pp_bias = (const float*)d_in[39];
  const float* c2_bp_Wsrc = (const float*)d_in[46];
  const float* c2_bp_Wdst = (const float*)d_in[47];
  const float* c2_bp_We = (const float*)d_in[48];
  const float* c2_bp_asrc = (const float*)d_in[49];
  const float* c2_bp_adst = (const float*)d_in[50];
  const float* c2_bp_aedge = (const float*)d_in[51];
  const float* c2_bp_bias = (const float*)d_in[52];
  const float* W_out = (const float*)d_in[53];
  const float* b_out = (const float*)d_in[54];
  const int* ei_pp = (const int*)d_in[55];
  const int* ei_bb = (const int*)d_in[56];
  const int* ei_bp = (const int*)d_in[57];

  // ---- workspace layout
  float* ws = (float*)d_ws;
  int* offs_cat = (int*)ws;                  // NCAT
  int* cnt_cat  = offs_cat + NCAT;           // NCAT
  int* bsum     = cnt_cat + NCAT;            // pad 2560
  int* srcs_cat = bsum + 2560;               // 3*En
  int* pos_cat  = srcs_cat + 3 * En;         // 3*En
  float* xp    = (float*)(pos_cat + 3 * En); // NPn*64
  float* p1    = xp + (size_t)NPn * 64;      // NPn*64
  float* b1v   = p1 + (size_t)NPn * 64;      // NBn*64
  float* hbuf  = b1v + (size_t)NBn * 64;     // NBn*64
  float* hd_pp1 = hbuf + (size_t)NBn * 64;   // En x5 (CSR order)
  float* hd_pp2 = hd_pp1 + En;
  float* hd_bb1 = hd_pp2 + En;
  float* hd_bp1 = hd_bb1 + En;
  float* hd_bp2 = hd_bp1 + En;
  float* sA_src = hd_bp2 + En;               // NBn
  float* sA_dst = sA_src + NBn;              // NBn
  float* sB_src = sA_dst + NBn;              // NBn
  float* sB_dst = sB_src + NBn;              // NPn
  float* sC_src = sB_dst + NPn;              // NBn
  float* sC_dst = sC_src + NBn;              // NBn
  float* small  = sC_dst + NBn;              // 1024
  float* p2     = xp;

  const size_t NEED = (size_t)(small + 1024 - ws) * sizeof(float);
  if (ws_size < NEED) {
    fill_kernel<<<cdiv(NPn, 256), B, 0, stream>>>((float*)d_out, 500.0f, NPn);
    return;
  }

  float* sacc    = small + 0;    // [3]
  float* wa_pp1  = small + 128;  float* wa_pp2  = small + 192;
  float* wa_bb1  = small + 256;  float* wa_bp1  = small + 320; float* wa_bp2 = small + 384;
  float* wd1     = small + 448;  float* wd2     = small + 512;
  float* self_pp1= small + 576;  float* self_pp2= small + 577; float* self_bb1 = small + 578;
  const float invE = 1.0f / (float)En;

  hipMemsetAsync(sacc, 0, 16 * sizeof(float), stream);

  // ---- collapsed attention vectors (before hgemm needs wd1)
  RowdotJobs RJ;
  RJ.M[0] = c1_pp_We;  RJ.v[0] = c1_pp_aedge; RJ.out[0] = wa_pp1;
  RJ.M[1] = c2_pp_We;  RJ.v[1] = c2_pp_aedge; RJ.out[1] = wa_pp2;
  RJ.M[2] = c1_bb_We;  RJ.v[2] = c1_bb_aedge; RJ.out[2] = wa_bb1;
  RJ.M[3] = c1_bp_We;  RJ.v[3] = c1_bp_aedge; RJ.out[3] = wa_bp1;
  RJ.M[4] = c2_bp_We;  RJ.v[4] = c2_bp_aedge; RJ.out[4] = wa_bp2;
  RJ.M[5] = c1_bp_Wdst; RJ.v[5] = c1_bp_adst; RJ.out[5] = wd1;
  RJ.M[6] = c2_bp_Wdst; RJ.v[6] = c2_bp_adst; RJ.out[6] = wd2;
  rowdot_batch_kernel<<<7, 64, 0, stream>>>(RJ);

  // ---- projections
  proj_kernel<<<cdiv(NPn, 256), B, 0, stream>>>(x_p, W_node_p, b_node_p, xp, NPn);
  proj_kernel<<<cdiv(NBn, 256), B, 0, stream>>>(x_b, W_node_b, b_node_b, hbuf, NBn);

  // ---- batched CSR build
  Dsts DS;
  DS.d[0] = ei_pp + En; DS.d[1] = ei_bp + En; DS.d[2] = ei_bb + En;
  DS.s[0] = ei_pp;      DS.s[1] = ei_bp;      DS.s[2] = ei_bb;
  zero_int_kernel<<<cdiv(NCAT, 256), B, 0, stream>>>(cnt_cat, NCAT);
  hist_all_kernel<<<cdiv(3 * En, 256), B, 0, stream>>>(DS, cnt_cat);
  scan1_kernel<<<NB_TOT, B, 0, stream>>>(cnt_cat, offs_cat, bsum, NCAT);
  scan2_kernel<<<1, 64, 0, stream>>>(bsum);
  scan3_kernel<<<NB_TOT, B, 0, stream>>>(cnt_cat, offs_cat, bsum, NCAT);
  copy_int_kernel<<<cdiv(NCAT, 256), B, 0, stream>>>(offs_cat, cnt_cat, NCAT);
  scatter_all_kernel<<<cdiv(3 * En, 256), B, 0, stream>>>(DS, cnt_cat, srcs_cat, pos_cat);

  const int* offs_pp = offs_cat + OFF_PP;
  const int* offs_bp = offs_cat + OFF_BP;
  const int* offs_bb = offs_cat + OFF_BB;
  const int* srcs_pp = srcs_cat;
  const int* srcs_bp = srcs_cat + En;
  const int* srcs_bb = srcs_cat + 2 * En;

  // ---- edge scalars (CSR-ordered outputs), relation order pp, bb, bp
  EdgeJobs EJ;
  EJ.EA[0] = ea_pp; EJ.We[0] = W_edge_pp; EJ.be[0] = b_edge_pp;
  EJ.wa1[0] = wa_pp1; EJ.wa2[0] = wa_pp2; EJ.hd1[0] = hd_pp1; EJ.hd2[0] = hd_pp2;
  EJ.pos[0] = pos_cat;
  EJ.EA[1] = ea_bb; EJ.We[1] = W_edge_bb; EJ.be[1] = b_edge_bb;
  EJ.wa1[1] = wa_bb1; EJ.wa2[1] = nullptr; EJ.hd1[1] = hd_bb1; EJ.hd2[1] = nullptr;
  EJ.pos[1] = pos_cat + 2 * En;
  EJ.EA[2] = ea_bp; EJ.We[2] = W_edge_bp; EJ.be[2] = b_edge_bp;
  EJ.wa1[2] = wa_bp1; EJ.wa2[2] = wa_bp2; EJ.hd1[2] = hd_bp1; EJ.hd2[2] = hd_bp2;
  EJ.pos[2] = pos_cat + En;
  edge_fused_kernel<<<3 * 512, B, 0, stream>>>(EJ, sacc);

  selfscale_kernel<<<1, 64, 0, stream>>>(sacc, invE, self_pp1, self_pp2, self_bb1);

  // ---- conv1 ----
  // pp: H in-place into xp; S3 = original_xp . wd1 -> sB_dst (bp's s_dst)
  hgemm_kernel<<<cdiv(NPn, 256), B, 0, stream>>>(xp, c1_pp_W, c1_pp_asrc, c1_pp_adst,
      wd1, xp, sA_src, sA_dst, sB_dst, NPn);
  // b-side: one pass -> bp H in b1v (+sB_src), bb H in-place hbuf (+sC_src,sC_dst)
  hgemm2_kernel<<<cdiv(NBn, 256), B, 0, stream>>>(hbuf, c1_bp_Wsrc, c1_bp_asrc,
      c1_bb_W, c1_bb_asrc, c1_bb_adst, b1v, sB_src, sC_src, sC_dst, NBn);
  // merged pp+bp -> p1
  gat_row2_kernel<<<cdiv(NPn * 64, 256), B, 0, stream>>>(
      offs_pp, srcs_pp, sA_src, sA_dst, hd_pp1, self_pp1, xp, c1_pp_bias,
      offs_bp, srcs_bp, sB_src, sB_dst, hd_bp1, b1v, c1_bp_bias, p1, NPn);
  // bb -> b1v (overwrites b1v after gat_row2 consumed it)
  gat_row_kernel<<<cdiv(NBn * 64, 256), B, 0, stream>>>(offs_bb, srcs_bb, sC_src, sC_dst,
      hd_bb1, self_bb1, hbuf, c1_bb_bias, b1v, NBn);

  // ---- conv2 ----
  // pp: p1 -> hbuf; S3 = p1 . wd2 -> sB_dst
  hgemm_kernel<<<cdiv(NPn, 256), B, 0, stream>>>(p1, c2_pp_W, c2_pp_asrc, c2_pp_adst,
      wd2, hbuf, sA_src, sA_dst, sB_dst, NPn);
  // bp: b1v in-place
  hgemm_kernel<<<cdiv(NBn, 256), B, 0, stream>>>(b1v, c2_bp_Wsrc, c2_bp_asrc, nullptr,
      nullptr, b1v, sB_src, nullptr, nullptr, NBn);
  gat_row2_kernel<<<cdiv(NPn * 64, 256), B, 0, stream>>>(
      offs_pp, srcs_pp, sA_src, sA_dst, hd_pp2, self_pp2, hbuf, c2_pp_bias,
      offs_bp, srcs_bp, sB_src, sB_dst, hd_bp2, b1v, c2_bp_bias, p2, NPn);

  // ---- head
  head_kernel<<<cdiv(NPn, 256), B, 0, stream>>>(p2, W_out, b_out, (float*)d_out, NPn);
}

// Round 19
// 1436.789 us; speedup vs baseline: 1.8604x; 1.0345x over previous
//
#include <hip/hip_runtime.h>

// ---------------------------------------------------------------------------
// HeteroGNN (2-layer hetero GAT) forward on MI355X — round 19.
// vs round 18 (passed, 1486us):
//  (1) edge_fused: per-WAVE private 32-edge LDS slices — zero block barriers
//      in the hot loop (was ~24); same quarter-wave compute layout.
//  (2) conv2's gat_row2 fused with the head (gat_row2h): final row stays in
//      registers, dot(W_out) via shuffles — deletes head launch + p2 traffic.
// ---------------------------------------------------------------------------

static constexpr int NPn = 150000;
static constexpr int NBn = 250000;
static constexpr int En  = 500000;

// concatenated CSR layout (256-aligned segments); relation order: pp, bp, bb
static constexpr int OFF_PP = 0;
static constexpr int OFF_BP = 150016;
static constexpr int OFF_BB = 300032;
static constexpr int NCAT   = 550144;
static constexpr int NB_TOT = NCAT / 256;
static constexpr int BS_BP  = OFF_BP / 256;
static constexpr int BS_BB  = OFF_BB / 256;

__device__ __forceinline__ float lrelu(float x, float s) { return x >= 0.0f ? x : s * x; }

__global__ void fill_kernel(float* out, float val, int n) {
  int i = blockIdx.x * blockDim.x + threadIdx.x;
  if (i < n) out[i] = val;
}

// ---------------- batched CSR build ----------------
struct Dsts { const int* d[3]; const int* s[3]; };

__global__ void zero_int_kernel(int* p, int n) {
  int i = blockIdx.x * blockDim.x + threadIdx.x;
  if (i < n) p[i] = 0;
}

__global__ void hist_all_kernel(Dsts ds, int* __restrict__ cnt) {
  int t = blockIdx.x * blockDim.x + threadIdx.x;
  if (t >= 3 * En) return;
  int rel = t / En, e = t - rel * En;
  int base = (rel == 0) ? OFF_PP : (rel == 1) ? OFF_BP : OFF_BB;
  atomicAdd(&cnt[base + ds.d[rel][e]], 1);
}

__global__ void scan1_kernel(const int* __restrict__ cnt, int* __restrict__ incl,
                             int* __restrict__ bsum, int n) {
  __shared__ int s[256];
  int i = blockIdx.x * 256 + threadIdx.x;
  s[threadIdx.x] = (i < n) ? cnt[i] : 0;
  __syncthreads();
  for (int o = 1; o < 256; o <<= 1) {
    int t = (threadIdx.x >= o) ? s[threadIdx.x - o] : 0;
    __syncthreads();
    s[threadIdx.x] += t;
    __syncthreads();
  }
  if (i < n) incl[i] = s[threadIdx.x];
  if (threadIdx.x == 255) bsum[blockIdx.x] = s[255];
}

__global__ void scan2_kernel(int* bsum) {
  int t = threadIdx.x;
  if (t >= 3) return;
  int lo = (t == 0) ? 0 : (t == 1) ? BS_BP : BS_BB;
  int hi = (t == 0) ? BS_BP : (t == 1) ? BS_BB : NB_TOT;
  int run = 0;
  for (int i = lo; i < hi; ++i) { int v = bsum[i]; bsum[i] = run; run += v; }
}

__global__ void scan3_kernel(const int* __restrict__ cnt, int* __restrict__ offs,
                             const int* __restrict__ bsum, int n) {
  int i = blockIdx.x * 256 + threadIdx.x;
  if (i < n) offs[i] = offs[i] - cnt[i] + bsum[i >> 8];
}

__global__ void copy_int_kernel(const int* __restrict__ src, int* __restrict__ dstp, int n) {
  int i = blockIdx.x * blockDim.x + threadIdx.x;
  if (i < n) dstp[i] = src[i];
}

__global__ void scatter_all_kernel(Dsts ds, int* __restrict__ cursor,
                                   int* __restrict__ srcs, int* __restrict__ pos) {
  int t = blockIdx.x * blockDim.x + threadIdx.x;
  if (t >= 3 * En) return;
  int rel = t / En, e = t - rel * En;
  int base = (rel == 0) ? OFF_PP : (rel == 1) ? OFF_BP : OFF_BB;
  int p = atomicAdd(&cursor[base + ds.d[rel][e]], 1);
  srcs[rel * En + p] = ds.s[rel][e];
  pos[rel * En + e] = p;
}

// ---------------- dense kernels ----------------
__global__ void proj_kernel(const float* __restrict__ X, const float* __restrict__ W,
                            const float* __restrict__ b, float* __restrict__ Y, int N) {
  __shared__ __align__(16) float Ws[32 * 64];
  __shared__ float bs[64];
  for (int i = threadIdx.x; i < 32 * 64; i += blockDim.x) Ws[i] = W[i];
  if (threadIdx.x < 64) bs[threadIdx.x] = b[threadIdx.x];
  __syncthreads();
  int row = blockIdx.x * blockDim.x + threadIdx.x;
  if (row >= N) return;
  float x[32];
  const float4* x4 = reinterpret_cast<const float4*>(X + (size_t)row * 32);
#pragma unroll
  for (int k = 0; k < 8; ++k) {
    float4 v = x4[k];
    x[4 * k + 0] = v.x; x[4 * k + 1] = v.y; x[4 * k + 2] = v.z; x[4 * k + 3] = v.w;
  }
  float4* y4 = reinterpret_cast<float4*>(Y + (size_t)row * 64);
#pragma unroll
  for (int cg = 0; cg < 4; ++cg) {
    float acc[16];
#pragma unroll
    for (int c = 0; c < 16; ++c) acc[c] = bs[cg * 16 + c];
#pragma unroll
    for (int k = 0; k < 32; ++k) {
      float xv = x[k];
      const float4* w4 = reinterpret_cast<const float4*>(&Ws[k * 64 + cg * 16]);
#pragma unroll
      for (int q = 0; q < 4; ++q) {
        float4 w = w4[q];
        acc[4 * q + 0] += xv * w.x; acc[4 * q + 1] += xv * w.y;
        acc[4 * q + 2] += xv * w.z; acc[4 * q + 3] += xv * w.w;
      }
    }
#pragma unroll
    for (int q = 0; q < 4; ++q)
      y4[cg * 4 + q] = make_float4(lrelu(acc[4 * q + 0], 0.01f), lrelu(acc[4 * q + 1], 0.01f),
                                   lrelu(acc[4 * q + 2], 0.01f), lrelu(acc[4 * q + 3], 0.01f));
  }
}

// H = X @ W; S1=H.a1; optional S2=H.a2; optional S3 = x_in . xv.
// X/H may alias (row-private).
__global__ void hgemm_kernel(const float* X, const float* __restrict__ W,
                             const float* __restrict__ a1, const float* __restrict__ a2,
                             const float* __restrict__ xv,
                             float* H, float* __restrict__ S1,
                             float* __restrict__ S2, float* __restrict__ S3, int N) {
  __shared__ __align__(16) float Ws[64 * 64];
  __shared__ float a1s[64], a2s[64], xvs[64];
  for (int i = threadIdx.x; i < 64 * 64; i += blockDim.x) Ws[i] = W[i];
  if (threadIdx.x < 64) {
    a1s[threadIdx.x] = a1[threadIdx.x];
    a2s[threadIdx.x] = a2 ? a2[threadIdx.x] : 0.0f;
    xvs[threadIdx.x] = xv ? xv[threadIdx.x] : 0.0f;
  }
  __syncthreads();
  int row = blockIdx.x * blockDim.x + threadIdx.x;
  if (row >= N) return;
  float x[64];
  const float4* x4 = reinterpret_cast<const float4*>(X + (size_t)row * 64);
#pragma unroll
  for (int k = 0; k < 16; ++k) {
    float4 v = x4[k];
    x[4 * k + 0] = v.x; x[4 * k + 1] = v.y; x[4 * k + 2] = v.z; x[4 * k + 3] = v.w;
  }
  if (S3) {
    float s3 = 0.0f;
#pragma unroll
    for (int k = 0; k < 64; ++k) s3 += x[k] * xvs[k];
    S3[row] = s3;
  }
  float4* h4 = reinterpret_cast<float4*>(H + (size_t)row * 64);
  float s1 = 0.0f, s2 = 0.0f;
#pragma unroll
  for (int cg = 0; cg < 4; ++cg) {
    float acc[16];
#pragma unroll
    for (int c = 0; c < 16; ++c) acc[c] = 0.0f;
#pragma unroll
    for (int k = 0; k < 64; ++k) {
      float xvv = x[k];
      const float4* w4 = reinterpret_cast<const float4*>(&Ws[k * 64 + cg * 16]);
#pragma unroll
      for (int q = 0; q < 4; ++q) {
        float4 w = w4[q];
        acc[4 * q + 0] += xvv * w.x; acc[4 * q + 1] += xvv * w.y;
        acc[4 * q + 2] += xvv * w.z; acc[4 * q + 3] += xvv * w.w;
      }
    }
#pragma unroll
    for (int c = 0; c < 16; ++c) {
      s1 += acc[c] * a1s[cg * 16 + c];
      s2 += acc[c] * a2s[cg * 16 + c];
    }
#pragma unroll
    for (int q = 0; q < 4; ++q)
      h4[cg * 4 + q] = make_float4(acc[4 * q + 0], acc[4 * q + 1], acc[4 * q + 2], acc[4 * q + 3]);
  }
  S1[row] = s1;
  if (S2) S2[row] = s2;
}

// One pass over X: H1 = X@W1 (-> H1out, S1a=H1.a1a) and H2 = X@W2
// (-> X in-place, S2a=H2.a2a, S2b=H2.a2b). Row-private.
__global__ void hgemm2_kernel(float* X, const float* __restrict__ W1,
                              const float* __restrict__ a1a,
                              const float* __restrict__ W2,
                              const float* __restrict__ a2a, const float* __restrict__ a2b,
                              float* __restrict__ H1out,
                              float* __restrict__ S1a, float* __restrict__ S2a,
                              float* __restrict__ S2b, int N) {
  __shared__ __align__(16) float W1s[64 * 64];
  __shared__ __align__(16) float W2s[64 * 64];
  __shared__ float v1[64], v2a[64], v2b[64];
  for (int i = threadIdx.x; i < 64 * 64; i += blockDim.x) { W1s[i] = W1[i]; W2s[i] = W2[i]; }
  if (threadIdx.x < 64) {
    v1[threadIdx.x] = a1a[threadIdx.x];
    v2a[threadIdx.x] = a2a[threadIdx.x];
    v2b[threadIdx.x] = a2b[threadIdx.x];
  }
  __syncthreads();
  int row = blockIdx.x * blockDim.x + threadIdx.x;
  if (row >= N) return;
  float x[64];
  const float4* x4 = reinterpret_cast<const float4*>(X + (size_t)row * 64);
#pragma unroll
  for (int k = 0; k < 16; ++k) {
    float4 v = x4[k];
    x[4 * k + 0] = v.x; x[4 * k + 1] = v.y; x[4 * k + 2] = v.z; x[4 * k + 3] = v.w;
  }
  {
    float4* h4 = reinterpret_cast<float4*>(H1out + (size_t)row * 64);
    float s1 = 0.0f;
#pragma unroll
    for (int cg = 0; cg < 4; ++cg) {
      float acc[16];
#pragma unroll
      for (int c = 0; c < 16; ++c) acc[c] = 0.0f;
#pragma unroll
      for (int k = 0; k < 64; ++k) {
        float xv = x[k];
        const float4* w4 = reinterpret_cast<const float4*>(&W1s[k * 64 + cg * 16]);
#pragma unroll
        for (int q = 0; q < 4; ++q) {
          float4 w = w4[q];
          acc[4 * q + 0] += xv * w.x; acc[4 * q + 1] += xv * w.y;
          acc[4 * q + 2] += xv * w.z; acc[4 * q + 3] += xv * w.w;
        }
      }
#pragma unroll
      for (int c = 0; c < 16; ++c) s1 += acc[c] * v1[cg * 16 + c];
#pragma unroll
      for (int q = 0; q < 4; ++q)
        h4[cg * 4 + q] = make_float4(acc[4 * q + 0], acc[4 * q + 1], acc[4 * q + 2], acc[4 * q + 3]);
    }
    S1a[row] = s1;
  }
  {
    float4* h4 = reinterpret_cast<float4*>(X + (size_t)row * 64);
    float sa = 0.0f, sb = 0.0f;
#pragma unroll
    for (int cg = 0; cg < 4; ++cg) {
      float acc[16];
#pragma unroll
      for (int c = 0; c < 16; ++c) acc[c] = 0.0f;
#pragma unroll
      for (int k = 0; k < 64; ++k) {
        float xv = x[k];
        const float4* w4 = reinterpret_cast<const float4*>(&W2s[k * 64 + cg * 16]);
#pragma unroll
        for (int q = 0; q < 4; ++q) {
          float4 w = w4[q];
          acc[4 * q + 0] += xv * w.x; acc[4 * q + 1] += xv * w.y;
          acc[4 * q + 2] += xv * w.z; acc[4 * q + 3] += xv * w.w;
        }
      }
#pragma unroll
      for (int c = 0; c < 16; ++c) {
        sa += acc[c] * v2a[cg * 16 + c];
        sb += acc[c] * v2b[cg * 16 + c];
      }
#pragma unroll
      for (int q = 0; q < 4; ++q)
        h4[cg * 4 + q] = make_float4(acc[4 * q + 0], acc[4 * q + 1], acc[4 * q + 2], acc[4 * q + 3]);
    }
    S2a[row] = sa;
    S2b[row] = sb;
  }
}

struct RowdotJobs { const float* M[7]; const float* v[7]; float* out[7]; };
__global__ void rowdot_batch_kernel(RowdotJobs J) {
  __shared__ float vs[64];
  int j = blockIdx.x;
  vs[threadIdx.x] = J.v[j][threadIdx.x];
  __syncthreads();
  float s = 0.0f;
  const float* M = J.M[j];
#pragma unroll
  for (int c = 0; c < 64; ++c) s += M[threadIdx.x * 64 + c] * vs[c];
  J.out[j][threadIdx.x] = s;
}

// ---------------- quarter-wave edge kernel, per-wave LDS slices -------------
// Each wave stages its own 32-edge tile into a private 2KB LDS slice — no
// block barriers in the hot loop (same-wave ds ordering via lgkmcnt).
struct EdgeJobs {
  const float* EA[3]; const float* We[3]; const float* be[3];
  const float* wa1[3]; const float* wa2[3]; float* hd1[3]; float* hd2[3];
  const int* pos[3];
};
__global__ __launch_bounds__(256, 2) void edge_fused_kernel(EdgeJobs J,
                                                            float* __restrict__ sacc) {
  int rel = blockIdx.x >> 9;          // 512 blocks per relation (order pp, bb, bp)
  int blk = blockIdx.x & 511;
  __shared__ float eas[4][32 * 16];   // per-wave slices
  __shared__ float red1[4], red2[4];
  bool has2 = (J.wa2[rel] != nullptr);
  int lane = threadIdx.x & 63;
  int wv   = threadIdx.x >> 6;
  int qd   = lane >> 4;               // quarter
  int sl   = lane & 15;               // sublane: columns sl*4..sl*4+3
  float* myeas = eas[wv];
  float wreg[16][4];
  const float* We = J.We[rel];
#pragma unroll
  for (int k = 0; k < 16; ++k) {
    float4 w = *reinterpret_cast<const float4*>(&We[k * 64 + sl * 4]);
    wreg[k][0] = w.x; wreg[k][1] = w.y; wreg[k][2] = w.z; wreg[k][3] = w.w;
  }
  float4 bc = *reinterpret_cast<const float4*>(&J.be[rel][sl * 4]);
  float4 w1c = *reinterpret_cast<const float4*>(&J.wa1[rel][sl * 4]);
  float4 w2c = has2 ? *reinterpret_cast<const float4*>(&J.wa2[rel][sl * 4])
                    : make_float4(0.f, 0.f, 0.f, 0.f);
  const float* EA = J.EA[rel];
  float* hd1 = J.hd1[rel];
  float* hd2 = J.hd2[rel];
  const int* pos = J.pos[rel];
  float s1 = 0.0f, s2 = 0.0f;
  // wave-strided 32-edge tiles: 512 blocks x 4 waves x 32 edges = 65536/sweep
  for (int base = (blk * 4 + wv) * 32; base < En; base += 512 * 4 * 32) {
    int tile = min(32, En - base);
    float4* d4 = reinterpret_cast<float4*>(myeas);
    const float4* s4 = reinterpret_cast<const float4*>(EA + (size_t)base * 16);
    for (int i = lane; i < tile * 4; i += 64) d4[i] = s4[i];
    // same-wave LDS write->read: compiler-inserted lgkmcnt orders this
#pragma unroll
    for (int it = 0; it < 8; ++it) {
      int e = it * 4 + qd;
      if (e < tile) {
        float t0 = bc.x, t1 = bc.y, t2 = bc.z, t3 = bc.w;
#pragma unroll
        for (int k = 0; k < 16; ++k) {
          float xv = myeas[e * 16 + k];
          t0 += xv * wreg[k][0]; t1 += xv * wreg[k][1];
          t2 += xv * wreg[k][2]; t3 += xv * wreg[k][3];
        }
        t0 = lrelu(t0, 0.01f); t1 = lrelu(t1, 0.01f);
        t2 = lrelu(t2, 0.01f); t3 = lrelu(t3, 0.01f);
        float d1 = t0 * w1c.x + t1 * w1c.y + t2 * w1c.z + t3 * w1c.w;
        float d2 = t0 * w2c.x + t1 * w2c.y + t2 * w2c.z + t3 * w2c.w;
#pragma unroll
        for (int o = 1; o < 16; o <<= 1) {
          d1 += __shfl_xor(d1, o, 64);
          d2 += __shfl_xor(d2, o, 64);
        }
        if (sl == 0) {
          int p = pos[base + e];
          hd1[p] = d1;
          if (has2) hd2[p] = d2;
          s1 += d1;
          s2 += d2;
        }
      }
    }
  }
  if (rel < 2) {
#pragma unroll
    for (int o = 32; o >= 1; o >>= 1) {
      s1 += __shfl_xor(s1, o, 64);
      s2 += __shfl_xor(s2, o, 64);
    }
    if (lane == 0) { red1[wv] = s1; red2[wv] = s2; }
    __syncthreads();
    if (threadIdx.x == 0) {
      float t1 = red1[0] + red1[1] + red1[2] + red1[3];
      float t2 = red2[0] + red2[1] + red2[2] + red2[3];
      if (rel == 0) {
        atomicAdd(&sacc[0], t1);
        atomicAdd(&sacc[1], t2);
      } else {
        atomicAdd(&sacc[2], t1);
      }
    }
  }
}

__global__ void selfscale_kernel(const float* __restrict__ sacc, float invE,
                                 float* __restrict__ self_pp1, float* __restrict__ self_pp2,
                                 float* __restrict__ self_bb1) {
  if (threadIdx.x == 0) {
    self_pp1[0] = sacc[0] * invE;
    self_pp2[0] = sacc[1] * invE;
    self_bb1[0] = sacc[2] * invE;
  }
}

// ---------------- fused per-row GAT kernels ----------------
__global__ void gat_row_kernel(const int* __restrict__ offs, const int* __restrict__ srcs,
                               const float* __restrict__ ssrc, const float* __restrict__ sdst,
                               const float* __restrict__ hd, const float* __restrict__ selfhd,
                               const float* __restrict__ H, const float* __restrict__ bias,
                               float* __restrict__ out, int N) {
  int wid = (int)(((size_t)blockIdx.x * blockDim.x + threadIdx.x) >> 6);
  int lane = threadIdx.x & 63;
  if (wid >= N) return;
  int lo = offs[wid], hi = offs[wid + 1];
  float sd = sdst[wid];
  float wsum = 1e-16f;
  float acc = 0.0f;
  if (selfhd) {
    float wself = __expf(lrelu(ssrc[wid] + sd + selfhd[0], 0.2f));
    wsum += wself;
    acc = wself * H[(size_t)wid * 64 + lane];
  }
  for (int p = lo; p < hi; ++p) {
    int s = srcs[p];
    float w = __expf(lrelu(ssrc[s] + sd + hd[p], 0.2f));
    wsum += w;
    acc += w * H[(size_t)s * 64 + lane];
  }
  out[(size_t)wid * 64 + lane] = acc / wsum + bias[lane];
}

__global__ void gat_row2_kernel(
    const int* __restrict__ offsA, const int* __restrict__ srcsA,
    const float* __restrict__ ssrcA, const float* __restrict__ sdstA,
    const float* __restrict__ hdA, const float* __restrict__ selfhdA,
    const float* __restrict__ HA, const float* __restrict__ biasA,
    const int* __restrict__ offsB, const int* __restrict__ srcsB,
    const float* __restrict__ ssrcB, const float* __restrict__ sdstB,
    const float* __restrict__ hdB, const float* __restrict__ HB,
    const float* __restrict__ biasB,
    float* __restrict__ out, int N) {
  int wid = (int)(((size_t)blockIdx.x * blockDim.x + threadIdx.x) >> 6);
  int lane = threadIdx.x & 63;
  if (wid >= N) return;
  int lo = offsA[wid], hi = offsA[wid + 1];
  float sd = sdstA[wid];
  float wself = __expf(lrelu(ssrcA[wid] + sd + selfhdA[0], 0.2f));
  float wsumA = 1e-16f + wself;
  float accA = wself * HA[(size_t)wid * 64 + lane];
  for (int p = lo; p < hi; ++p) {
    int s = srcsA[p];
    float w = __expf(lrelu(ssrcA[s] + sd + hdA[p], 0.2f));
    wsumA += w;
    accA += w * HA[(size_t)s * 64 + lane];
  }
  lo = offsB[wid]; hi = offsB[wid + 1];
  float sdB = sdstB[wid];
  float wsumB = 1e-16f;
  float accB = 0.0f;
  for (int p = lo; p < hi; ++p) {
    int s = srcsB[p];
    float w = __expf(lrelu(ssrcB[s] + sdB + hdB[p], 0.2f));
    wsumB += w;
    accB += w * HB[(size_t)s * 64 + lane];
  }
  out[(size_t)wid * 64 + lane] =
      accA / wsumA + biasA[lane] + accB / wsumB + biasB[lane];
}

// dual-relation GAT with fused head: out[wid] = (row . wout) + bout[0]
__global__ void gat_row2h_kernel(
    const int* __restrict__ offsA, const int* __restrict__ srcsA,
    const float* __restrict__ ssrcA, const float* __restrict__ sdstA,
    const float* __restrict__ hdA, const float* __restrict__ selfhdA,
    const float* __restrict__ HA, const float* __restrict__ biasA,
    const int* __restrict__ offsB, const int* __restrict__ srcsB,
    const float* __restrict__ ssrcB, const float* __restrict__ sdstB,
    const float* __restrict__ hdB, const float* __restrict__ HB,
    const float* __restrict__ biasB,
    const float* __restrict__ wout, const float* __restrict__ bout,
    float* __restrict__ out, int N) {
  int wid = (int)(((size_t)blockIdx.x * blockDim.x + threadIdx.x) >> 6);
  int lane = threadIdx.x & 63;
  if (wid >= N) return;
  int lo = offsA[wid], hi = offsA[wid + 1];
  float sd = sdstA[wid];
  float wself = __expf(lrelu(ssrcA[wid] + sd + selfhdA[0], 0.2f));
  float wsumA = 1e-16f + wself;
  float accA = wself * HA[(size_t)wid * 64 + lane];
  for (int p = lo; p < hi; ++p) {
    int s = srcsA[p];
    float w = __expf(lrelu(ssrcA[s] + sd + hdA[p], 0.2f));
    wsumA += w;
    accA += w * HA[(size_t)s * 64 + lane];
  }
  lo = offsB[wid]; hi = offsB[wid + 1];
  float sdB = sdstB[wid];
  float wsumB = 1e-16f;
  float accB = 0.0f;
  for (int p = lo; p < hi; ++p) {
    int s = srcsB[p];
    float w = __expf(lrelu(ssrcB[s] + sdB + hdB[p], 0.2f));
    wsumB += w;
    accB += w * HB[(size_t)s * 64 + lane];
  }
  float r = accA / wsumA + biasA[lane] + accB / wsumB + biasB[lane];
  r *= wout[lane];
#pragma unroll
  for (int o = 32; o >= 1; o >>= 1) r += __shfl_xor(r, o, 64);
  if (lane == 0) out[wid] = r + bout[0];
}

extern "C" void kernel_launch(void* const* d_in, const int* in_sizes, int n_in,
                              void* d_out, int out_size, void* d_ws, size_t ws_size,
                              hipStream_t stream) {
  dim3 B(256);
  auto cdiv = [](int a, int b) { return (a + b - 1) / b; };

  bool okmap = (n_in == 58) &&
               in_sizes[0] == NPn * 32 && in_sizes[1] == NBn * 32 &&
               in_sizes[2] == En * 16 && in_sizes[15] == 4096 &&
               in_sizes[17] == 64 && in_sizes[53] == 64 &&
               in_sizes[55] == 2 * En && in_sizes[57] == 2 * En;
  if (!okmap) {
    fill_kernel<<<cdiv(NPn, 256), B, 0, stream>>>((float*)d_out, 1000.0f, NPn);
    return;
  }

  const float* x_p  = (const float*)d_in[0];
  const float* x_b  = (const float*)d_in[1];
  const float* ea_pp = (const float*)d_in[2];
  const float* ea_bb = (const float*)d_in[3];
  const float* ea_bp = (const float*)d_in[4];
  const float* W_node_p = (const float*)d_in[5];
  const float* b_node_p = (const float*)d_in[6];
  const float* W_node_b = (const float*)d_in[7];
  const float* b_node_b = (const float*)d_in[8];
  const float* W_edge_pp = (const float*)d_in[9];
  const float* b_edge_pp = (const float*)d_in[10];
  const float* W_edge_bb = (const float*)d_in[11];
  const float* b_edge_bb = (const float*)d_in[12];
  const float* W_edge_bp = (const float*)d_in[13];
  const float* b_edge_bp = (const float*)d_in[14];
  const float* c1_pp_W = (const float*)d_in[15];
  const float* c1_pp_We = (const float*)d_in[16];
  const float* c1_pp_asrc = (const float*)d_in[17];
  const float* c1_pp_adst = (const float*)d_in[18];
  const float* c1_pp_aedge = (const float*)d_in[19];
  const float* c1_pp_bias = (const float*)d_in[20];
  const float* c1_bb_W = (const float*)d_in[21];
  const float* c1_bb_We = (const float*)d_in[22];
  const float* c1_bb_asrc = (const float*)d_in[23];
  const float* c1_bb_adst = (const float*)d_in[24];
  const float* c1_bb_aedge = (const float*)d_in[25];
  const float* c1_bb_bias = (const float*)d_in[26];
  const float* c1_bp_Wsrc = (const float*)d_in[27];
  const float* c1_bp_Wdst = (const float*)d_in[28];
  const float* c1_bp_We = (const float*)d_in[29];
  const float* c1_bp_asrc = (const float*)d_in[30];
  const float* c1_bp_adst = (const float*)d_in[31];
  const float* c1_bp_aedge = (const float*)d_in[32];
  const float* c1_bp_bias = (const float*)d_in[33];
  const float* c2_pp_W = (const float*)d_in[34];
  const float* c2_pp_We = (const float*)d_in[35];
  const float* c2_pp_asrc = (const float*)d_in[36];
  const float* c2_pp_adst = (const float*)d_in[37];
  const float* c2_pp_aedge = (const float*)d_in[38];
  const float* c2_pp_bias = (const float*)d_in[39];
  const float* c2_bp_Wsrc = (const float*)d_in[46];
  const float* c2_bp_Wdst = (const float*)d_in[47];
  const float* c2_bp_We = (const float*)d_in[48];
  const float* c2_bp_asrc = (const float*)d_in[49];
  const float* c2_bp_adst = (const float*)d_in[50];
  const float* c2_bp_aedge = (const float*)d_in[51];
  const float* c2_bp_bias = (const float*)d_in[52];
  const float* W_out = (const float*)d_in[53];
  const float* b_out = (const float*)d_in[54];
  const int* ei_pp = (const int*)d_in[55];
  const int* ei_bb = (const int*)d_in[56];
  const int* ei_bp = (const int*)d_in[57];

  // ---- workspace layout
  float* ws = (float*)d_ws;
  int* offs_cat = (int*)ws;                  // NCAT
  int* cnt_cat  = offs_cat + NCAT;           // NCAT
  int* bsum     = cnt_cat + NCAT;            // pad 2560
  int* srcs_cat = bsum + 2560;               // 3*En
  int* pos_cat  = srcs_cat + 3 * En;         // 3*En
  float* xp    = (float*)(pos_cat + 3 * En); // NPn*64
  float* p1    = xp + (size_t)NPn * 64;      // NPn*64
  float* b1v   = p1 + (size_t)NPn * 64;      // NBn*64
  float* hbuf  = b1v + (size_t)NBn * 64;     // NBn*64
  float* hd_pp1 = hbuf + (size_t)NBn * 64;   // En x5 (CSR order)
  float* hd_pp2 = hd_pp1 + En;
  float* hd_bb1 = hd_pp2 + En;
  float* hd_bp1 = hd_bb1 + En;
  float* hd_bp2 = hd_bp1 + En;
  float* sA_src = hd_bp2 + En;               // NBn
  float* sA_dst = sA_src + NBn;              // NBn
  float* sB_src = sA_dst + NBn;              // NBn
  float* sB_dst = sB_src + NBn;              // NPn
  float* sC_src = sB_dst + NPn;              // NBn
  float* sC_dst = sC_src + NBn;              // NBn
  float* small  = sC_dst + NBn;              // 1024

  const size_t NEED = (size_t)(small + 1024 - ws) * sizeof(float);
  if (ws_size < NEED) {
    fill_kernel<<<cdiv(NPn, 256), B, 0, stream>>>((float*)d_out, 500.0f, NPn);
    return;
  }

  float* sacc    = small + 0;    // [3]
  float* wa_pp1  = small + 128;  float* wa_pp2  = small + 192;
  float* wa_bb1  = small + 256;  float* wa_bp1  = small + 320; float* wa_bp2 = small + 384;
  float* wd1     = small + 448;  float* wd2     = small + 512;
  float* self_pp1= small + 576;  float* self_pp2= small + 577; float* self_bb1 = small + 578;
  const float invE = 1.0f / (float)En;

  hipMemsetAsync(sacc, 0, 16 * sizeof(float), stream);

  // ---- collapsed attention vectors
  RowdotJobs RJ;
  RJ.M[0] = c1_pp_We;  RJ.v[0] = c1_pp_aedge; RJ.out[0] = wa_pp1;
  RJ.M[1] = c2_pp_We;  RJ.v[1] = c2_pp_aedge; RJ.out[1] = wa_pp2;
  RJ.M[2] = c1_bb_We;  RJ.v[2] = c1_bb_aedge; RJ.out[2] = wa_bb1;
  RJ.M[3] = c1_bp_We;  RJ.v[3] = c1_bp_aedge; RJ.out[3] = wa_bp1;
  RJ.M[4] = c2_bp_We;  RJ.v[4] = c2_bp_aedge; RJ.out[4] = wa_bp2;
  RJ.M[5] = c1_bp_Wdst; RJ.v[5] = c1_bp_adst; RJ.out[5] = wd1;
  RJ.M[6] = c2_bp_Wdst; RJ.v[6] = c2_bp_adst; RJ.out[6] = wd2;
  rowdot_batch_kernel<<<7, 64, 0, stream>>>(RJ);

  // ---- projections
  proj_kernel<<<cdiv(NPn, 256), B, 0, stream>>>(x_p, W_node_p, b_node_p, xp, NPn);
  proj_kernel<<<cdiv(NBn, 256), B, 0, stream>>>(x_b, W_node_b, b_node_b, hbuf, NBn);

  // ---- batched CSR build
  Dsts DS;
  DS.d[0] = ei_pp + En; DS.d[1] = ei_bp + En; DS.d[2] = ei_bb + En;
  DS.s[0] = ei_pp;      DS.s[1] = ei_bp;      DS.s[2] = ei_bb;
  zero_int_kernel<<<cdiv(NCAT, 256), B, 0, stream>>>(cnt_cat, NCAT);
  hist_all_kernel<<<cdiv(3 * En, 256), B, 0, stream>>>(DS, cnt_cat);
  scan1_kernel<<<NB_TOT, B, 0, stream>>>(cnt_cat, offs_cat, bsum, NCAT);
  scan2_kernel<<<1, 64, 0, stream>>>(bsum);
  scan3_kernel<<<NB_TOT, B, 0, stream>>>(cnt_cat, offs_cat, bsum, NCAT);
  copy_int_kernel<<<cdiv(NCAT, 256), B, 0, stream>>>(offs_cat, cnt_cat, NCAT);
  scatter_all_kernel<<<cdiv(3 * En, 256), B, 0, stream>>>(DS, cnt_cat, srcs_cat, pos_cat);

  const int* offs_pp = offs_cat + OFF_PP;
  const int* offs_bp = offs_cat + OFF_BP;
  const int* offs_bb = offs_cat + OFF_BB;
  const int* srcs_pp = srcs_cat;
  const int* srcs_bp = srcs_cat + En;
  const int* srcs_bb = srcs_cat + 2 * En;

  // ---- edge scalars (CSR-ordered outputs), relation order pp, bb, bp
  EdgeJobs EJ;
  EJ.EA[0] = ea_pp; EJ.We[0] = W_edge_pp; EJ.be[0] = b_edge_pp;
  EJ.wa1[0] = wa_pp1; EJ.wa2[0] = wa_pp2; EJ.hd1[0] = hd_pp1; EJ.hd2[0] = hd_pp2;
  EJ.pos[0] = pos_cat;
  EJ.EA[1] = ea_bb; EJ.We[1] = W_edge_bb; EJ.be[1] = b_edge_bb;
  EJ.wa1[1] = wa_bb1; EJ.wa2[1] = nullptr; EJ.hd1[1] = hd_bb1; EJ.hd2[1] = nullptr;
  EJ.pos[1] = pos_cat + 2 * En;
  EJ.EA[2] = ea_bp; EJ.We[2] = W_edge_bp; EJ.be[2] = b_edge_bp;
  EJ.wa1[2] = wa_bp1; EJ.wa2[2] = wa_bp2; EJ.hd1[2] = hd_bp1; EJ.hd2[2] = hd_bp2;
  EJ.pos[2] = pos_cat + En;
  edge_fused_kernel<<<3 * 512, B, 0, stream>>>(EJ, sacc);

  selfscale_kernel<<<1, 64, 0, stream>>>(sacc, invE, self_pp1, self_pp2, self_bb1);

  // ---- conv1 ----
  hgemm_kernel<<<cdiv(NPn, 256), B, 0, stream>>>(xp, c1_pp_W, c1_pp_asrc, c1_pp_adst,
      wd1, xp, sA_src, sA_dst, sB_dst, NPn);
  hgemm2_kernel<<<cdiv(NBn, 256), B, 0, stream>>>(hbuf, c1_bp_Wsrc, c1_bp_asrc,
      c1_bb_W, c1_bb_asrc, c1_bb_adst, b1v, sB_src, sC_src, sC_dst, NBn);
  gat_row2_kernel<<<cdiv(NPn * 64, 256), B, 0, stream>>>(
      offs_pp, srcs_pp, sA_src, sA_dst, hd_pp1, self_pp1, xp, c1_pp_bias,
      offs_bp, srcs_bp, sB_src, sB_dst, hd_bp1, b1v, c1_bp_bias, p1, NPn);
  gat_row_kernel<<<cdiv(NBn * 64, 256), B, 0, stream>>>(offs_bb, srcs_bb, sC_src, sC_dst,
      hd_bb1, self_bb1, hbuf, c1_bb_bias, b1v, NBn);

  // ---- conv2 (head fused into gat_row2h; writes d_out scalars directly) ----
  hgemm_kernel<<<cdiv(NPn, 256), B, 0, stream>>>(p1, c2_pp_W, c2_pp_asrc, c2_pp_adst,
      wd2, hbuf, sA_src, sA_dst, sB_dst, NPn);
  hgemm_kernel<<<cdiv(NBn, 256), B, 0, stream>>>(b1v, c2_bp_Wsrc, c2_bp_asrc, nullptr,
      nullptr, b1v, sB_src, nullptr, nullptr, NBn);
  gat_row2h_kernel<<<cdiv(NPn * 64, 256), B, 0, stream>>>(
      offs_pp, srcs_pp, sA_src, sA_dst, hd_pp2, self_pp2, hbuf, c2_pp_bias,
      offs_bp, srcs_bp, sB_src, sB_dst, hd_bp2, b1v, c2_bp_bias,
      W_out, b_out, (float*)d_out, NPn);
}

// Round 20
// 1098.810 us; speedup vs baseline: 2.4326x; 1.3076x over previous
//
#include <hip/hip_runtime.h>

// ---------------------------------------------------------------------------
// HeteroGNN (2-layer hetero GAT) forward on MI355X — round 20.
// vs round 19 (passed, 1437us): GEMM family (proj/hgemm/hgemm2) rebuilt as
// 64-row LDS-tiled kernels — coalesced full-line loads AND stores (round-19
// profile showed 5x fetch / 2x write amplification from the row-per-thread
// layout's partial-sector traffic). Thread (r=tid>>2, q=tid&3) computes a
// 16-col quarter; Xs padded to stride 65 (conflict-free); epilogue scalars
// reduced across the 4 quarter-lanes by 2 shuffles. Everything else = r19.
// ---------------------------------------------------------------------------

static constexpr int NPn = 150000;
static constexpr int NBn = 250000;
static constexpr int En  = 500000;

static constexpr int OFF_PP = 0;
static constexpr int OFF_BP = 150016;
static constexpr int OFF_BB = 300032;
static constexpr int NCAT   = 550144;
static constexpr int NB_TOT = NCAT / 256;
static constexpr int BS_BP  = OFF_BP / 256;
static constexpr int BS_BB  = OFF_BB / 256;

__device__ __forceinline__ float lrelu(float x, float s) { return x >= 0.0f ? x : s * x; }

__global__ void fill_kernel(float* out, float val, int n) {
  int i = blockIdx.x * blockDim.x + threadIdx.x;
  if (i < n) out[i] = val;
}

// ---------------- batched CSR build (unchanged) ----------------
struct Dsts { const int* d[3]; const int* s[3]; };

__global__ void zero_int_kernel(int* p, int n) {
  int i = blockIdx.x * blockDim.x + threadIdx.x;
  if (i < n) p[i] = 0;
}

__global__ void hist_all_kernel(Dsts ds, int* __restrict__ cnt) {
  int t = blockIdx.x * blockDim.x + threadIdx.x;
  if (t >= 3 * En) return;
  int rel = t / En, e = t - rel * En;
  int base = (rel == 0) ? OFF_PP : (rel == 1) ? OFF_BP : OFF_BB;
  atomicAdd(&cnt[base + ds.d[rel][e]], 1);
}

__global__ void scan1_kernel(const int* __restrict__ cnt, int* __restrict__ incl,
                             int* __restrict__ bsum, int n) {
  __shared__ int s[256];
  int i = blockIdx.x * 256 + threadIdx.x;
  s[threadIdx.x] = (i < n) ? cnt[i] : 0;
  __syncthreads();
  for (int o = 1; o < 256; o <<= 1) {
    int t = (threadIdx.x >= o) ? s[threadIdx.x - o] : 0;
    __syncthreads();
    s[threadIdx.x] += t;
    __syncthreads();
  }
  if (i < n) incl[i] = s[threadIdx.x];
  if (threadIdx.x == 255) bsum[blockIdx.x] = s[255];
}

__global__ void scan2_kernel(int* bsum) {
  int t = threadIdx.x;
  if (t >= 3) return;
  int lo = (t == 0) ? 0 : (t == 1) ? BS_BP : BS_BB;
  int hi = (t == 0) ? BS_BP : (t == 1) ? BS_BB : NB_TOT;
  int run = 0;
  for (int i = lo; i < hi; ++i) { int v = bsum[i]; bsum[i] = run; run += v; }
}

__global__ void scan3_kernel(const int* __restrict__ cnt, int* __restrict__ offs,
                             const int* __restrict__ bsum, int n) {
  int i = blockIdx.x * 256 + threadIdx.x;
  if (i < n) offs[i] = offs[i] - cnt[i] + bsum[i >> 8];
}

__global__ void copy_int_kernel(const int* __restrict__ src, int* __restrict__ dstp, int n) {
  int i = blockIdx.x * blockDim.x + threadIdx.x;
  if (i < n) dstp[i] = src[i];
}

__global__ void scatter_all_kernel(Dsts ds, int* __restrict__ cursor,
                                   int* __restrict__ srcs, int* __restrict__ pos) {
  int t = blockIdx.x * blockDim.x + threadIdx.x;
  if (t >= 3 * En) return;
  int rel = t / En, e = t - rel * En;
  int base = (rel == 0) ? OFF_PP : (rel == 1) ? OFF_BP : OFF_BB;
  int p = atomicAdd(&cursor[base + ds.d[rel][e]], 1);
  srcs[rel * En + p] = ds.s[rel][e];
  pos[rel * En + e] = p;
}

// ---------------- tiled dense kernels (coalesced loads AND stores) -----------
// proj: Y[N,64] = lrelu(X[N,32] @ W + b, 0.01). 64-row tiles.
__global__ void proj_kernel(const float* __restrict__ X, const float* __restrict__ W,
                            const float* __restrict__ b, float* __restrict__ Y, int N) {
  __shared__ __align__(16) float Ws[32 * 64];
  __shared__ float Xs[64 * 33];
  __shared__ float bs[64];
  for (int i = threadIdx.x; i < 32 * 64; i += 256) Ws[i] = W[i];
  if (threadIdx.x < 64) bs[threadIdx.x] = b[threadIdx.x];
  int base = blockIdx.x * 64;
  int rows = min(64, N - base);
  // coalesced load: rows*32 floats = rows*8 float4
  {
    const float4* s4 = reinterpret_cast<const float4*>(X + (size_t)base * 32);
    for (int idx = threadIdx.x; idx < rows * 8; idx += 256) {
      float4 v = s4[idx];
      int r = idx >> 3, c4 = idx & 7;
      float* d = &Xs[r * 33 + c4 * 4];
      d[0] = v.x; d[1] = v.y; d[2] = v.z; d[3] = v.w;
    }
  }
  __syncthreads();
  int r = threadIdx.x >> 2, q = threadIdx.x & 3;
  if (r >= rows) return;
  const float4* Ws4 = reinterpret_cast<const float4*>(Ws);
  float acc[16];
  const float4* b4 = reinterpret_cast<const float4*>(&bs[q * 16]);
#pragma unroll
  for (int j = 0; j < 4; ++j) {
    float4 v = b4[j];
    acc[4 * j + 0] = v.x; acc[4 * j + 1] = v.y; acc[4 * j + 2] = v.z; acc[4 * j + 3] = v.w;
  }
#pragma unroll
  for (int k = 0; k < 32; ++k) {
    float xv = Xs[r * 33 + k];
#pragma unroll
    for (int j = 0; j < 4; ++j) {
      float4 w = Ws4[k * 16 + q * 4 + j];
      acc[4 * j + 0] += xv * w.x; acc[4 * j + 1] += xv * w.y;
      acc[4 * j + 2] += xv * w.z; acc[4 * j + 3] += xv * w.w;
    }
  }
  float4* y4 = reinterpret_cast<float4*>(Y + (size_t)(base + r) * 64 + q * 16);
#pragma unroll
  for (int j = 0; j < 4; ++j)
    y4[j] = make_float4(lrelu(acc[4 * j + 0], 0.01f), lrelu(acc[4 * j + 1], 0.01f),
                        lrelu(acc[4 * j + 2], 0.01f), lrelu(acc[4 * j + 3], 0.01f));
}

// hgemm: H = X @ W; S1=H.a1; opt S2=H.a2; opt S3 = x_in.xv. X/H may alias
// (tile staged in LDS before any write; tile is block-private).
__global__ void hgemm_kernel(const float* X, const float* __restrict__ W,
                             const float* __restrict__ a1, const float* __restrict__ a2,
                             const float* __restrict__ xv,
                             float* H, float* __restrict__ S1,
                             float* __restrict__ S2, float* __restrict__ S3, int N) {
  __shared__ __align__(16) float Ws[64 * 64];
  __shared__ float Xs[64 * 65];
  __shared__ float a1s[64], a2s[64], xvs[64];
  for (int i = threadIdx.x; i < 64 * 64; i += 256) Ws[i] = W[i];
  if (threadIdx.x < 64) {
    a1s[threadIdx.x] = a1[threadIdx.x];
    a2s[threadIdx.x] = a2 ? a2[threadIdx.x] : 0.0f;
    xvs[threadIdx.x] = xv ? xv[threadIdx.x] : 0.0f;
  }
  int base = blockIdx.x * 64;
  int rows = min(64, N - base);
  {
    const float4* s4 = reinterpret_cast<const float4*>(X + (size_t)base * 64);
    for (int idx = threadIdx.x; idx < rows * 16; idx += 256) {
      float4 v = s4[idx];
      int r = idx >> 4, c4 = idx & 15;
      float* d = &Xs[r * 65 + c4 * 4];
      d[0] = v.x; d[1] = v.y; d[2] = v.z; d[3] = v.w;
    }
  }
  __syncthreads();
  int r = threadIdx.x >> 2, q = threadIdx.x & 3;
  if (r >= rows) return;
  const float4* Ws4 = reinterpret_cast<const float4*>(Ws);
  float acc[16];
#pragma unroll
  for (int c = 0; c < 16; ++c) acc[c] = 0.0f;
  float s3p = 0.0f;
#pragma unroll
  for (int k = 0; k < 64; ++k) {
    float xval = Xs[r * 65 + k];
#pragma unroll
    for (int j = 0; j < 4; ++j) {
      float4 w = Ws4[k * 16 + q * 4 + j];
      acc[4 * j + 0] += xval * w.x; acc[4 * j + 1] += xval * w.y;
      acc[4 * j + 2] += xval * w.z; acc[4 * j + 3] += xval * w.w;
    }
  }
#pragma unroll
  for (int k = 0; k < 16; ++k) s3p += Xs[r * 65 + q * 16 + k] * xvs[q * 16 + k];
  float s1p = 0.0f, s2p = 0.0f;
#pragma unroll
  for (int c = 0; c < 16; ++c) {
    s1p += acc[c] * a1s[q * 16 + c];
    s2p += acc[c] * a2s[q * 16 + c];
  }
  // reduce across the 4 quarter-lanes (consecutive lanes, same wave)
  s1p += __shfl_xor(s1p, 1, 64); s1p += __shfl_xor(s1p, 2, 64);
  s2p += __shfl_xor(s2p, 1, 64); s2p += __shfl_xor(s2p, 2, 64);
  s3p += __shfl_xor(s3p, 1, 64); s3p += __shfl_xor(s3p, 2, 64);
  // write AFTER reductions (aliasing-safe: all inputs already consumed)
  float4* h4 = reinterpret_cast<float4*>(H + (size_t)(base + r) * 64 + q * 16);
#pragma unroll
  for (int j = 0; j < 4; ++j)
    h4[j] = make_float4(acc[4 * j + 0], acc[4 * j + 1], acc[4 * j + 2], acc[4 * j + 3]);
  if (q == 0) {
    S1[base + r] = s1p;
    if (S2) S2[base + r] = s2p;
    if (S3) S3[base + r] = s3p;
  }
}

// hgemm2: one tile read; H1 = X@W1 -> H1out (S1a=H1.a1a); H2 = X@W2 -> X
// in-place (S2a=H2.a2a, S2b=H2.a2b).
__global__ void hgemm2_kernel(float* X, const float* __restrict__ W1,
                              const float* __restrict__ a1a,
                              const float* __restrict__ W2,
                              const float* __restrict__ a2a, const float* __restrict__ a2b,
                              float* __restrict__ H1out,
                              float* __restrict__ S1a, float* __restrict__ S2a,
                              float* __restrict__ S2b, int N) {
  __shared__ __align__(16) float W1s[64 * 64];
  __shared__ __align__(16) float W2s[64 * 64];
  __shared__ float Xs[64 * 65];
  __shared__ float v1[64], v2a[64], v2b[64];
  for (int i = threadIdx.x; i < 64 * 64; i += 256) { W1s[i] = W1[i]; W2s[i] = W2[i]; }
  if (threadIdx.x < 64) {
    v1[threadIdx.x] = a1a[threadIdx.x];
    v2a[threadIdx.x] = a2a[threadIdx.x];
    v2b[threadIdx.x] = a2b[threadIdx.x];
  }
  int base = blockIdx.x * 64;
  int rows = min(64, N - base);
  {
    const float4* s4 = reinterpret_cast<const float4*>(X + (size_t)base * 64);
    for (int idx = threadIdx.x; idx < rows * 16; idx += 256) {
      float4 v = s4[idx];
      int r = idx >> 4, c4 = idx & 15;
      float* d = &Xs[r * 65 + c4 * 4];
      d[0] = v.x; d[1] = v.y; d[2] = v.z; d[3] = v.w;
    }
  }
  __syncthreads();
  int r = threadIdx.x >> 2, q = threadIdx.x & 3;
  if (r >= rows) return;
  const float4* W1s4 = reinterpret_cast<const float4*>(W1s);
  const float4* W2s4 = reinterpret_cast<const float4*>(W2s);
  float acc1[16], acc2[16];
#pragma unroll
  for (int c = 0; c < 16; ++c) { acc1[c] = 0.0f; acc2[c] = 0.0f; }
#pragma unroll
  for (int k = 0; k < 64; ++k) {
    float xval = Xs[r * 65 + k];
#pragma unroll
    for (int j = 0; j < 4; ++j) {
      float4 w1 = W1s4[k * 16 + q * 4 + j];
      acc1[4 * j + 0] += xval * w1.x; acc1[4 * j + 1] += xval * w1.y;
      acc1[4 * j + 2] += xval * w1.z; acc1[4 * j + 3] += xval * w1.w;
      float4 w2 = W2s4[k * 16 + q * 4 + j];
      acc2[4 * j + 0] += xval * w2.x; acc2[4 * j + 1] += xval * w2.y;
      acc2[4 * j + 2] += xval * w2.z; acc2[4 * j + 3] += xval * w2.w;
    }
  }
  float s1p = 0.0f, sap = 0.0f, sbp = 0.0f;
#pragma unroll
  for (int c = 0; c < 16; ++c) {
    s1p += acc1[c] * v1[q * 16 + c];
    sap += acc2[c] * v2a[q * 16 + c];
    sbp += acc2[c] * v2b[q * 16 + c];
  }
  s1p += __shfl_xor(s1p, 1, 64); s1p += __shfl_xor(s1p, 2, 64);
  sap += __shfl_xor(sap, 1, 64); sap += __shfl_xor(sap, 2, 64);
  sbp += __shfl_xor(sbp, 1, 64); sbp += __shfl_xor(sbp, 2, 64);
  float4* h14 = reinterpret_cast<float4*>(H1out + (size_t)(base + r) * 64 + q * 16);
  float4* h24 = reinterpret_cast<float4*>(X + (size_t)(base + r) * 64 + q * 16);
#pragma unroll
  for (int j = 0; j < 4; ++j) {
    h14[j] = make_float4(acc1[4 * j + 0], acc1[4 * j + 1], acc1[4 * j + 2], acc1[4 * j + 3]);
    h24[j] = make_float4(acc2[4 * j + 0], acc2[4 * j + 1], acc2[4 * j + 2], acc2[4 * j + 3]);
  }
  if (q == 0) {
    S1a[base + r] = s1p;
    S2a[base + r] = sap;
    S2b[base + r] = sbp;
  }
}

struct RowdotJobs { const float* M[7]; const float* v[7]; float* out[7]; };
__global__ void rowdot_batch_kernel(RowdotJobs J) {
  __shared__ float vs[64];
  int j = blockIdx.x;
  vs[threadIdx.x] = J.v[j][threadIdx.x];
  __syncthreads();
  float s = 0.0f;
  const float* M = J.M[j];
#pragma unroll
  for (int c = 0; c < 64; ++c) s += M[threadIdx.x * 64 + c] * vs[c];
  J.out[j][threadIdx.x] = s;
}

// ---------------- quarter-wave edge kernel, per-wave LDS slices (r19) --------
struct EdgeJobs {
  const float* EA[3]; const float* We[3]; const float* be[3];
  const float* wa1[3]; const float* wa2[3]; float* hd1[3]; float* hd2[3];
  const int* pos[3];
};
__global__ __launch_bounds__(256, 2) void edge_fused_kernel(EdgeJobs J,
                                                            float* __restrict__ sacc) {
  int rel = blockIdx.x >> 9;
  int blk = blockIdx.x & 511;
  __shared__ float eas[4][32 * 16];
  __shared__ float red1[4], red2[4];
  bool has2 = (J.wa2[rel] != nullptr);
  int lane = threadIdx.x & 63;
  int wv   = threadIdx.x >> 6;
  int qd   = lane >> 4;
  int sl   = lane & 15;
  float* myeas = eas[wv];
  float wreg[16][4];
  const float* We = J.We[rel];
#pragma unroll
  for (int k = 0; k < 16; ++k) {
    float4 w = *reinterpret_cast<const float4*>(&We[k * 64 + sl * 4]);
    wreg[k][0] = w.x; wreg[k][1] = w.y; wreg[k][2] = w.z; wreg[k][3] = w.w;
  }
  float4 bc = *reinterpret_cast<const float4*>(&J.be[rel][sl * 4]);
  float4 w1c = *reinterpret_cast<const float4*>(&J.wa1[rel][sl * 4]);
  float4 w2c = has2 ? *reinterpret_cast<const float4*>(&J.wa2[rel][sl * 4])
                    : make_float4(0.f, 0.f, 0.f, 0.f);
  const float* EA = J.EA[rel];
  float* hd1 = J.hd1[rel];
  float* hd2 = J.hd2[rel];
  const int* pos = J.pos[rel];
  float s1 = 0.0f, s2 = 0.0f;
  for (int base = (blk * 4 + wv) * 32; base < En; base += 512 * 4 * 32) {
    int tile = min(32, En - base);
    float4* d4 = reinterpret_cast<float4*>(myeas);
    const float4* s4 = reinterpret_cast<const float4*>(EA + (size_t)base * 16);
    for (int i = lane; i < tile * 4; i += 64) d4[i] = s4[i];
#pragma unroll
    for (int it = 0; it < 8; ++it) {
      int e = it * 4 + qd;
      if (e < tile) {
        float t0 = bc.x, t1 = bc.y, t2 = bc.z, t3 = bc.w;
#pragma unroll
        for (int k = 0; k < 16; ++k) {
          float xv = myeas[e * 16 + k];
          t0 += xv * wreg[k][0]; t1 += xv * wreg[k][1];
          t2 += xv * wreg[k][2]; t3 += xv * wreg[k][3];
        }
        t0 = lrelu(t0, 0.01f); t1 = lrelu(t1, 0.01f);
        t2 = lrelu(t2, 0.01f); t3 = lrelu(t3, 0.01f);
        float d1 = t0 * w1c.x + t1 * w1c.y + t2 * w1c.z + t3 * w1c.w;
        float d2 = t0 * w2c.x + t1 * w2c.y + t2 * w2c.z + t3 * w2c.w;
#pragma unroll
        for (int o = 1; o < 16; o <<= 1) {
          d1 += __shfl_xor(d1, o, 64);
          d2 += __shfl_xor(d2, o, 64);
        }
        if (sl == 0) {
          int p = pos[base + e];
          hd1[p] = d1;
          if (has2) hd2[p] = d2;
          s1 += d1;
          s2 += d2;
        }
      }
    }
  }
  if (rel < 2) {
#pragma unroll
    for (int o = 32; o >= 1; o >>= 1) {
      s1 += __shfl_xor(s1, o, 64);
      s2 += __shfl_xor(s2, o, 64);
    }
    if (lane == 0) { red1[wv] = s1; red2[wv] = s2; }
    __syncthreads();
    if (threadIdx.x == 0) {
      float t1 = red1[0] + red1[1] + red1[2] + red1[3];
      float t2 = red2[0] + red2[1] + red2[2] + red2[3];
      if (rel == 0) {
        atomicAdd(&sacc[0], t1);
        atomicAdd(&sacc[1], t2);
      } else {
        atomicAdd(&sacc[2], t1);
      }
    }
  }
}

__global__ void selfscale_kernel(const float* __restrict__ sacc, float invE,
                                 float* __restrict__ self_pp1, float* __restrict__ self_pp2,
                                 float* __restrict__ self_bb1) {
  if (threadIdx.x == 0) {
    self_pp1[0] = sacc[0] * invE;
    self_pp2[0] = sacc[1] * invE;
    self_bb1[0] = sacc[2] * invE;
  }
}

// ---------------- fused per-row GAT kernels (r19) ----------------
__global__ void gat_row_kernel(const int* __restrict__ offs, const int* __restrict__ srcs,
                               const float* __restrict__ ssrc, const float* __restrict__ sdst,
                               const float* __restrict__ hd, const float* __restrict__ selfhd,
                               const float* __restrict__ H, const float* __restrict__ bias,
                               float* __restrict__ out, int N) {
  int wid = (int)(((size_t)blockIdx.x * blockDim.x + threadIdx.x) >> 6);
  int lane = threadIdx.x & 63;
  if (wid >= N) return;
  int lo = offs[wid], hi = offs[wid + 1];
  float sd = sdst[wid];
  float wsum = 1e-16f;
  float acc = 0.0f;
  if (selfhd) {
    float wself = __expf(lrelu(ssrc[wid] + sd + selfhd[0], 0.2f));
    wsum += wself;
    acc = wself * H[(size_t)wid * 64 + lane];
  }
  for (int p = lo; p < hi; ++p) {
    int s = srcs[p];
    float w = __expf(lrelu(ssrc[s] + sd + hd[p], 0.2f));
    wsum += w;
    acc += w * H[(size_t)s * 64 + lane];
  }
  out[(size_t)wid * 64 + lane] = acc / wsum + bias[lane];
}

__global__ void gat_row2_kernel(
    const int* __restrict__ offsA, const int* __restrict__ srcsA,
    const float* __restrict__ ssrcA, const float* __restrict__ sdstA,
    const float* __restrict__ hdA, const float* __restrict__ selfhdA,
    const float* __restrict__ HA, const float* __restrict__ biasA,
    const int* __restrict__ offsB, const int* __restrict__ srcsB,
    const float* __restrict__ ssrcB, const float* __restrict__ sdstB,
    const float* __restrict__ hdB, const float* __restrict__ HB,
    const float* __restrict__ biasB,
    float* __restrict__ out, int N) {
  int wid = (int)(((size_t)blockIdx.x * blockDim.x + threadIdx.x) >> 6);
  int lane = threadIdx.x & 63;
  if (wid >= N) return;
  int lo = offsA[wid], hi = offsA[wid + 1];
  float sd = sdstA[wid];
  float wself = __expf(lrelu(ssrcA[wid] + sd + selfhdA[0], 0.2f));
  float wsumA = 1e-16f + wself;
  float accA = wself * HA[(size_t)wid * 64 + lane];
  for (int p = lo; p < hi; ++p) {
    int s = srcsA[p];
    float w = __expf(lrelu(ssrcA[s] + sd + hdA[p], 0.2f));
    wsumA += w;
    accA += w * HA[(size_t)s * 64 + lane];
  }
  lo = offsB[wid]; hi = offsB[wid + 1];
  float sdB = sdstB[wid];
  float wsumB = 1e-16f;
  float accB = 0.0f;
  for (int p = lo; p < hi; ++p) {
    int s = srcsB[p];
    float w = __expf(lrelu(ssrcB[s] + sdB + hdB[p], 0.2f));
    wsumB += w;
    accB += w * HB[(size_t)s * 64 + lane];
  }
  out[(size_t)wid * 64 + lane] =
      accA / wsumA + biasA[lane] + accB / wsumB + biasB[lane];
}

__global__ void gat_row2h_kernel(
    const int* __restrict__ offsA, const int* __restrict__ srcsA,
    const float* __restrict__ ssrcA, const float* __restrict__ sdstA,
    const float* __restrict__ hdA, const float* __restrict__ selfhdA,
    const float* __restrict__ HA, const float* __restrict__ biasA,
    const int* __restrict__ offsB, const int* __restrict__ srcsB,
    const float* __restrict__ ssrcB, const float* __restrict__ sdstB,
    const float* __restrict__ hdB, const float* __restrict__ HB,
    const float* __restrict__ biasB,
    const float* __restrict__ wout, const float* __restrict__ bout,
    float* __restrict__ out, int N) {
  int wid = (int)(((size_t)blockIdx.x * blockDim.x + threadIdx.x) >> 6);
  int lane = threadIdx.x & 63;
  if (wid >= N) return;
  int lo = offsA[wid], hi = offsA[wid + 1];
  float sd = sdstA[wid];
  float wself = __expf(lrelu(ssrcA[wid] + sd + selfhdA[0], 0.2f));
  float wsumA = 1e-16f + wself;
  float accA = wself * HA[(size_t)wid * 64 + lane];
  for (int p = lo; p < hi; ++p) {
    int s = srcsA[p];
    float w = __expf(lrelu(ssrcA[s] + sd + hdA[p], 0.2f));
    wsumA += w;
    accA += w * HA[(size_t)s * 64 + lane];
  }
  lo = offsB[wid]; hi = offsB[wid + 1];
  float sdB = sdstB[wid];
  float wsumB = 1e-16f;
  float accB = 0.0f;
  for (int p = lo; p < hi; ++p) {
    int s = srcsB[p];
    float w = __expf(lrelu(ssrcB[s] + sdB + hdB[p], 0.2f));
    wsumB += w;
    accB += w * HB[(size_t)s * 64 + lane];
  }
  float r = accA / wsumA + biasA[lane] + accB / wsumB + biasB[lane];
  r *= wout[lane];
#pragma unroll
  for (int o = 32; o >= 1; o >>= 1) r += __shfl_xor(r, o, 64);
  if (lane == 0) out[wid] = r + bout[0];
}

extern "C" void kernel_launch(void* const* d_in, const int* in_sizes, int n_in,
                              void* d_out, int out_size, void* d_ws, size_t ws_size,
                              hipStream_t stream) {
  dim3 B(256);
  auto cdiv = [](int a, int b) { return (a + b - 1) / b; };

  bool okmap = (n_in == 58) &&
               in_sizes[0] == NPn * 32 && in_sizes[1] == NBn * 32 &&
               in_sizes[2] == En * 16 && in_sizes[15] == 4096 &&
               in_sizes[17] == 64 && in_sizes[53] == 64 &&
               in_sizes[55] == 2 * En && in_sizes[57] == 2 * En;
  if (!okmap) {
    fill_kernel<<<cdiv(NPn, 256), B, 0, stream>>>((float*)d_out, 1000.0f, NPn);
    return;
  }

  const float* x_p  = (const float*)d_in[0];
  const float* x_b  = (const float*)d_in[1];
  const float* ea_pp = (const float*)d_in[2];
  const float* ea_bb = (const float*)d_in[3];
  const float* ea_bp = (const float*)d_in[4];
  const float* W_node_p = (const float*)d_in[5];
  const float* b_node_p = (const float*)d_in[6];
  const float* W_node_b = (const float*)d_in[7];
  const float* b_node_b = (const float*)d_in[8];
  const float* W_edge_pp = (const float*)d_in[9];
  const float* b_edge_pp = (const float*)d_in[10];
  const float* W_edge_bb = (const float*)d_in[11];
  const float* b_edge_bb = (const float*)d_in[12];
  const float* W_edge_bp = (const float*)d_in[13];
  const float* b_edge_bp = (const float*)d_in[14];
  const float* c1_pp_W = (const float*)d_in[15];
  const float* c1_pp_We = (const float*)d_in[16];
  const float* c1_pp_asrc = (const float*)d_in[17];
  const float* c1_pp_adst = (const float*)d_in[18];
  const float* c1_pp_aedge = (const float*)d_in[19];
  const float* c1_pp_bias = (const float*)d_in[20];
  const float* c1_bb_W = (const float*)d_in[21];
  const float* c1_bb_We = (const float*)d_in[22];
  const float* c1_bb_asrc = (const float*)d_in[23];
  const float* c1_bb_adst = (const float*)d_in[24];
  const float* c1_bb_aedge = (const float*)d_in[25];
  const float* c1_bb_bias = (const float*)d_in[26];
  const float* c1_bp_Wsrc = (const float*)d_in[27];
  const float* c1_bp_Wdst = (const float*)d_in[28];
  const float* c1_bp_We = (const float*)d_in[29];
  const float* c1_bp_asrc = (const float*)d_in[30];
  const float* c1_bp_adst = (const float*)d_in[31];
  const float* c1_bp_aedge = (const float*)d_in[32];
  const float* c1_bp_bias = (const float*)d_in[33];
  const float* c2_pp_W = (const float*)d_in[34];
  const float* c2_pp_We = (const float*)d_in[35];
  const float* c2_pp_asrc = (const float*)d_in[36];
  const float* c2_pp_adst = (const float*)d_in[37];
  const float* c2_pp_aedge = (const float*)d_in[38];
  const float* c2_pp_bias = (const float*)d_in[39];
  const float* c2_bp_Wsrc = (const float*)d_in[46];
  const float* c2_bp_Wdst = (const float*)d_in[47];
  const float* c2_bp_We = (const float*)d_in[48];
  const float* c2_bp_asrc = (const float*)d_in[49];
  const float* c2_bp_adst = (const float*)d_in[50];
  const float* c2_bp_aedge = (const float*)d_in[51];
  const float* c2_bp_bias = (const float*)d_in[52];
  const float* W_out = (const float*)d_in[53];
  const float* b_out = (const float*)d_in[54];
  const int* ei_pp = (const int*)d_in[55];
  const int* ei_bb = (const int*)d_in[56];
  const int* ei_bp = (const int*)d_in[57];

  // ---- workspace layout
  float* ws = (float*)d_ws;
  int* offs_cat = (int*)ws;                  // NCAT
  int* cnt_cat  = offs_cat + NCAT;           // NCAT
  int* bsum     = cnt_cat + NCAT;            // pad 2560
  int* srcs_cat = bsum + 2560;               // 3*En
  int* pos_cat  = srcs_cat + 3 * En;         // 3*En
  float* xp    = (float*)(pos_cat + 3 * En); // NPn*64
  float* p1    = xp + (size_t)NPn * 64;      // NPn*64
  float* b1v   = p1 + (size_t)NPn * 64;      // NBn*64
  float* hbuf  = b1v + (size_t)NBn * 64;     // NBn*64
  float* hd_pp1 = hbuf + (size_t)NBn * 64;   // En x5 (CSR order)
  float* hd_pp2 = hd_pp1 + En;
  float* hd_bb1 = hd_pp2 + En;
  float* hd_bp1 = hd_bb1 + En;
  float* hd_bp2 = hd_bp1 + En;
  float* sA_src = hd_bp2 + En;               // NBn
  float* sA_dst = sA_src + NBn;              // NBn
  float* sB_src = sA_dst + NBn;              // NBn
  float* sB_dst = sB_src + NBn;              // NPn
  float* sC_src = sB_dst + NPn;              // NBn
  float* sC_dst = sC_src + NBn;              // NBn
  float* small  = sC_dst + NBn;              // 1024

  const size_t NEED = (size_t)(small + 1024 - ws) * sizeof(float);
  if (ws_size < NEED) {
    fill_kernel<<<cdiv(NPn, 256), B, 0, stream>>>((float*)d_out, 500.0f, NPn);
    return;
  }

  float* sacc    = small + 0;
  float* wa_pp1  = small + 128;  float* wa_pp2  = small + 192;
  float* wa_bb1  = small + 256;  float* wa_bp1  = small + 320; float* wa_bp2 = small + 384;
  float* wd1     = small + 448;  float* wd2     = small + 512;
  float* self_pp1= small + 576;  float* self_pp2= small + 577; float* self_bb1 = small + 578;
  const float invE = 1.0f / (float)En;

  hipMemsetAsync(sacc, 0, 16 * sizeof(float), stream);

  RowdotJobs RJ;
  RJ.M[0] = c1_pp_We;  RJ.v[0] = c1_pp_aedge; RJ.out[0] = wa_pp1;
  RJ.M[1] = c2_pp_We;  RJ.v[1] = c2_pp_aedge; RJ.out[1] = wa_pp2;
  RJ.M[2] = c1_bb_We;  RJ.v[2] = c1_bb_aedge; RJ.out[2] = wa_bb1;
  RJ.M[3] = c1_bp_We;  RJ.v[3] = c1_bp_aedge; RJ.out[3] = wa_bp1;
  RJ.M[4] = c2_bp_We;  RJ.v[4] = c2_bp_aedge; RJ.out[4] = wa_bp2;
  RJ.M[5] = c1_bp_Wdst; RJ.v[5] = c1_bp_adst; RJ.out[5] = wd1;
  RJ.M[6] = c2_bp_Wdst; RJ.v[6] = c2_bp_adst; RJ.out[6] = wd2;
  rowdot_batch_kernel<<<7, 64, 0, stream>>>(RJ);

  proj_kernel<<<cdiv(NPn, 64), B, 0, stream>>>(x_p, W_node_p, b_node_p, xp, NPn);
  proj_kernel<<<cdiv(NBn, 64), B, 0, stream>>>(x_b, W_node_b, b_node_b, hbuf, NBn);

  Dsts DS;
  DS.d[0] = ei_pp + En; DS.d[1] = ei_bp + En; DS.d[2] = ei_bb + En;
  DS.s[0] = ei_pp;      DS.s[1] = ei_bp;      DS.s[2] = ei_bb;
  zero_int_kernel<<<cdiv(NCAT, 256), B, 0, stream>>>(cnt_cat, NCAT);
  hist_all_kernel<<<cdiv(3 * En, 256), B, 0, stream>>>(DS, cnt_cat);
  scan1_kernel<<<NB_TOT, B, 0, stream>>>(cnt_cat, offs_cat, bsum, NCAT);
  scan2_kernel<<<1, 64, 0, stream>>>(bsum);
  scan3_kernel<<<NB_TOT, B, 0, stream>>>(cnt_cat, offs_cat, bsum, NCAT);
  copy_int_kernel<<<cdiv(NCAT, 256), B, 0, stream>>>(offs_cat, cnt_cat, NCAT);
  scatter_all_kernel<<<cdiv(3 * En, 256), B, 0, stream>>>(DS, cnt_cat, srcs_cat, pos_cat);

  const int* offs_pp = offs_cat + OFF_PP;
  const int* offs_bp = offs_cat + OFF_BP;
  const int* offs_bb = offs_cat + OFF_BB;
  const int* srcs_pp = srcs_cat;
  const int* srcs_bp = srcs_cat + En;
  const int* srcs_bb = srcs_cat + 2 * En;

  EdgeJobs EJ;
  EJ.EA[0] = ea_pp; EJ.We[0] = W_edge_pp; EJ.be[0] = b_edge_pp;
  EJ.wa1[0] = wa_pp1; EJ.wa2[0] = wa_pp2; EJ.hd1[0] = hd_pp1; EJ.hd2[0] = hd_pp2;
  EJ.pos[0] = pos_cat;
  EJ.EA[1] = ea_bb; EJ.We[1] = W_edge_bb; EJ.be[1] = b_edge_bb;
  EJ.wa1[1] = wa_bb1; EJ.wa2[1] = nullptr; EJ.hd1[1] = hd_bb1; EJ.hd2[1] = nullptr;
  EJ.pos[1] = pos_cat + 2 * En;
  EJ.EA[2] = ea_bp; EJ.We[2] = W_edge_bp; EJ.be[2] = b_edge_bp;
  EJ.wa1[2] = wa_bp1; EJ.wa2[2] = wa_bp2; EJ.hd1[2] = hd_bp1; EJ.hd2[2] = hd_bp2;
  EJ.pos[2] = pos_cat + En;
  edge_fused_kernel<<<3 * 512, B, 0, stream>>>(EJ, sacc);

  selfscale_kernel<<<1, 64, 0, stream>>>(sacc, invE, self_pp1, self_pp2, self_bb1);

  // ---- conv1 ----
  hgemm_kernel<<<cdiv(NPn, 64), B, 0, stream>>>(xp, c1_pp_W, c1_pp_asrc, c1_pp_adst,
      wd1, xp, sA_src, sA_dst, sB_dst, NPn);
  hgemm2_kernel<<<cdiv(NBn, 64), B, 0, stream>>>(hbuf, c1_bp_Wsrc, c1_bp_asrc,
      c1_bb_W, c1_bb_asrc, c1_bb_adst, b1v, sB_src, sC_src, sC_dst, NBn);
  gat_row2_kernel<<<cdiv(NPn * 64, 256), B, 0, stream>>>(
      offs_pp, srcs_pp, sA_src, sA_dst, hd_pp1, self_pp1, xp, c1_pp_bias,
      offs_bp, srcs_bp, sB_src, sB_dst, hd_bp1, b1v, c1_bp_bias, p1, NPn);
  gat_row_kernel<<<cdiv(NBn * 64, 256), B, 0, stream>>>(offs_bb, srcs_bb, sC_src, sC_dst,
      hd_bb1, self_bb1, hbuf, c1_bb_bias, b1v, NBn);

  // ---- conv2 (head fused) ----
  hgemm_kernel<<<cdiv(NPn, 64), B, 0, stream>>>(p1, c2_pp_W, c2_pp_asrc, c2_pp_adst,
      wd2, hbuf, sA_src, sA_dst, sB_dst, NPn);
  hgemm_kernel<<<cdiv(NBn, 64), B, 0, stream>>>(b1v, c2_bp_Wsrc, c2_bp_asrc, nullptr,
      nullptr, b1v, sB_src, nullptr, nullptr, NBn);
  gat_row2h_kernel<<<cdiv(NPn * 64, 256), B, 0, stream>>>(
      offs_pp, srcs_pp, sA_src, sA_dst, hd_pp2, self_pp2, hbuf, c2_pp_bias,
      offs_bp, srcs_bp, sB_src, sB_dst, hd_bp2, b1v, c2_bp_bias,
      W_out, b_out, (float*)d_out, NPn);
}

// Round 21
// 1017.904 us; speedup vs baseline: 2.6260x; 1.0795x over previous
//
#include <hip/hip_runtime.h>

// ---------------------------------------------------------------------------
// HeteroGNN (2-layer hetero GAT) forward on MI355X — round 21.
// vs round 20 (passed, 1099us):
//  (1) edge_fused __launch_bounds__(256,4): the r20 profile showed 29%
//      occupancy because (256,2) pinned 2 blocks/CU while 84 VGPR allows 4
//      waves/SIMD — latency-bound kernel was TLP-starved by the annotation.
//  (2) scan2 parallelized (3 blocks x 256, chunked block-scan) — was a
//      3-thread serial walk over 2149 block sums.
//  (3) unroll-2 hints on gat inner loops. Everything else identical to r20.
// ---------------------------------------------------------------------------

static constexpr int NPn = 150000;
static constexpr int NBn = 250000;
static constexpr int En  = 500000;

static constexpr int OFF_PP = 0;
static constexpr int OFF_BP = 150016;
static constexpr int OFF_BB = 300032;
static constexpr int NCAT   = 550144;
static constexpr int NB_TOT = NCAT / 256;
static constexpr int BS_BP  = OFF_BP / 256;
static constexpr int BS_BB  = OFF_BB / 256;

__device__ __forceinline__ float lrelu(float x, float s) { return x >= 0.0f ? x : s * x; }

__global__ void fill_kernel(float* out, float val, int n) {
  int i = blockIdx.x * blockDim.x + threadIdx.x;
  if (i < n) out[i] = val;
}

// ---------------- batched CSR build ----------------
struct Dsts { const int* d[3]; const int* s[3]; };

__global__ void zero_int_kernel(int* p, int n) {
  int i = blockIdx.x * blockDim.x + threadIdx.x;
  if (i < n) p[i] = 0;
}

__global__ void hist_all_kernel(Dsts ds, int* __restrict__ cnt) {
  int t = blockIdx.x * blockDim.x + threadIdx.x;
  if (t >= 3 * En) return;
  int rel = t / En, e = t - rel * En;
  int base = (rel == 0) ? OFF_PP : (rel == 1) ? OFF_BP : OFF_BB;
  atomicAdd(&cnt[base + ds.d[rel][e]], 1);
}

__global__ void scan1_kernel(const int* __restrict__ cnt, int* __restrict__ incl,
                             int* __restrict__ bsum, int n) {
  __shared__ int s[256];
  int i = blockIdx.x * 256 + threadIdx.x;
  s[threadIdx.x] = (i < n) ? cnt[i] : 0;
  __syncthreads();
  for (int o = 1; o < 256; o <<= 1) {
    int t = (threadIdx.x >= o) ? s[threadIdx.x - o] : 0;
    __syncthreads();
    s[threadIdx.x] += t;
    __syncthreads();
  }
  if (i < n) incl[i] = s[threadIdx.x];
  if (threadIdx.x == 255) bsum[blockIdx.x] = s[255];
}

// parallel exclusive scan of block sums, one block per segment
__global__ void scan2_kernel(int* bsum) {
  int seg = blockIdx.x;
  int lo = (seg == 0) ? 0 : (seg == 1) ? BS_BP : BS_BB;
  int hi = (seg == 0) ? BS_BP : (seg == 1) ? BS_BB : NB_TOT;
  int len = hi - lo;
  int chunk = (len + 255) / 256;
  int s = lo + threadIdx.x * chunk;
  int e = min(s + chunk, hi);
  __shared__ int part[256];
  int sum = 0;
  for (int i = s; i < e; ++i) sum += bsum[i];
  part[threadIdx.x] = sum;
  __syncthreads();
  for (int o = 1; o < 256; o <<= 1) {
    int t = (threadIdx.x >= o) ? part[threadIdx.x - o] : 0;
    __syncthreads();
    part[threadIdx.x] += t;
    __syncthreads();
  }
  int run = (threadIdx.x == 0) ? 0 : part[threadIdx.x - 1];
  for (int i = s; i < e; ++i) { int v = bsum[i]; bsum[i] = run; run += v; }
}

__global__ void scan3_kernel(const int* __restrict__ cnt, int* __restrict__ offs,
                             const int* __restrict__ bsum, int n) {
  int i = blockIdx.x * 256 + threadIdx.x;
  if (i < n) offs[i] = offs[i] - cnt[i] + bsum[i >> 8];
}

__global__ void copy_int_kernel(const int* __restrict__ src, int* __restrict__ dstp, int n) {
  int i = blockIdx.x * blockDim.x + threadIdx.x;
  if (i < n) dstp[i] = src[i];
}

__global__ void scatter_all_kernel(Dsts ds, int* __restrict__ cursor,
                                   int* __restrict__ srcs, int* __restrict__ pos) {
  int t = blockIdx.x * blockDim.x + threadIdx.x;
  if (t >= 3 * En) return;
  int rel = t / En, e = t - rel * En;
  int base = (rel == 0) ? OFF_PP : (rel == 1) ? OFF_BP : OFF_BB;
  int p = atomicAdd(&cursor[base + ds.d[rel][e]], 1);
  srcs[rel * En + p] = ds.s[rel][e];
  pos[rel * En + e] = p;
}

// ---------------- tiled dense kernels (r20, proven) ----------------
__global__ void proj_kernel(const float* __restrict__ X, const float* __restrict__ W,
                            const float* __restrict__ b, float* __restrict__ Y, int N) {
  __shared__ __align__(16) float Ws[32 * 64];
  __shared__ float Xs[64 * 33];
  __shared__ float bs[64];
  for (int i = threadIdx.x; i < 32 * 64; i += 256) Ws[i] = W[i];
  if (threadIdx.x < 64) bs[threadIdx.x] = b[threadIdx.x];
  int base = blockIdx.x * 64;
  int rows = min(64, N - base);
  {
    const float4* s4 = reinterpret_cast<const float4*>(X + (size_t)base * 32);
    for (int idx = threadIdx.x; idx < rows * 8; idx += 256) {
      float4 v = s4[idx];
      int r = idx >> 3, c4 = idx & 7;
      float* d = &Xs[r * 33 + c4 * 4];
      d[0] = v.x; d[1] = v.y; d[2] = v.z; d[3] = v.w;
    }
  }
  __syncthreads();
  int r = threadIdx.x >> 2, q = threadIdx.x & 3;
  if (r >= rows) return;
  const float4* Ws4 = reinterpret_cast<const float4*>(Ws);
  float acc[16];
  const float4* b4 = reinterpret_cast<const float4*>(&bs[q * 16]);
#pragma unroll
  for (int j = 0; j < 4; ++j) {
    float4 v = b4[j];
    acc[4 * j + 0] = v.x; acc[4 * j + 1] = v.y; acc[4 * j + 2] = v.z; acc[4 * j + 3] = v.w;
  }
#pragma unroll
  for (int k = 0; k < 32; ++k) {
    float xv = Xs[r * 33 + k];
#pragma unroll
    for (int j = 0; j < 4; ++j) {
      float4 w = Ws4[k * 16 + q * 4 + j];
      acc[4 * j + 0] += xv * w.x; acc[4 * j + 1] += xv * w.y;
      acc[4 * j + 2] += xv * w.z; acc[4 * j + 3] += xv * w.w;
    }
  }
  float4* y4 = reinterpret_cast<float4*>(Y + (size_t)(base + r) * 64 + q * 16);
#pragma unroll
  for (int j = 0; j < 4; ++j)
    y4[j] = make_float4(lrelu(acc[4 * j + 0], 0.01f), lrelu(acc[4 * j + 1], 0.01f),
                        lrelu(acc[4 * j + 2], 0.01f), lrelu(acc[4 * j + 3], 0.01f));
}

__global__ void hgemm_kernel(const float* X, const float* __restrict__ W,
                             const float* __restrict__ a1, const float* __restrict__ a2,
                             const float* __restrict__ xv,
                             float* H, float* __restrict__ S1,
                             float* __restrict__ S2, float* __restrict__ S3, int N) {
  __shared__ __align__(16) float Ws[64 * 64];
  __shared__ float Xs[64 * 65];
  __shared__ float a1s[64], a2s[64], xvs[64];
  for (int i = threadIdx.x; i < 64 * 64; i += 256) Ws[i] = W[i];
  if (threadIdx.x < 64) {
    a1s[threadIdx.x] = a1[threadIdx.x];
    a2s[threadIdx.x] = a2 ? a2[threadIdx.x] : 0.0f;
    xvs[threadIdx.x] = xv ? xv[threadIdx.x] : 0.0f;
  }
  int base = blockIdx.x * 64;
  int rows = min(64, N - base);
  {
    const float4* s4 = reinterpret_cast<const float4*>(X + (size_t)base * 64);
    for (int idx = threadIdx.x; idx < rows * 16; idx += 256) {
      float4 v = s4[idx];
      int r = idx >> 4, c4 = idx & 15;
      float* d = &Xs[r * 65 + c4 * 4];
      d[0] = v.x; d[1] = v.y; d[2] = v.z; d[3] = v.w;
    }
  }
  __syncthreads();
  int r = threadIdx.x >> 2, q = threadIdx.x & 3;
  if (r >= rows) return;
  const float4* Ws4 = reinterpret_cast<const float4*>(Ws);
  float acc[16];
#pragma unroll
  for (int c = 0; c < 16; ++c) acc[c] = 0.0f;
  float s3p = 0.0f;
#pragma unroll
  for (int k = 0; k < 64; ++k) {
    float xval = Xs[r * 65 + k];
#pragma unroll
    for (int j = 0; j < 4; ++j) {
      float4 w = Ws4[k * 16 + q * 4 + j];
      acc[4 * j + 0] += xval * w.x; acc[4 * j + 1] += xval * w.y;
      acc[4 * j + 2] += xval * w.z; acc[4 * j + 3] += xval * w.w;
    }
  }
#pragma unroll
  for (int k = 0; k < 16; ++k) s3p += Xs[r * 65 + q * 16 + k] * xvs[q * 16 + k];
  float s1p = 0.0f, s2p = 0.0f;
#pragma unroll
  for (int c = 0; c < 16; ++c) {
    s1p += acc[c] * a1s[q * 16 + c];
    s2p += acc[c] * a2s[q * 16 + c];
  }
  s1p += __shfl_xor(s1p, 1, 64); s1p += __shfl_xor(s1p, 2, 64);
  s2p += __shfl_xor(s2p, 1, 64); s2p += __shfl_xor(s2p, 2, 64);
  s3p += __shfl_xor(s3p, 1, 64); s3p += __shfl_xor(s3p, 2, 64);
  float4* h4 = reinterpret_cast<float4*>(H + (size_t)(base + r) * 64 + q * 16);
#pragma unroll
  for (int j = 0; j < 4; ++j)
    h4[j] = make_float4(acc[4 * j + 0], acc[4 * j + 1], acc[4 * j + 2], acc[4 * j + 3]);
  if (q == 0) {
    S1[base + r] = s1p;
    if (S2) S2[base + r] = s2p;
    if (S3) S3[base + r] = s3p;
  }
}

__global__ void hgemm2_kernel(float* X, const float* __restrict__ W1,
                              const float* __restrict__ a1a,
                              const float* __restrict__ W2,
                              const float* __restrict__ a2a, const float* __restrict__ a2b,
                              float* __restrict__ H1out,
                              float* __restrict__ S1a, float* __restrict__ S2a,
                              float* __restrict__ S2b, int N) {
  __shared__ __align__(16) float W1s[64 * 64];
  __shared__ __align__(16) float W2s[64 * 64];
  __shared__ float Xs[64 * 65];
  __shared__ float v1[64], v2a[64], v2b[64];
  for (int i = threadIdx.x; i < 64 * 64; i += 256) { W1s[i] = W1[i]; W2s[i] = W2[i]; }
  if (threadIdx.x < 64) {
    v1[threadIdx.x] = a1a[threadIdx.x];
    v2a[threadIdx.x] = a2a[threadIdx.x];
    v2b[threadIdx.x] = a2b[threadIdx.x];
  }
  int base = blockIdx.x * 64;
  int rows = min(64, N - base);
  {
    const float4* s4 = reinterpret_cast<const float4*>(X + (size_t)base * 64);
    for (int idx = threadIdx.x; idx < rows * 16; idx += 256) {
      float4 v = s4[idx];
      int r = idx >> 4, c4 = idx & 15;
      float* d = &Xs[r * 65 + c4 * 4];
      d[0] = v.x; d[1] = v.y; d[2] = v.z; d[3] = v.w;
    }
  }
  __syncthreads();
  int r = threadIdx.x >> 2, q = threadIdx.x & 3;
  if (r >= rows) return;
  const float4* W1s4 = reinterpret_cast<const float4*>(W1s);
  const float4* W2s4 = reinterpret_cast<const float4*>(W2s);
  float acc1[16], acc2[16];
#pragma unroll
  for (int c = 0; c < 16; ++c) { acc1[c] = 0.0f; acc2[c] = 0.0f; }
#pragma unroll
  for (int k = 0; k < 64; ++k) {
    float xval = Xs[r * 65 + k];
#pragma unroll
    for (int j = 0; j < 4; ++j) {
      float4 w1 = W1s4[k * 16 + q * 4 + j];
      acc1[4 * j + 0] += xval * w1.x; acc1[4 * j + 1] += xval * w1.y;
      acc1[4 * j + 2] += xval * w1.z; acc1[4 * j + 3] += xval * w1.w;
      float4 w2 = W2s4[k * 16 + q * 4 + j];
      acc2[4 * j + 0] += xval * w2.x; acc2[4 * j + 1] += xval * w2.y;
      acc2[4 * j + 2] += xval * w2.z; acc2[4 * j + 3] += xval * w2.w;
    }
  }
  float s1p = 0.0f, sap = 0.0f, sbp = 0.0f;
#pragma unroll
  for (int c = 0; c < 16; ++c) {
    s1p += acc1[c] * v1[q * 16 + c];
    sap += acc2[c] * v2a[q * 16 + c];
    sbp += acc2[c] * v2b[q * 16 + c];
  }
  s1p += __shfl_xor(s1p, 1, 64); s1p += __shfl_xor(s1p, 2, 64);
  sap += __shfl_xor(sap, 1, 64); sap += __shfl_xor(sap, 2, 64);
  sbp += __shfl_xor(sbp, 1, 64); sbp += __shfl_xor(sbp, 2, 64);
  float4* h14 = reinterpret_cast<float4*>(H1out + (size_t)(base + r) * 64 + q * 16);
  float4* h24 = reinterpret_cast<float4*>(X + (size_t)(base + r) * 64 + q * 16);
#pragma unroll
  for (int j = 0; j < 4; ++j) {
    h14[j] = make_float4(acc1[4 * j + 0], acc1[4 * j + 1], acc1[4 * j + 2], acc1[4 * j + 3]);
    h24[j] = make_float4(acc2[4 * j + 0], acc2[4 * j + 1], acc2[4 * j + 2], acc2[4 * j + 3]);
  }
  if (q == 0) {
    S1a[base + r] = s1p;
    S2a[base + r] = sap;
    S2b[base + r] = sbp;
  }
}

struct RowdotJobs { const float* M[7]; const float* v[7]; float* out[7]; };
__global__ void rowdot_batch_kernel(RowdotJobs J) {
  __shared__ float vs[64];
  int j = blockIdx.x;
  vs[threadIdx.x] = J.v[j][threadIdx.x];
  __syncthreads();
  float s = 0.0f;
  const float* M = J.M[j];
#pragma unroll
  for (int c = 0; c < 64; ++c) s += M[threadIdx.x * 64 + c] * vs[c];
  J.out[j][threadIdx.x] = s;
}

// ---------------- quarter-wave edge kernel, per-wave LDS slices --------------
struct EdgeJobs {
  const float* EA[3]; const float* We[3]; const float* be[3];
  const float* wa1[3]; const float* wa2[3]; float* hd1[3]; float* hd2[3];
  const int* pos[3];
};
__global__ __launch_bounds__(256, 4) void edge_fused_kernel(EdgeJobs J,
                                                            float* __restrict__ sacc) {
  int rel = blockIdx.x >> 9;
  int blk = blockIdx.x & 511;
  __shared__ float eas[4][32 * 16];
  __shared__ float red1[4], red2[4];
  bool has2 = (J.wa2[rel] != nullptr);
  int lane = threadIdx.x & 63;
  int wv   = threadIdx.x >> 6;
  int qd   = lane >> 4;
  int sl   = lane & 15;
  float* myeas = eas[wv];
  float wreg[16][4];
  const float* We = J.We[rel];
#pragma unroll
  for (int k = 0; k < 16; ++k) {
    float4 w = *reinterpret_cast<const float4*>(&We[k * 64 + sl * 4]);
    wreg[k][0] = w.x; wreg[k][1] = w.y; wreg[k][2] = w.z; wreg[k][3] = w.w;
  }
  float4 bc = *reinterpret_cast<const float4*>(&J.be[rel][sl * 4]);
  float4 w1c = *reinterpret_cast<const float4*>(&J.wa1[rel][sl * 4]);
  float4 w2c = has2 ? *reinterpret_cast<const float4*>(&J.wa2[rel][sl * 4])
                    : make_float4(0.f, 0.f, 0.f, 0.f);
  const float* EA = J.EA[rel];
  float* hd1 = J.hd1[rel];
  float* hd2 = J.hd2[rel];
  const int* pos = J.pos[rel];
  float s1 = 0.0f, s2 = 0.0f;
  for (int base = (blk * 4 + wv) * 32; base < En; base += 512 * 4 * 32) {
    int tile = min(32, En - base);
    float4* d4 = reinterpret_cast<float4*>(myeas);
    const float4* s4 = reinterpret_cast<const float4*>(EA + (size_t)base * 16);
    for (int i = lane; i < tile * 4; i += 64) d4[i] = s4[i];
#pragma unroll
    for (int it = 0; it < 8; ++it) {
      int e = it * 4 + qd;
      if (e < tile) {
        float t0 = bc.x, t1 = bc.y, t2 = bc.z, t3 = bc.w;
#pragma unroll
        for (int k = 0; k < 16; ++k) {
          float xv = myeas[e * 16 + k];
          t0 += xv * wreg[k][0]; t1 += xv * wreg[k][1];
          t2 += xv * wreg[k][2]; t3 += xv * wreg[k][3];
        }
        t0 = lrelu(t0, 0.01f); t1 = lrelu(t1, 0.01f);
        t2 = lrelu(t2, 0.01f); t3 = lrelu(t3, 0.01f);
        float d1 = t0 * w1c.x + t1 * w1c.y + t2 * w1c.z + t3 * w1c.w;
        float d2 = t0 * w2c.x + t1 * w2c.y + t2 * w2c.z + t3 * w2c.w;
#pragma unroll
        for (int o = 1; o < 16; o <<= 1) {
          d1 += __shfl_xor(d1, o, 64);
          d2 += __shfl_xor(d2, o, 64);
        }
        if (sl == 0) {
          int p = pos[base + e];
          hd1[p] = d1;
          if (has2) hd2[p] = d2;
          s1 += d1;
          s2 += d2;
        }
      }
    }
  }
  if (rel < 2) {
#pragma unroll
    for (int o = 32; o >= 1; o >>= 1) {
      s1 += __shfl_xor(s1, o, 64);
      s2 += __shfl_xor(s2, o, 64);
    }
    if (lane == 0) { red1[wv] = s1; red2[wv] = s2; }
    __syncthreads();
    if (threadIdx.x == 0) {
      float t1 = red1[0] + red1[1] + red1[2] + red1[3];
      float t2 = red2[0] + red2[1] + red2[2] + red2[3];
      if (rel == 0) {
        atomicAdd(&sacc[0], t1);
        atomicAdd(&sacc[1], t2);
      } else {
        atomicAdd(&sacc[2], t1);
      }
    }
  }
}

__global__ void selfscale_kernel(const float* __restrict__ sacc, float invE,
                                 float* __restrict__ self_pp1, float* __restrict__ self_pp2,
                                 float* __restrict__ self_bb1) {
  if (threadIdx.x == 0) {
    self_pp1[0] = sacc[0] * invE;
    self_pp2[0] = sacc[1] * invE;
    self_bb1[0] = sacc[2] * invE;
  }
}

// ---------------- fused per-row GAT kernels ----------------
__global__ void gat_row_kernel(const int* __restrict__ offs, const int* __restrict__ srcs,
                               const float* __restrict__ ssrc, const float* __restrict__ sdst,
                               const float* __restrict__ hd, const float* __restrict__ selfhd,
                               const float* __restrict__ H, const float* __restrict__ bias,
                               float* __restrict__ out, int N) {
  int wid = (int)(((size_t)blockIdx.x * blockDim.x + threadIdx.x) >> 6);
  int lane = threadIdx.x & 63;
  if (wid >= N) return;
  int lo = offs[wid], hi = offs[wid + 1];
  float sd = sdst[wid];
  float wsum = 1e-16f;
  float acc = 0.0f;
  if (selfhd) {
    float wself = __expf(lrelu(ssrc[wid] + sd + selfhd[0], 0.2f));
    wsum += wself;
    acc = wself * H[(size_t)wid * 64 + lane];
  }
#pragma unroll 2
  for (int p = lo; p < hi; ++p) {
    int s = srcs[p];
    float w = __expf(lrelu(ssrc[s] + sd + hd[p], 0.2f));
    wsum += w;
    acc += w * H[(size_t)s * 64 + lane];
  }
  out[(size_t)wid * 64 + lane] = acc / wsum + bias[lane];
}

__global__ void gat_row2_kernel(
    const int* __restrict__ offsA, const int* __restrict__ srcsA,
    const float* __restrict__ ssrcA, const float* __restrict__ sdstA,
    const float* __restrict__ hdA, const float* __restrict__ selfhdA,
    const float* __restrict__ HA, const float* __restrict__ biasA,
    const int* __restrict__ offsB, const int* __restrict__ srcsB,
    const float* __restrict__ ssrcB, const float* __restrict__ sdstB,
    const float* __restrict__ hdB, const float* __restrict__ HB,
    const float* __restrict__ biasB,
    float* __restrict__ out, int N) {
  int wid = (int)(((size_t)blockIdx.x * blockDim.x + threadIdx.x) >> 6);
  int lane = threadIdx.x & 63;
  if (wid >= N) return;
  int lo = offsA[wid], hi = offsA[wid + 1];
  float sd = sdstA[wid];
  float wself = __expf(lrelu(ssrcA[wid] + sd + selfhdA[0], 0.2f));
  float wsumA = 1e-16f + wself;
  float accA = wself * HA[(size_t)wid * 64 + lane];
#pragma unroll 2
  for (int p = lo; p < hi; ++p) {
    int s = srcsA[p];
    float w = __expf(lrelu(ssrcA[s] + sd + hdA[p], 0.2f));
    wsumA += w;
    accA += w * HA[(size_t)s * 64 + lane];
  }
  lo = offsB[wid]; hi = offsB[wid + 1];
  float sdB = sdstB[wid];
  float wsumB = 1e-16f;
  float accB = 0.0f;
#pragma unroll 2
  for (int p = lo; p < hi; ++p) {
    int s = srcsB[p];
    float w = __expf(lrelu(ssrcB[s] + sdB + hdB[p], 0.2f));
    wsumB += w;
    accB += w * HB[(size_t)s * 64 + lane];
  }
  out[(size_t)wid * 64 + lane] =
      accA / wsumA + biasA[lane] + accB / wsumB + biasB[lane];
}

__global__ void gat_row2h_kernel(
    const int* __restrict__ offsA, const int* __restrict__ srcsA,
    const float* __restrict__ ssrcA, const float* __restrict__ sdstA,
    const float* __restrict__ hdA, const float* __restrict__ selfhdA,
    const float* __restrict__ HA, const float* __restrict__ biasA,
    const int* __restrict__ offsB, const int* __restrict__ srcsB,
    const float* __restrict__ ssrcB, const float* __restrict__ sdstB,
    const float* __restrict__ hdB, const float* __restrict__ HB,
    const float* __restrict__ biasB,
    const float* __restrict__ wout, const float* __restrict__ bout,
    float* __restrict__ out, int N) {
  int wid = (int)(((size_t)blockIdx.x * blockDim.x + threadIdx.x) >> 6);
  int lane = threadIdx.x & 63;
  if (wid >= N) return;
  int lo = offsA[wid], hi = offsA[wid + 1];
  float sd = sdstA[wid];
  float wself = __expf(lrelu(ssrcA[wid] + sd + selfhdA[0], 0.2f));
  float wsumA = 1e-16f + wself;
  float accA = wself * HA[(size_t)wid * 64 + lane];
#pragma unroll 2
  for (int p = lo; p < hi; ++p) {
    int s = srcsA[p];
    float w = __expf(lrelu(ssrcA[s] + sd + hdA[p], 0.2f));
    wsumA += w;
    accA += w * HA[(size_t)s * 64 + lane];
  }
  lo = offsB[wid]; hi = offsB[wid + 1];
  float sdB = sdstB[wid];
  float wsumB = 1e-16f;
  float accB = 0.0f;
#pragma unroll 2
  for (int p = lo; p < hi; ++p) {
    int s = srcsB[p];
    float w = __expf(lrelu(ssrcB[s] + sdB + hdB[p], 0.2f));
    wsumB += w;
    accB += w * HB[(size_t)s * 64 + lane];
  }
  float r = accA / wsumA + biasA[lane] + accB / wsumB + biasB[lane];
  r *= wout[lane];
#pragma unroll
  for (int o = 32; o >= 1; o >>= 1) r += __shfl_xor(r, o, 64);
  if (lane == 0) out[wid] = r + bout[0];
}

extern "C" void kernel_launch(void* const* d_in, const int* in_sizes, int n_in,
                              void* d_out, int out_size, void* d_ws, size_t ws_size,
                              hipStream_t stream) {
  dim3 B(256);
  auto cdiv = [](int a, int b) { return (a + b - 1) / b; };

  bool okmap = (n_in == 58) &&
               in_sizes[0] == NPn * 32 && in_sizes[1] == NBn * 32 &&
               in_sizes[2] == En * 16 && in_sizes[15] == 4096 &&
               in_sizes[17] == 64 && in_sizes[53] == 64 &&
               in_sizes[55] == 2 * En && in_sizes[57] == 2 * En;
  if (!okmap) {
    fill_kernel<<<cdiv(NPn, 256), B, 0, stream>>>((float*)d_out, 1000.0f, NPn);
    return;
  }

  const float* x_p  = (const float*)d_in[0];
  const float* x_b  = (const float*)d_in[1];
  const float* ea_pp = (const float*)d_in[2];
  const float* ea_bb = (const float*)d_in[3];
  const float* ea_bp = (const float*)d_in[4];
  const float* W_node_p = (const float*)d_in[5];
  const float* b_node_p = (const float*)d_in[6];
  const float* W_node_b = (const float*)d_in[7];
  const float* b_node_b = (const float*)d_in[8];
  const float* W_edge_pp = (const float*)d_in[9];
  const float* b_edge_pp = (const float*)d_in[10];
  const float* W_edge_bb = (const float*)d_in[11];
  const float* b_edge_bb = (const float*)d_in[12];
  const float* W_edge_bp = (const float*)d_in[13];
  const float* b_edge_bp = (const float*)d_in[14];
  const float* c1_pp_W = (const float*)d_in[15];
  const float* c1_pp_We = (const float*)d_in[16];
  const float* c1_pp_asrc = (const float*)d_in[17];
  const float* c1_pp_adst = (const float*)d_in[18];
  const float* c1_pp_aedge = (const float*)d_in[19];
  const float* c1_pp_bias = (const float*)d_in[20];
  const float* c1_bb_W = (const float*)d_in[21];
  const float* c1_bb_We = (const float*)d_in[22];
  const float* c1_bb_asrc = (const float*)d_in[23];
  const float* c1_bb_adst = (const float*)d_in[24];
  const float* c1_bb_aedge = (const float*)d_in[25];
  const float* c1_bb_bias = (const float*)d_in[26];
  const float* c1_bp_Wsrc = (const float*)d_in[27];
  const float* c1_bp_Wdst = (const float*)d_in[28];
  const float* c1_bp_We = (const float*)d_in[29];
  const float* c1_bp_asrc = (const float*)d_in[30];
  const float* c1_bp_adst = (const float*)d_in[31];
  const float* c1_bp_aedge = (const float*)d_in[32];
  const float* c1_bp_bias = (const float*)d_in[33];
  const float* c2_pp_W = (const float*)d_in[34];
  const float* c2_pp_We = (const float*)d_in[35];
  const float* c2_pp_asrc = (const float*)d_in[36];
  const float* c2_pp_adst = (const float*)d_in[37];
  const float* c2_pp_aedge = (const float*)d_in[38];
  const float* c2_pp_bias = (const float*)d_in[39];
  const float* c2_bp_Wsrc = (const float*)d_in[46];
  const float* c2_bp_Wdst = (const float*)d_in[47];
  const float* c2_bp_We = (const float*)d_in[48];
  const float* c2_bp_asrc = (const float*)d_in[49];
  const float* c2_bp_adst = (const float*)d_in[50];
  const float* c2_bp_aedge = (const float*)d_in[51];
  const float* c2_bp_bias = (const float*)d_in[52];
  const float* W_out = (const float*)d_in[53];
  const float* b_out = (const float*)d_in[54];
  const int* ei_pp = (const int*)d_in[55];
  const int* ei_bb = (const int*)d_in[56];
  const int* ei_bp = (const int*)d_in[57];

  // ---- workspace layout
  float* ws = (float*)d_ws;
  int* offs_cat = (int*)ws;                  // NCAT
  int* cnt_cat  = offs_cat + NCAT;           // NCAT
  int* bsum     = cnt_cat + NCAT;            // pad 2560
  int* srcs_cat = bsum + 2560;               // 3*En
  int* pos_cat  = srcs_cat + 3 * En;         // 3*En
  float* xp    = (float*)(pos_cat + 3 * En); // NPn*64
  float* p1    = xp + (size_t)NPn * 64;      // NPn*64
  float* b1v   = p1 + (size_t)NPn * 64;      // NBn*64
  float* hbuf  = b1v + (size_t)NBn * 64;     // NBn*64
  float* hd_pp1 = hbuf + (size_t)NBn * 64;   // En x5 (CSR order)
  float* hd_pp2 = hd_pp1 + En;
  float* hd_bb1 = hd_pp2 + En;
  float* hd_bp1 = hd_bb1 + En;
  float* hd_bp2 = hd_bp1 + En;
  float* sA_src = hd_bp2 + En;               // NBn
  float* sA_dst = sA_src + NBn;              // NBn
  float* sB_src = sA_dst + NBn;              // NBn
  float* sB_dst = sB_src + NBn;              // NPn
  float* sC_src = sB_dst + NPn;              // NBn
  float* sC_dst = sC_src + NBn;              // NBn
  float* small  = sC_dst + NBn;              // 1024

  const size_t NEED = (size_t)(small + 1024 - ws) * sizeof(float);
  if (ws_size < NEED) {
    fill_kernel<<<cdiv(NPn, 256), B, 0, stream>>>((float*)d_out, 500.0f, NPn);
    return;
  }

  float* sacc    = small + 0;
  float* wa_pp1  = small + 128;  float* wa_pp2  = small + 192;
  float* wa_bb1  = small + 256;  float* wa_bp1  = small + 320; float* wa_bp2 = small + 384;
  float* wd1     = small + 448;  float* wd2     = small + 512;
  float* self_pp1= small + 576;  float* self_pp2= small + 577; float* self_bb1 = small + 578;
  const float invE = 1.0f / (float)En;

  hipMemsetAsync(sacc, 0, 16 * sizeof(float), stream);

  RowdotJobs RJ;
  RJ.M[0] = c1_pp_We;  RJ.v[0] = c1_pp_aedge; RJ.out[0] = wa_pp1;
  RJ.M[1] = c2_pp_We;  RJ.v[1] = c2_pp_aedge; RJ.out[1] = wa_pp2;
  RJ.M[2] = c1_bb_We;  RJ.v[2] = c1_bb_aedge; RJ.out[2] = wa_bb1;
  RJ.M[3] = c1_bp_We;  RJ.v[3] = c1_bp_aedge; RJ.out[3] = wa_bp1;
  RJ.M[4] = c2_bp_We;  RJ.v[4] = c2_bp_aedge; RJ.out[4] = wa_bp2;
  RJ.M[5] = c1_bp_Wdst; RJ.v[5] = c1_bp_adst; RJ.out[5] = wd1;
  RJ.M[6] = c2_bp_Wdst; RJ.v[6] = c2_bp_adst; RJ.out[6] = wd2;
  rowdot_batch_kernel<<<7, 64, 0, stream>>>(RJ);

  proj_kernel<<<cdiv(NPn, 64), B, 0, stream>>>(x_p, W_node_p, b_node_p, xp, NPn);
  proj_kernel<<<cdiv(NBn, 64), B, 0, stream>>>(x_b, W_node_b, b_node_b, hbuf, NBn);

  Dsts DS;
  DS.d[0] = ei_pp + En; DS.d[1] = ei_bp + En; DS.d[2] = ei_bb + En;
  DS.s[0] = ei_pp;      DS.s[1] = ei_bp;      DS.s[2] = ei_bb;
  zero_int_kernel<<<cdiv(NCAT, 256), B, 0, stream>>>(cnt_cat, NCAT);
  hist_all_kernel<<<cdiv(3 * En, 256), B, 0, stream>>>(DS, cnt_cat);
  scan1_kernel<<<NB_TOT, B, 0, stream>>>(cnt_cat, offs_cat, bsum, NCAT);
  scan2_kernel<<<3, B, 0, stream>>>(bsum);
  scan3_kernel<<<NB_TOT, B, 0, stream>>>(cnt_cat, offs_cat, bsum, NCAT);
  copy_int_kernel<<<cdiv(NCAT, 256), B, 0, stream>>>(offs_cat, cnt_cat, NCAT);
  scatter_all_kernel<<<cdiv(3 * En, 256), B, 0, stream>>>(DS, cnt_cat, srcs_cat, pos_cat);

  const int* offs_pp = offs_cat + OFF_PP;
  const int* offs_bp = offs_cat + OFF_BP;
  const int* offs_bb = offs_cat + OFF_BB;
  const int* srcs_pp = srcs_cat;
  const int* srcs_bp = srcs_cat + En;
  const int* srcs_bb = srcs_cat + 2 * En;

  EdgeJobs EJ;
  EJ.EA[0] = ea_pp; EJ.We[0] = W_edge_pp; EJ.be[0] = b_edge_pp;
  EJ.wa1[0] = wa_pp1; EJ.wa2[0] = wa_pp2; EJ.hd1[0] = hd_pp1; EJ.hd2[0] = hd_pp2;
  EJ.pos[0] = pos_cat;
  EJ.EA[1] = ea_bb; EJ.We[1] = W_edge_bb; EJ.be[1] = b_edge_bb;
  EJ.wa1[1] = wa_bb1; EJ.wa2[1] = nullptr; EJ.hd1[1] = hd_bb1; EJ.hd2[1] = nullptr;
  EJ.pos[1] = pos_cat + 2 * En;
  EJ.EA[2] = ea_bp; EJ.We[2] = W_edge_bp; EJ.be[2] = b_edge_bp;
  EJ.wa1[2] = wa_bp1; EJ.wa2[2] = wa_bp2; EJ.hd1[2] = hd_bp1; EJ.hd2[2] = hd_bp2;
  EJ.pos[2] = pos_cat + En;
  edge_fused_kernel<<<3 * 512, B, 0, stream>>>(EJ, sacc);

  selfscale_kernel<<<1, 64, 0, stream>>>(sacc, invE, self_pp1, self_pp2, self_bb1);

  // ---- conv1 ----
  hgemm_kernel<<<cdiv(NPn, 64), B, 0, stream>>>(xp, c1_pp_W, c1_pp_asrc, c1_pp_adst,
      wd1, xp, sA_src, sA_dst, sB_dst, NPn);
  hgemm2_kernel<<<cdiv(NBn, 64), B, 0, stream>>>(hbuf, c1_bp_Wsrc, c1_bp_asrc,
      c1_bb_W, c1_bb_asrc, c1_bb_adst, b1v, sB_src, sC_src, sC_dst, NBn);
  gat_row2_kernel<<<cdiv(NPn * 64, 256), B, 0, stream>>>(
      offs_pp, srcs_pp, sA_src, sA_dst, hd_pp1, self_pp1, xp, c1_pp_bias,
      offs_bp, srcs_bp, sB_src, sB_dst, hd_bp1, b1v, c1_bp_bias, p1, NPn);
  gat_row_kernel<<<cdiv(NBn * 64, 256), B, 0, stream>>>(offs_bb, srcs_bb, sC_src, sC_dst,
      hd_bb1, self_bb1, hbuf, c1_bb_bias, b1v, NBn);

  // ---- conv2 (head fused) ----
  hgemm_kernel<<<cdiv(NPn, 64), B, 0, stream>>>(p1, c2_pp_W, c2_pp_asrc, c2_pp_adst,
      wd2, hbuf, sA_src, sA_dst, sB_dst, NPn);
  hgemm_kernel<<<cdiv(NBn, 64), B, 0, stream>>>(b1v, c2_bp_Wsrc, c2_bp_asrc, nullptr,
      nullptr, b1v, sB_src, nullptr, nullptr, NBn);
  gat_row2h_kernel<<<cdiv(NPn * 64, 256), B, 0, stream>>>(
      offs_pp, srcs_pp, sA_src, sA_dst, hd_pp2, self_pp2, hbuf, c2_pp_bias,
      offs_bp, srcs_bp, sB_src, sB_dst, hd_bp2, b1v, c2_bp_bias,
      W_out, b_out, (float*)d_out, NPn);
}

// Round 22
// 909.893 us; speedup vs baseline: 2.9377x; 1.1187x over previous
//
#include <hip/hip_runtime.h>

// ---------------------------------------------------------------------------
// HeteroGNN (2-layer hetero GAT) forward on MI355X — round 22.
// vs round 21 (passed, 1018us): edge_fused __launch_bounds__(256,3).
// r21's (256,4) forced VGPR 84->64 and spilled wreg[16][4] (hbm 143->362MB,
// 158->260us). (256,3) caps at ~170 VGPR -> natural 84-VGPR allocation kept,
// 3 waves/SIMD occupancy. Everything else identical to r21.
// ---------------------------------------------------------------------------

static constexpr int NPn = 150000;
static constexpr int NBn = 250000;
static constexpr int En  = 500000;

static constexpr int OFF_PP = 0;
static constexpr int OFF_BP = 150016;
static constexpr int OFF_BB = 300032;
static constexpr int NCAT   = 550144;
static constexpr int NB_TOT = NCAT / 256;
static constexpr int BS_BP  = OFF_BP / 256;
static constexpr int BS_BB  = OFF_BB / 256;

__device__ __forceinline__ float lrelu(float x, float s) { return x >= 0.0f ? x : s * x; }

__global__ void fill_kernel(float* out, float val, int n) {
  int i = blockIdx.x * blockDim.x + threadIdx.x;
  if (i < n) out[i] = val;
}

// ---------------- batched CSR build ----------------
struct Dsts { const int* d[3]; const int* s[3]; };

__global__ void zero_int_kernel(int* p, int n) {
  int i = blockIdx.x * blockDim.x + threadIdx.x;
  if (i < n) p[i] = 0;
}

__global__ void hist_all_kernel(Dsts ds, int* __restrict__ cnt) {
  int t = blockIdx.x * blockDim.x + threadIdx.x;
  if (t >= 3 * En) return;
  int rel = t / En, e = t - rel * En;
  int base = (rel == 0) ? OFF_PP : (rel == 1) ? OFF_BP : OFF_BB;
  atomicAdd(&cnt[base + ds.d[rel][e]], 1);
}

__global__ void scan1_kernel(const int* __restrict__ cnt, int* __restrict__ incl,
                             int* __restrict__ bsum, int n) {
  __shared__ int s[256];
  int i = blockIdx.x * 256 + threadIdx.x;
  s[threadIdx.x] = (i < n) ? cnt[i] : 0;
  __syncthreads();
  for (int o = 1; o < 256; o <<= 1) {
    int t = (threadIdx.x >= o) ? s[threadIdx.x - o] : 0;
    __syncthreads();
    s[threadIdx.x] += t;
    __syncthreads();
  }
  if (i < n) incl[i] = s[threadIdx.x];
  if (threadIdx.x == 255) bsum[blockIdx.x] = s[255];
}

// parallel exclusive scan of block sums, one block per segment
__global__ void scan2_kernel(int* bsum) {
  int seg = blockIdx.x;
  int lo = (seg == 0) ? 0 : (seg == 1) ? BS_BP : BS_BB;
  int hi = (seg == 0) ? BS_BP : (seg == 1) ? BS_BB : NB_TOT;
  int len = hi - lo;
  int chunk = (len + 255) / 256;
  int s = lo + threadIdx.x * chunk;
  int e = min(s + chunk, hi);
  __shared__ int part[256];
  int sum = 0;
  for (int i = s; i < e; ++i) sum += bsum[i];
  part[threadIdx.x] = sum;
  __syncthreads();
  for (int o = 1; o < 256; o <<= 1) {
    int t = (threadIdx.x >= o) ? part[threadIdx.x - o] : 0;
    __syncthreads();
    part[threadIdx.x] += t;
    __syncthreads();
  }
  int run = (threadIdx.x == 0) ? 0 : part[threadIdx.x - 1];
  for (int i = s; i < e; ++i) { int v = bsum[i]; bsum[i] = run; run += v; }
}

__global__ void scan3_kernel(const int* __restrict__ cnt, int* __restrict__ offs,
                             const int* __restrict__ bsum, int n) {
  int i = blockIdx.x * 256 + threadIdx.x;
  if (i < n) offs[i] = offs[i] - cnt[i] + bsum[i >> 8];
}

__global__ void copy_int_kernel(const int* __restrict__ src, int* __restrict__ dstp, int n) {
  int i = blockIdx.x * blockDim.x + threadIdx.x;
  if (i < n) dstp[i] = src[i];
}

__global__ void scatter_all_kernel(Dsts ds, int* __restrict__ cursor,
                                   int* __restrict__ srcs, int* __restrict__ pos) {
  int t = blockIdx.x * blockDim.x + threadIdx.x;
  if (t >= 3 * En) return;
  int rel = t / En, e = t - rel * En;
  int base = (rel == 0) ? OFF_PP : (rel == 1) ? OFF_BP : OFF_BB;
  int p = atomicAdd(&cursor[base + ds.d[rel][e]], 1);
  srcs[rel * En + p] = ds.s[rel][e];
  pos[rel * En + e] = p;
}

// ---------------- tiled dense kernels (r20, proven) ----------------
__global__ void proj_kernel(const float* __restrict__ X, const float* __restrict__ W,
                            const float* __restrict__ b, float* __restrict__ Y, int N) {
  __shared__ __align__(16) float Ws[32 * 64];
  __shared__ float Xs[64 * 33];
  __shared__ float bs[64];
  for (int i = threadIdx.x; i < 32 * 64; i += 256) Ws[i] = W[i];
  if (threadIdx.x < 64) bs[threadIdx.x] = b[threadIdx.x];
  int base = blockIdx.x * 64;
  int rows = min(64, N - base);
  {
    const float4* s4 = reinterpret_cast<const float4*>(X + (size_t)base * 32);
    for (int idx = threadIdx.x; idx < rows * 8; idx += 256) {
      float4 v = s4[idx];
      int r = idx >> 3, c4 = idx & 7;
      float* d = &Xs[r * 33 + c4 * 4];
      d[0] = v.x; d[1] = v.y; d[2] = v.z; d[3] = v.w;
    }
  }
  __syncthreads();
  int r = threadIdx.x >> 2, q = threadIdx.x & 3;
  if (r >= rows) return;
  const float4* Ws4 = reinterpret_cast<const float4*>(Ws);
  float acc[16];
  const float4* b4 = reinterpret_cast<const float4*>(&bs[q * 16]);
#pragma unroll
  for (int j = 0; j < 4; ++j) {
    float4 v = b4[j];
    acc[4 * j + 0] = v.x; acc[4 * j + 1] = v.y; acc[4 * j + 2] = v.z; acc[4 * j + 3] = v.w;
  }
#pragma unroll
  for (int k = 0; k < 32; ++k) {
    float xv = Xs[r * 33 + k];
#pragma unroll
    for (int j = 0; j < 4; ++j) {
      float4 w = Ws4[k * 16 + q * 4 + j];
      acc[4 * j + 0] += xv * w.x; acc[4 * j + 1] += xv * w.y;
      acc[4 * j + 2] += xv * w.z; acc[4 * j + 3] += xv * w.w;
    }
  }
  float4* y4 = reinterpret_cast<float4*>(Y + (size_t)(base + r) * 64 + q * 16);
#pragma unroll
  for (int j = 0; j < 4; ++j)
    y4[j] = make_float4(lrelu(acc[4 * j + 0], 0.01f), lrelu(acc[4 * j + 1], 0.01f),
                        lrelu(acc[4 * j + 2], 0.01f), lrelu(acc[4 * j + 3], 0.01f));
}

__global__ void hgemm_kernel(const float* X, const float* __restrict__ W,
                             const float* __restrict__ a1, const float* __restrict__ a2,
                             const float* __restrict__ xv,
                             float* H, float* __restrict__ S1,
                             float* __restrict__ S2, float* __restrict__ S3, int N) {
  __shared__ __align__(16) float Ws[64 * 64];
  __shared__ float Xs[64 * 65];
  __shared__ float a1s[64], a2s[64], xvs[64];
  for (int i = threadIdx.x; i < 64 * 64; i += 256) Ws[i] = W[i];
  if (threadIdx.x < 64) {
    a1s[threadIdx.x] = a1[threadIdx.x];
    a2s[threadIdx.x] = a2 ? a2[threadIdx.x] : 0.0f;
    xvs[threadIdx.x] = xv ? xv[threadIdx.x] : 0.0f;
  }
  int base = blockIdx.x * 64;
  int rows = min(64, N - base);
  {
    const float4* s4 = reinterpret_cast<const float4*>(X + (size_t)base * 64);
    for (int idx = threadIdx.x; idx < rows * 16; idx += 256) {
      float4 v = s4[idx];
      int r = idx >> 4, c4 = idx & 15;
      float* d = &Xs[r * 65 + c4 * 4];
      d[0] = v.x; d[1] = v.y; d[2] = v.z; d[3] = v.w;
    }
  }
  __syncthreads();
  int r = threadIdx.x >> 2, q = threadIdx.x & 3;
  if (r >= rows) return;
  const float4* Ws4 = reinterpret_cast<const float4*>(Ws);
  float acc[16];
#pragma unroll
  for (int c = 0; c < 16; ++c) acc[c] = 0.0f;
  float s3p = 0.0f;
#pragma unroll
  for (int k = 0; k < 64; ++k) {
    float xval = Xs[r * 65 + k];
#pragma unroll
    for (int j = 0; j < 4; ++j) {
      float4 w = Ws4[k * 16 + q * 4 + j];
      acc[4 * j + 0] += xval * w.x; acc[4 * j + 1] += xval * w.y;
      acc[4 * j + 2] += xval * w.z; acc[4 * j + 3] += xval * w.w;
    }
  }
#pragma unroll
  for (int k = 0; k < 16; ++k) s3p += Xs[r * 65 + q * 16 + k] * xvs[q * 16 + k];
  float s1p = 0.0f, s2p = 0.0f;
#pragma unroll
  for (int c = 0; c < 16; ++c) {
    s1p += acc[c] * a1s[q * 16 + c];
    s2p += acc[c] * a2s[q * 16 + c];
  }
  s1p += __shfl_xor(s1p, 1, 64); s1p += __shfl_xor(s1p, 2, 64);
  s2p += __shfl_xor(s2p, 1, 64); s2p += __shfl_xor(s2p, 2, 64);
  s3p += __shfl_xor(s3p, 1, 64); s3p += __shfl_xor(s3p, 2, 64);
  float4* h4 = reinterpret_cast<float4*>(H + (size_t)(base + r) * 64 + q * 16);
#pragma unroll
  for (int j = 0; j < 4; ++j)
    h4[j] = make_float4(acc[4 * j + 0], acc[4 * j + 1], acc[4 * j + 2], acc[4 * j + 3]);
  if (q == 0) {
    S1[base + r] = s1p;
    if (S2) S2[base + r] = s2p;
    if (S3) S3[base + r] = s3p;
  }
}

__global__ void hgemm2_kernel(float* X, const float* __restrict__ W1,
                              const float* __restrict__ a1a,
                              const float* __restrict__ W2,
                              const float* __restrict__ a2a, const float* __restrict__ a2b,
                              float* __restrict__ H1out,
                              float* __restrict__ S1a, float* __restrict__ S2a,
                              float* __restrict__ S2b, int N) {
  __shared__ __align__(16) float W1s[64 * 64];
  __shared__ __align__(16) float W2s[64 * 64];
  __shared__ float Xs[64 * 65];
  __shared__ float v1[64], v2a[64], v2b[64];
  for (int i = threadIdx.x; i < 64 * 64; i += 256) { W1s[i] = W1[i]; W2s[i] = W2[i]; }
  if (threadIdx.x < 64) {
    v1[threadIdx.x] = a1a[threadIdx.x];
    v2a[threadIdx.x] = a2a[threadIdx.x];
    v2b[threadIdx.x] = a2b[threadIdx.x];
  }
  int base = blockIdx.x * 64;
  int rows = min(64, N - base);
  {
    const float4* s4 = reinterpret_cast<const float4*>(X + (size_t)base * 64);
    for (int idx = threadIdx.x; idx < rows * 16; idx += 256) {
      float4 v = s4[idx];
      int r = idx >> 4, c4 = idx & 15;
      float* d = &Xs[r * 65 + c4 * 4];
      d[0] = v.x; d[1] = v.y; d[2] = v.z; d[3] = v.w;
    }
  }
  __syncthreads();
  int r = threadIdx.x >> 2, q = threadIdx.x & 3;
  if (r >= rows) return;
  const float4* W1s4 = reinterpret_cast<const float4*>(W1s);
  const float4* W2s4 = reinterpret_cast<const float4*>(W2s);
  float acc1[16], acc2[16];
#pragma unroll
  for (int c = 0; c < 16; ++c) { acc1[c] = 0.0f; acc2[c] = 0.0f; }
#pragma unroll
  for (int k = 0; k < 64; ++k) {
    float xval = Xs[r * 65 + k];
#pragma unroll
    for (int j = 0; j < 4; ++j) {
      float4 w1 = W1s4[k * 16 + q * 4 + j];
      acc1[4 * j + 0] += xval * w1.x; acc1[4 * j + 1] += xval * w1.y;
      acc1[4 * j + 2] += xval * w1.z; acc1[4 * j + 3] += xval * w1.w;
      float4 w2 = W2s4[k * 16 + q * 4 + j];
      acc2[4 * j + 0] += xval * w2.x; acc2[4 * j + 1] += xval * w2.y;
      acc2[4 * j + 2] += xval * w2.z; acc2[4 * j + 3] += xval * w2.w;
    }
  }
  float s1p = 0.0f, sap = 0.0f, sbp = 0.0f;
#pragma unroll
  for (int c = 0; c < 16; ++c) {
    s1p += acc1[c] * v1[q * 16 + c];
    sap += acc2[c] * v2a[q * 16 + c];
    sbp += acc2[c] * v2b[q * 16 + c];
  }
  s1p += __shfl_xor(s1p, 1, 64); s1p += __shfl_xor(s1p, 2, 64);
  sap += __shfl_xor(sap, 1, 64); sap += __shfl_xor(sap, 2, 64);
  sbp += __shfl_xor(sbp, 1, 64); sbp += __shfl_xor(sbp, 2, 64);
  float4* h14 = reinterpret_cast<float4*>(H1out + (size_t)(base + r) * 64 + q * 16);
  float4* h24 = reinterpret_cast<float4*>(X + (size_t)(base + r) * 64 + q * 16);
#pragma unroll
  for (int j = 0; j < 4; ++j) {
    h14[j] = make_float4(acc1[4 * j + 0], acc1[4 * j + 1], acc1[4 * j + 2], acc1[4 * j + 3]);
    h24[j] = make_float4(acc2[4 * j + 0], acc2[4 * j + 1], acc2[4 * j + 2], acc2[4 * j + 3]);
  }
  if (q == 0) {
    S1a[base + r] = s1p;
    S2a[base + r] = sap;
    S2b[base + r] = sbp;
  }
}

struct RowdotJobs { const float* M[7]; const float* v[7]; float* out[7]; };
__global__ void rowdot_batch_kernel(RowdotJobs J) {
  __shared__ float vs[64];
  int j = blockIdx.x;
  vs[threadIdx.x] = J.v[j][threadIdx.x];
  __syncthreads();
  float s = 0.0f;
  const float* M = J.M[j];
#pragma unroll
  for (int c = 0; c < 64; ++c) s += M[threadIdx.x * 64 + c] * vs[c];
  J.out[j][threadIdx.x] = s;
}

// ---------------- quarter-wave edge kernel, per-wave LDS slices --------------
struct EdgeJobs {
  const float* EA[3]; const float* We[3]; const float* be[3];
  const float* wa1[3]; const float* wa2[3]; float* hd1[3]; float* hd2[3];
  const int* pos[3];
};
__global__ __launch_bounds__(256, 3) void edge_fused_kernel(EdgeJobs J,
                                                            float* __restrict__ sacc) {
  int rel = blockIdx.x >> 9;
  int blk = blockIdx.x & 511;
  __shared__ float eas[4][32 * 16];
  __shared__ float red1[4], red2[4];
  bool has2 = (J.wa2[rel] != nullptr);
  int lane = threadIdx.x & 63;
  int wv   = threadIdx.x >> 6;
  int qd   = lane >> 4;
  int sl   = lane & 15;
  float* myeas = eas[wv];
  float wreg[16][4];
  const float* We = J.We[rel];
#pragma unroll
  for (int k = 0; k < 16; ++k) {
    float4 w = *reinterpret_cast<const float4*>(&We[k * 64 + sl * 4]);
    wreg[k][0] = w.x; wreg[k][1] = w.y; wreg[k][2] = w.z; wreg[k][3] = w.w;
  }
  float4 bc = *reinterpret_cast<const float4*>(&J.be[rel][sl * 4]);
  float4 w1c = *reinterpret_cast<const float4*>(&J.wa1[rel][sl * 4]);
  float4 w2c = has2 ? *reinterpret_cast<const float4*>(&J.wa2[rel][sl * 4])
                    : make_float4(0.f, 0.f, 0.f, 0.f);
  const float* EA = J.EA[rel];
  float* hd1 = J.hd1[rel];
  float* hd2 = J.hd2[rel];
  const int* pos = J.pos[rel];
  float s1 = 0.0f, s2 = 0.0f;
  for (int base = (blk * 4 + wv) * 32; base < En; base += 512 * 4 * 32) {
    int tile = min(32, En - base);
    float4* d4 = reinterpret_cast<float4*>(myeas);
    const float4* s4 = reinterpret_cast<const float4*>(EA + (size_t)base * 16);
    for (int i = lane; i < tile * 4; i += 64) d4[i] = s4[i];
#pragma unroll
    for (int it = 0; it < 8; ++it) {
      int e = it * 4 + qd;
      if (e < tile) {
        float t0 = bc.x, t1 = bc.y, t2 = bc.z, t3 = bc.w;
#pragma unroll
        for (int k = 0; k < 16; ++k) {
          float xv = myeas[e * 16 + k];
          t0 += xv * wreg[k][0]; t1 += xv * wreg[k][1];
          t2 += xv * wreg[k][2]; t3 += xv * wreg[k][3];
        }
        t0 = lrelu(t0, 0.01f); t1 = lrelu(t1, 0.01f);
        t2 = lrelu(t2, 0.01f); t3 = lrelu(t3, 0.01f);
        float d1 = t0 * w1c.x + t1 * w1c.y + t2 * w1c.z + t3 * w1c.w;
        float d2 = t0 * w2c.x + t1 * w2c.y + t2 * w2c.z + t3 * w2c.w;
#pragma unroll
        for (int o = 1; o < 16; o <<= 1) {
          d1 += __shfl_xor(d1, o, 64);
          d2 += __shfl_xor(d2, o, 64);
        }
        if (sl == 0) {
          int p = pos[base + e];
          hd1[p] = d1;
          if (has2) hd2[p] = d2;
          s1 += d1;
          s2 += d2;
        }
      }
    }
  }
  if (rel < 2) {
#pragma unroll
    for (int o = 32; o >= 1; o >>= 1) {
      s1 += __shfl_xor(s1, o, 64);
      s2 += __shfl_xor(s2, o, 64);
    }
    if (lane == 0) { red1[wv] = s1; red2[wv] = s2; }
    __syncthreads();
    if (threadIdx.x == 0) {
      float t1 = red1[0] + red1[1] + red1[2] + red1[3];
      float t2 = red2[0] + red2[1] + red2[2] + red2[3];
      if (rel == 0) {
        atomicAdd(&sacc[0], t1);
        atomicAdd(&sacc[1], t2);
      } else {
        atomicAdd(&sacc[2], t1);
      }
    }
  }
}

__global__ void selfscale_kernel(const float* __restrict__ sacc, float invE,
                                 float* __restrict__ self_pp1, float* __restrict__ self_pp2,
                                 float* __restrict__ self_bb1) {
  if (threadIdx.x == 0) {
    self_pp1[0] = sacc[0] * invE;
    self_pp2[0] = sacc[1] * invE;
    self_bb1[0] = sacc[2] * invE;
  }
}

// ---------------- fused per-row GAT kernels ----------------
__global__ void gat_row_kernel(const int* __restrict__ offs, const int* __restrict__ srcs,
                               const float* __restrict__ ssrc, const float* __restrict__ sdst,
                               const float* __restrict__ hd, const float* __restrict__ selfhd,
                               const float* __restrict__ H, const float* __restrict__ bias,
                               float* __restrict__ out, int N) {
  int wid = (int)(((size_t)blockIdx.x * blockDim.x + threadIdx.x) >> 6);
  int lane = threadIdx.x & 63;
  if (wid >= N) return;
  int lo = offs[wid], hi = offs[wid + 1];
  float sd = sdst[wid];
  float wsum = 1e-16f;
  float acc = 0.0f;
  if (selfhd) {
    float wself = __expf(lrelu(ssrc[wid] + sd + selfhd[0], 0.2f));
    wsum += wself;
    acc = wself * H[(size_t)wid * 64 + lane];
  }
#pragma unroll 2
  for (int p = lo; p < hi; ++p) {
    int s = srcs[p];
    float w = __expf(lrelu(ssrc[s] + sd + hd[p], 0.2f));
    wsum += w;
    acc += w * H[(size_t)s * 64 + lane];
  }
  out[(size_t)wid * 64 + lane] = acc / wsum + bias[lane];
}

__global__ void gat_row2_kernel(
    const int* __restrict__ offsA, const int* __restrict__ srcsA,
    const float* __restrict__ ssrcA, const float* __restrict__ sdstA,
    const float* __restrict__ hdA, const float* __restrict__ selfhdA,
    const float* __restrict__ HA, const float* __restrict__ biasA,
    const int* __restrict__ offsB, const int* __restrict__ srcsB,
    const float* __restrict__ ssrcB, const float* __restrict__ sdstB,
    const float* __restrict__ hdB, const float* __restrict__ HB,
    const float* __restrict__ biasB,
    float* __restrict__ out, int N) {
  int wid = (int)(((size_t)blockIdx.x * blockDim.x + threadIdx.x) >> 6);
  int lane = threadIdx.x & 63;
  if (wid >= N) return;
  int lo = offsA[wid], hi = offsA[wid + 1];
  float sd = sdstA[wid];
  float wself = __expf(lrelu(ssrcA[wid] + sd + selfhdA[0], 0.2f));
  float wsumA = 1e-16f + wself;
  float accA = wself * HA[(size_t)wid * 64 + lane];
#pragma unroll 2
  for (int p = lo; p < hi; ++p) {
    int s = srcsA[p];
    float w = __expf(lrelu(ssrcA[s] + sd + hdA[p], 0.2f));
    wsumA += w;
    accA += w * HA[(size_t)s * 64 + lane];
  }
  lo = offsB[wid]; hi = offsB[wid + 1];
  float sdB = sdstB[wid];
  float wsumB = 1e-16f;
  float accB = 0.0f;
#pragma unroll 2
  for (int p = lo; p < hi; ++p) {
    int s = srcsB[p];
    float w = __expf(lrelu(ssrcB[s] + sdB + hdB[p], 0.2f));
    wsumB += w;
    accB += w * HB[(size_t)s * 64 + lane];
  }
  out[(size_t)wid * 64 + lane] =
      accA / wsumA + biasA[lane] + accB / wsumB + biasB[lane];
}

__global__ void gat_row2h_kernel(
    const int* __restrict__ offsA, const int* __restrict__ srcsA,
    const float* __restrict__ ssrcA, const float* __restrict__ sdstA,
    const float* __restrict__ hdA, const float* __restrict__ selfhdA,
    const float* __restrict__ HA, const float* __restrict__ biasA,
    const int* __restrict__ offsB, const int* __restrict__ srcsB,
    const float* __restrict__ ssrcB, const float* __restrict__ sdstB,
    const float* __restrict__ hdB, const float* __restrict__ HB,
    const float* __restrict__ biasB,
    const float* __restrict__ wout, const float* __restrict__ bout,
    float* __restrict__ out, int N) {
  int wid = (int)(((size_t)blockIdx.x * blockDim.x + threadIdx.x) >> 6);
  int lane = threadIdx.x & 63;
  if (wid >= N) return;
  int lo = offsA[wid], hi = offsA[wid + 1];
  float sd = sdstA[wid];
  float wself = __expf(lrelu(ssrcA[wid] + sd + selfhdA[0], 0.2f));
  float wsumA = 1e-16f + wself;
  float accA = wself * HA[(size_t)wid * 64 + lane];
#pragma unroll 2
  for (int p = lo; p < hi; ++p) {
    int s = srcsA[p];
    float w = __expf(lrelu(ssrcA[s] + sd + hdA[p], 0.2f));
    wsumA += w;
    accA += w * HA[(size_t)s * 64 + lane];
  }
  lo = offsB[wid]; hi = offsB[wid + 1];
  float sdB = sdstB[wid];
  float wsumB = 1e-16f;
  float accB = 0.0f;
#pragma unroll 2
  for (int p = lo; p < hi; ++p) {
    int s = srcsB[p];
    float w = __expf(lrelu(ssrcB[s] + sdB + hdB[p], 0.2f));
    wsumB += w;
    accB += w * HB[(size_t)s * 64 + lane];
  }
  float r = accA / wsumA + biasA[lane] + accB / wsumB + biasB[lane];
  r *= wout[lane];
#pragma unroll
  for (int o = 32; o >= 1; o >>= 1) r += __shfl_xor(r, o, 64);
  if (lane == 0) out[wid] = r + bout[0];
}

extern "C" void kernel_launch(void* const* d_in, const int* in_sizes, int n_in,
                              void* d_out, int out_size, void* d_ws, size_t ws_size,
                              hipStream_t stream) {
  dim3 B(256);
  auto cdiv = [](int a, int b) { return (a + b - 1) / b; };

  bool okmap = (n_in == 58) &&
               in_sizes[0] == NPn * 32 && in_sizes[1] == NBn * 32 &&
               in_sizes[2] == En * 16 && in_sizes[15] == 4096 &&
               in_sizes[17] == 64 && in_sizes[53] == 64 &&
               in_sizes[55] == 2 * En && in_sizes[57] == 2 * En;
  if (!okmap) {
    fill_kernel<<<cdiv(NPn, 256), B, 0, stream>>>((float*)d_out, 1000.0f, NPn);
    return;
  }

  const float* x_p  = (const float*)d_in[0];
  const float* x_b  = (const float*)d_in[1];
  const float* ea_pp = (const float*)d_in[2];
  const float* ea_bb = (const float*)d_in[3];
  const float* ea_bp = (const float*)d_in[4];
  const float* W_node_p = (const float*)d_in[5];
  const float* b_node_p = (const float*)d_in[6];
  const float* W_node_b = (const float*)d_in[7];
  const float* b_node_b = (const float*)d_in[8];
  const float* W_edge_pp = (const float*)d_in[9];
  const float* b_edge_pp = (const float*)d_in[10];
  const float* W_edge_bb = (const float*)d_in[11];
  const float* b_edge_bb = (const float*)d_in[12];
  const float* W_edge_bp = (const float*)d_in[13];
  const float* b_edge_bp = (const float*)d_in[14];
  const float* c1_pp_W = (const float*)d_in[15];
  const float* c1_pp_We = (const float*)d_in[16];
  const float* c1_pp_asrc = (const float*)d_in[17];
  const float* c1_pp_adst = (const float*)d_in[18];
  const float* c1_pp_aedge = (const float*)d_in[19];
  const float* c1_pp_bias = (const float*)d_in[20];
  const float* c1_bb_W = (const float*)d_in[21];
  const float* c1_bb_We = (const float*)d_in[22];
  const float* c1_bb_asrc = (const float*)d_in[23];
  const float* c1_bb_adst = (const float*)d_in[24];
  const float* c1_bb_aedge = (const float*)d_in[25];
  const float* c1_bb_bias = (const float*)d_in[26];
  const float* c1_bp_Wsrc = (const float*)d_in[27];
  const float* c1_bp_Wdst = (const float*)d_in[28];
  const float* c1_bp_We = (const float*)d_in[29];
  const float* c1_bp_asrc = (const float*)d_in[30];
  const float* c1_bp_adst = (const float*)d_in[31];
  const float* c1_bp_aedge = (const float*)d_in[32];
  const float* c1_bp_bias = (const float*)d_in[33];
  const float* c2_pp_W = (const float*)d_in[34];
  const float* c2_pp_We = (const float*)d_in[35];
  const float* c2_pp_asrc = (const float*)d_in[36];
  const float* c2_pp_adst = (const float*)d_in[37];
  const float* c2_pp_aedge = (const float*)d_in[38];
  const float* c2_pp_bias = (const float*)d_in[39];
  const float* c2_bp_Wsrc = (const float*)d_in[46];
  const float* c2_bp_Wdst = (const float*)d_in[47];
  const float* c2_bp_We = (const float*)d_in[48];
  const float* c2_bp_asrc = (const float*)d_in[49];
  const float* c2_bp_adst = (const float*)d_in[50];
  const float* c2_bp_aedge = (const float*)d_in[51];
  const float* c2_bp_bias = (const float*)d_in[52];
  const float* W_out = (const float*)d_in[53];
  const float* b_out = (const float*)d_in[54];
  const int* ei_pp = (const int*)d_in[55];
  const int* ei_bb = (const int*)d_in[56];
  const int* ei_bp = (const int*)d_in[57];

  // ---- workspace layout
  float* ws = (float*)d_ws;
  int* offs_cat = (int*)ws;                  // NCAT
  int* cnt_cat  = offs_cat + NCAT;           // NCAT
  int* bsum     = cnt_cat + NCAT;            // pad 2560
  int* srcs_cat = bsum + 2560;               // 3*En
  int* pos_cat  = srcs_cat + 3 * En;         // 3*En
  float* xp    = (float*)(pos_cat + 3 * En); // NPn*64
  float* p1    = xp + (size_t)NPn * 64;      // NPn*64
  float* b1v   = p1 + (size_t)NPn * 64;      // NBn*64
  float* hbuf  = b1v + (size_t)NBn * 64;     // NBn*64
  float* hd_pp1 = hbuf + (size_t)NBn * 64;   // En x5 (CSR order)
  float* hd_pp2 = hd_pp1 + En;
  float* hd_bb1 = hd_pp2 + En;
  float* hd_bp1 = hd_bb1 + En;
  float* hd_bp2 = hd_bp1 + En;
  float* sA_src = hd_bp2 + En;               // NBn
  float* sA_dst = sA_src + NBn;              // NBn
  float* sB_src = sA_dst + NBn;              // NBn
  float* sB_dst = sB_src + NBn;              // NPn
  float* sC_src = sB_dst + NPn;              // NBn
  float* sC_dst = sC_src + NBn;              // NBn
  float* small  = sC_dst + NBn;              // 1024

  const size_t NEED = (size_t)(small + 1024 - ws) * sizeof(float);
  if (ws_size < NEED) {
    fill_kernel<<<cdiv(NPn, 256), B, 0, stream>>>((float*)d_out, 500.0f, NPn);
    return;
  }

  float* sacc    = small + 0;
  float* wa_pp1  = small + 128;  float* wa_pp2  = small + 192;
  float* wa_bb1  = small + 256;  float* wa_bp1  = small + 320; float* wa_bp2 = small + 384;
  float* wd1     = small + 448;  float* wd2     = small + 512;
  float* self_pp1= small + 576;  float* self_pp2= small + 577; float* self_bb1 = small + 578;
  const float invE = 1.0f / (float)En;

  hipMemsetAsync(sacc, 0, 16 * sizeof(float), stream);

  RowdotJobs RJ;
  RJ.M[0] = c1_pp_We;  RJ.v[0] = c1_pp_aedge; RJ.out[0] = wa_pp1;
  RJ.M[1] = c2_pp_We;  RJ.v[1] = c2_pp_aedge; RJ.out[1] = wa_pp2;
  RJ.M[2] = c1_bb_We;  RJ.v[2] = c1_bb_aedge; RJ.out[2] = wa_bb1;
  RJ.M[3] = c1_bp_We;  RJ.v[3] = c1_bp_aedge; RJ.out[3] = wa_bp1;
  RJ.M[4] = c2_bp_We;  RJ.v[4] = c2_bp_aedge; RJ.out[4] = wa_bp2;
  RJ.M[5] = c1_bp_Wdst; RJ.v[5] = c1_bp_adst; RJ.out[5] = wd1;
  RJ.M[6] = c2_bp_Wdst; RJ.v[6] = c2_bp_adst; RJ.out[6] = wd2;
  rowdot_batch_kernel<<<7, 64, 0, stream>>>(RJ);

  proj_kernel<<<cdiv(NPn, 64), B, 0, stream>>>(x_p, W_node_p, b_node_p, xp, NPn);
  proj_kernel<<<cdiv(NBn, 64), B, 0, stream>>>(x_b, W_node_b, b_node_b, hbuf, NBn);

  Dsts DS;
  DS.d[0] = ei_pp + En; DS.d[1] = ei_bp + En; DS.d[2] = ei_bb + En;
  DS.s[0] = ei_pp;      DS.s[1] = ei_bp;      DS.s[2] = ei_bb;
  zero_int_kernel<<<cdiv(NCAT, 256), B, 0, stream>>>(cnt_cat, NCAT);
  hist_all_kernel<<<cdiv(3 * En, 256), B, 0, stream>>>(DS, cnt_cat);
  scan1_kernel<<<NB_TOT, B, 0, stream>>>(cnt_cat, offs_cat, bsum, NCAT);
  scan2_kernel<<<3, B, 0, stream>>>(bsum);
  scan3_kernel<<<NB_TOT, B, 0, stream>>>(cnt_cat, offs_cat, bsum, NCAT);
  copy_int_kernel<<<cdiv(NCAT, 256), B, 0, stream>>>(offs_cat, cnt_cat, NCAT);
  scatter_all_kernel<<<cdiv(3 * En, 256), B, 0, stream>>>(DS, cnt_cat, srcs_cat, pos_cat);

  const int* offs_pp = offs_cat + OFF_PP;
  const int* offs_bp = offs_cat + OFF_BP;
  const int* offs_bb = offs_cat + OFF_BB;
  const int* srcs_pp = srcs_cat;
  const int* srcs_bp = srcs_cat + En;
  const int* srcs_bb = srcs_cat + 2 * En;

  EdgeJobs EJ;
  EJ.EA[0] = ea_pp; EJ.We[0] = W_edge_pp; EJ.be[0] = b_edge_pp;
  EJ.wa1[0] = wa_pp1; EJ.wa2[0] = wa_pp2; EJ.hd1[0] = hd_pp1; EJ.hd2[0] = hd_pp2;
  EJ.pos[0] = pos_cat;
  EJ.EA[1] = ea_bb; EJ.We[1] = W_edge_bb; EJ.be[1] = b_edge_bb;
  EJ.wa1[1] = wa_bb1; EJ.wa2[1] = nullptr; EJ.hd1[1] = hd_bb1; EJ.hd2[1] = nullptr;
  EJ.pos[1] = pos_cat + 2 * En;
  EJ.EA[2] = ea_bp; EJ.We[2] = W_edge_bp; EJ.be[2] = b_edge_bp;
  EJ.wa1[2] = wa_bp1; EJ.wa2[2] = wa_bp2; EJ.hd1[2] = hd_bp1; EJ.hd2[2] = hd_bp2;
  EJ.pos[2] = pos_cat + En;
  edge_fused_kernel<<<3 * 512, B, 0, stream>>>(EJ, sacc);

  selfscale_kernel<<<1, 64, 0, stream>>>(sacc, invE, self_pp1, self_pp2, self_bb1);

  // ---- conv1 ----
  hgemm_kernel<<<cdiv(NPn, 64), B, 0, stream>>>(xp, c1_pp_W, c1_pp_asrc, c1_pp_adst,
      wd1, xp, sA_src, sA_dst, sB_dst, NPn);
  hgemm2_kernel<<<cdiv(NBn, 64), B, 0, stream>>>(hbuf, c1_bp_Wsrc, c1_bp_asrc,
      c1_bb_W, c1_bb_asrc, c1_bb_adst, b1v, sB_src, sC_src, sC_dst, NBn);
  gat_row2_kernel<<<cdiv(NPn * 64, 256), B, 0, stream>>>(
      offs_pp, srcs_pp, sA_src, sA_dst, hd_pp1, self_pp1, xp, c1_pp_bias,
      offs_bp, srcs_bp, sB_src, sB_dst, hd_bp1, b1v, c1_bp_bias, p1, NPn);
  gat_row_kernel<<<cdiv(NBn * 64, 256), B, 0, stream>>>(offs_bb, srcs_bb, sC_src, sC_dst,
      hd_bb1, self_bb1, hbuf, c1_bb_bias, b1v, NBn);

  // ---- conv2 (head fused) ----
  hgemm_kernel<<<cdiv(NPn, 64), B, 0, stream>>>(p1, c2_pp_W, c2_pp_asrc, c2_pp_adst,
      wd2, hbuf, sA_src, sA_dst, sB_dst, NPn);
  hgemm_kernel<<<cdiv(NBn, 64), B, 0, stream>>>(b1v, c2_bp_Wsrc, c2_bp_asrc, nullptr,
      nullptr, b1v, sB_src, nullptr, nullptr, NBn);
  gat_row2h_kernel<<<cdiv(NPn * 64, 256), B, 0, stream>>>(
      offs_pp, srcs_pp, sA_src, sA_dst, hd_pp2, self_pp2, hbuf, c2_pp_bias,
      offs_bp, srcs_bp, sB_src, sB_dst, hd_bp2, b1v, c2_bp_bias,
      W_out, b_out, (float*)d_out, NPn);
}